// Round 2
// baseline (46020.428 us; speedup 1.0000x reference)
//
#include <hip/hip_runtime.h>
#include <math.h>

typedef float f32x4 __attribute__((ext_vector_type(4)));
typedef short s16x8 __attribute__((ext_vector_type(8)));

#define MFMA_BF16(a,b,c) __builtin_amdgcn_mfma_f32_16x16x32_bf16((a),(b),(c),0,0,0)
#define NBLK 41

// Geometry: D=850 pad 864 (27 kb of 32), 54 n-tiles of 16.
// Phase A: K=910 pad 928 (29 kb). M rows = T*B = 8192.
// PK_rec[mat][half][nt][kb][lane][8]; mat: 0=W0 lo, 1=W0 hi, 2+i=Ws[i].
//   elem = W[k][col], k = kb*32+(l>>4)*8+j, col = half*850 + nt*16+(l&15).
// float inputs may be fp32 or bf16 on device -> runtime-detected flag ctrl[0].

struct P {
  const int* tokens; const void* masks; const int* pos; const int* ner;
  const void* hidden;
  const void* enc_W; const void* ner_W; const void* pos_W;
  const void* agg_W; const void* agg_b;
  const void* W0; const void* Ws;
  const void* dec_W; const void* dec_b;
  void* out;
  unsigned short* PK_agg; unsigned short* PK_rec; unsigned short* comb;
  unsigned short* xbf; unsigned short* Sbf; unsigned short* hbf;
  float* Sf; float* hf; float* accr;
  int* ctrl; // [0]=bf16-input flag, [1]=barrier cnt, [2]=barrier gen
};

__device__ __forceinline__ unsigned short f2bf(float f) {
  union { float f; unsigned u; } v; v.f = f;
  return (unsigned short)((v.u + 0x7FFFu + ((v.u >> 16) & 1u)) >> 16);
}
__device__ __forceinline__ float ldf(const void* q, size_t i, int bf) {
  if (bf) { union { unsigned x; float f; } v;
            v.x = (unsigned)((const unsigned short*)q)[i] << 16; return v.f; }
  return ((const float*)q)[i];
}
__device__ __forceinline__ void stout(void* o, size_t i, float v, int bf) {
  if (bf) ((unsigned short*)o)[i] = f2bf(v);
  else    ((float*)o)[i] = v;
}
__device__ __forceinline__ float sigm(float x) { return 1.0f / (1.0f + expf(-x)); }
__device__ __forceinline__ float actf(int a, float x) {
  if (a == 0) return sigm(x);
  if (a == 1) return fmaxf(x, 0.0f);
  if (a == 2) return tanhf(x);
  return x;
}

// software grid barrier (sense-reversing, agent scope). All NBLK blocks call.
__device__ __forceinline__ void gbar(int* cnt, int* gen) {
  __syncthreads();
  if (threadIdx.x == 0) {
    int g = __hip_atomic_load(gen, __ATOMIC_RELAXED, __HIP_MEMORY_SCOPE_AGENT);
    int a = __hip_atomic_fetch_add(cnt, 1, __ATOMIC_ACQ_REL, __HIP_MEMORY_SCOPE_AGENT);
    if (a == NBLK - 1) {
      __hip_atomic_store(cnt, 0, __ATOMIC_RELAXED, __HIP_MEMORY_SCOPE_AGENT);
      __hip_atomic_store(gen, g + 1, __ATOMIC_RELEASE, __HIP_MEMORY_SCOPE_AGENT);
    } else {
      int spins = 0;
      while (__hip_atomic_load(gen, __ATOMIC_ACQUIRE, __HIP_MEMORY_SCOPE_AGENT) == g) {
        __builtin_amdgcn_s_sleep(2);
        if (++spins > 100000) break; // diagnostic escape, never hit when healthy
      }
    }
  }
  __syncthreads();
}

// ---------------- prep kernels ----------------

__global__ void k_detect(P p) {
  if (blockIdx.x == 0 && threadIdx.x == 0) {
    // bf16 buffer: ~all uint16s have exponent in [90,126] (|v|<=0.04 uniform).
    // fp32 buffer: even uint16s are mantissa noise -> ~14% plausible.
    const unsigned short* u = (const unsigned short*)p.W0;
    int good = 0;
    for (int i = 0; i < 256; ++i) {
      int e = (u[i] >> 7) & 0xFF;
      if (e >= 90 && e <= 126) ++good;
    }
    p.ctrl[0] = (good >= 192) ? 1 : 0;
    p.ctrl[1] = 0; p.ctrl[2] = 0;
  }
}

__global__ __launch_bounds__(256) void k_init(P p) {
  const int bf = p.ctrl[0];
  const int total = 54400 + 896 + 8064 + 114688;
  for (int e = blockIdx.x * blockDim.x + threadIdx.x; e < total;
       e += gridDim.x * blockDim.x) {
    if (e < 54400) {
      int b = e / 850, n = e % 850;
      float h0 = ldf(p.hidden, e, bf);
      p.hf[e] = h0; p.accr[e] = 0.0f;
      p.hbf[(size_t)b * 864 + n] = f2bf(h0);
    } else if (e < 54400 + 896) {
      int e2 = e - 54400; int b = e2 / 14, n = 850 + e2 % 14;
      p.hbf[(size_t)b * 864 + n] = 0;
    } else if (e < 54400 + 896 + 8064) {
      int e3 = e - 54400 - 896; int s = e3 / 896, r = e3 % 896;
      int b = r / 14, n = 850 + r % 14;
      p.Sbf[((size_t)s * 64 + b) * 864 + n] = 0;
    } else {
      int e4 = e - 54400 - 896 - 8064; int t = e4 / 896, r = e4 % 896;
      int b = r / 14, n = 850 + r % 14;
      p.xbf[((size_t)t * 64 + b) * 864 + n] = 0;
    }
  }
}

__global__ __launch_bounds__(256) void k_pack_agg(P p) {
  const int bf = p.ctrl[0];
  const long total = 801792L; // 54*29*512
  for (long e = (long)blockIdx.x * blockDim.x + threadIdx.x; e < total;
       e += (long)gridDim.x * blockDim.x) {
    int j = (int)(e & 7), l = (int)((e >> 3) & 63);
    long q9 = e >> 9;
    int kb = (int)(q9 % 29), nt = (int)(q9 / 29);
    int n = nt * 16 + (l & 15);
    int k = kb * 32 + ((l >> 4) << 3) + j;
    float v = 0.0f;
    if (n < 850 && k < 910) v = ldf(p.agg_W, (size_t)n * 910 + k, bf);
    p.PK_agg[e] = f2bf(v);
  }
}

__global__ __launch_bounds__(256) void k_comb(P p) {
  const int bf = p.ctrl[0];
  const long total = 7602176L; // 8192*928
  for (long e = (long)blockIdx.x * blockDim.x + threadIdx.x; e < total;
       e += (long)gridDim.x * blockDim.x) {
    int k = (int)(e % 928);
    int r = (int)(e / 928);  // r = t*64 + b
    int t = r >> 6, b = r & 63;
    float v = 0.0f;
    if (k < 850)      { int tok = p.tokens[b * 128 + t]; v = ldf(p.enc_W, (size_t)tok * 850 + k, bf); }
    else if (k < 880) { int nv = p.ner[b * 128 + t];     v = ldf(p.ner_W, nv * 30 + (k - 850), bf); }
    else if (k < 910) { int pv = p.pos[b * 128 + t];     v = ldf(p.pos_W, pv * 30 + (k - 880), bf); }
    p.comb[e] = f2bf(v);
  }
}

__global__ __launch_bounds__(256) void k_pack_rec(P p) {
  const int bf = p.ctrl[0];
  const long total = 14929920L; // 10*2*54*27*512
  for (long e = (long)blockIdx.x * blockDim.x + threadIdx.x; e < total;
       e += (long)gridDim.x * blockDim.x) {
    int j = (int)(e & 7), l = (int)((e >> 3) & 63);
    long q9 = e >> 9;
    int kb = (int)(q9 % 27);
    long q = q9 / 27;
    int nt = (int)(q % 54);
    int mh = (int)(q / 54);
    int half = mh & 1, mat = mh >> 1;
    int nl = nt * 16 + (l & 15);
    int col = half ? nl + 850 : nl;
    int k = kb * 32 + ((l >> 4) << 3) + j;
    float v = 0.0f;
    if (nl < 850 && k < 850) {
      if (mat == 0)      v = ldf(p.W0, (size_t)k * 1700 + col, bf);
      else if (mat == 1) v = ldf(p.W0, (size_t)(k + 850) * 1700 + col, bf);
      else               v = ldf(p.Ws, (size_t)(mat - 2) * 850 * 1700 + (size_t)k * 1700 + col, bf);
    }
    p.PK_rec[e] = f2bf(v);
  }
}

__global__ void k_diag(P p) { // ws_size too small sentinel
  if (blockIdx.x == 0 && threadIdx.x == 0)
    for (int i = 0; i < 64; ++i) ((float*)p.out)[i] = 2000.0f;
}

// ---------------- phase A: x = combined @ agg_W^T + b ----------------

__global__ __launch_bounds__(256) void k_phaseA(P p) {
  const int tid = threadIdx.x;
  const int l = tid & 63, lm = l & 15, lg = l >> 4;
  const int wid = (blockIdx.x << 2) | (tid >> 6);
  const int bf = p.ctrl[0];
  for (int u = wid; u < 512 * 54; u += 1024) {
    int mt = u / 54, nt = u - mt * 54;
    int r0 = mt << 4;
    f32x4 acc = {0.f, 0.f, 0.f, 0.f};
    const unsigned short* Arow = p.comb + (size_t)(r0 + lm) * 928 + (size_t)lg * 8;
    const unsigned short* Bp = p.PK_agg + (size_t)nt * 29 * 512 + (size_t)l * 8;
    for (int kb = 0; kb < 29; ++kb) {
      s16x8 a = *(const s16x8*)(Arow + (size_t)kb * 32);
      s16x8 b = *(const s16x8*)(Bp + (size_t)kb * 512);
      acc = MFMA_BF16(a, b, acc);
    }
    int n = nt * 16 + lm;
    if (n < 850) {
      float bias = ldf(p.agg_b, n, bf);
#pragma unroll
      for (int i = 0; i < 4; ++i) {
        int r = r0 + lg * 4 + i;
        p.xbf[(size_t)r * 864 + n] = f2bf(acc[i] + bias);
      }
    }
  }
}

// ---------------- scan kernel (persistent, software grid barrier) ----------------

__device__ __forceinline__ void kloop_pair4(
    const P& p, const unsigned short* Abase, int mat, int nt, int l,
    f32x4& c0, f32x4& c1, f32x4& c2, f32x4& c3,
    f32x4& h0, f32x4& h1, f32x4& h2, f32x4& h3) {
  const unsigned short* Bc = p.PK_rec + (((size_t)(mat * 2 + 0) * 54 + nt) * 27) * 512 + (size_t)l * 8;
  const unsigned short* Bh = p.PK_rec + (((size_t)(mat * 2 + 1) * 54 + nt) * 27) * 512 + (size_t)l * 8;
  for (int kb = 0; kb < 27; ++kb) {
    s16x8 bc = *(const s16x8*)(Bc + (size_t)kb * 512);
    s16x8 bh = *(const s16x8*)(Bh + (size_t)kb * 512);
    s16x8 a0 = *(const s16x8*)(Abase + (size_t)kb * 32);
    s16x8 a1 = *(const s16x8*)(Abase + 16 * 864 + (size_t)kb * 32);
    s16x8 a2 = *(const s16x8*)(Abase + 32 * 864 + (size_t)kb * 32);
    s16x8 a3 = *(const s16x8*)(Abase + 48 * 864 + (size_t)kb * 32);
    c0 = MFMA_BF16(a0, bc, c0); h0 = MFMA_BF16(a0, bh, h0);
    c1 = MFMA_BF16(a1, bc, c1); h1 = MFMA_BF16(a1, bh, h1);
    c2 = MFMA_BF16(a2, bc, c2); h2 = MFMA_BF16(a2, bh, h2);
    c3 = MFMA_BF16(a3, bc, c3); h3 = MFMA_BF16(a3, bh, h3);
  }
}

__device__ __forceinline__ void epi_unit(
    const P& p, int nt, int lm, int lg, const float* prevb, int dst, int act,
    const f32x4& c0, const f32x4& c1, const f32x4& c2, const f32x4& c3,
    const f32x4& h0, const f32x4& h1, const f32x4& h2, const f32x4& h3) {
  int n = nt * 16 + lm;
  if (n >= 850) return;
#define EPI_ONE(mt, cc, hh)                                                   \
  { _Pragma("unroll") for (int i = 0; i < 4; ++i) {                           \
      int b = (mt) * 16 + lg * 4 + i;                                         \
      float prev = prevb[b * 850 + n];                                        \
      float s = prev + sigm((cc)[i]) * (actf(act, (hh)[i]) - prev);           \
      p.Sf[((size_t)(dst) * 64 + b) * 850 + n] = s;                           \
      p.Sbf[((size_t)(dst) * 64 + b) * 864 + n] = f2bf(s);                    \
    } }
  EPI_ONE(0, c0, h0) EPI_ONE(1, c1, h1) EPI_ONE(2, c2, h2) EPI_ONE(3, c3, h3)
#undef EPI_ONE
}

__device__ __forceinline__ void thin_unit(
    const P& p, int nt, const unsigned short* Abase, int mat,
    const float* prevb, int dst, int act, int lm, int lg, int l) {
  f32x4 z = {0.f, 0.f, 0.f, 0.f};
  f32x4 c0 = z, c1 = z, c2 = z, c3 = z, h0 = z, h1 = z, h2 = z, h3 = z;
  kloop_pair4(p, Abase, mat, nt, l, c0, c1, c2, c3, h0, h1, h2, h3);
  epi_unit(p, nt, lm, lg, prevb, dst, act, c0, c1, c2, c3, h0, h1, h2, h3);
}

__global__ __launch_bounds__(256) void k_scan(P p) {
  const int tid = threadIdx.x;
  const int l = tid & 63, lm = l & 15, lg = l >> 4;
  const int wid = (blockIdx.x << 2) | (tid >> 6); // 0..163
  const int bf = p.ctrl[0];
  int* cnt = p.ctrl + 1; int* gen = p.ctrl + 2;

  for (int t = 0; t < 128; ++t) {
    // L0: s0 from [x_t | h] @ W0 (tanh)
    if (wid < 54) {
      int nt = wid;
      f32x4 z = {0.f, 0.f, 0.f, 0.f};
      f32x4 c0 = z, c1 = z, c2 = z, c3 = z, h0 = z, h1 = z, h2 = z, h3 = z;
      const unsigned short* Ax = p.xbf + ((size_t)t * 64 + lm) * 864 + (size_t)lg * 8;
      kloop_pair4(p, Ax, 0, nt, l, c0, c1, c2, c3, h0, h1, h2, h3);
      const unsigned short* Ah = p.hbf + (size_t)lm * 864 + (size_t)lg * 8;
      kloop_pair4(p, Ah, 1, nt, l, c0, c1, c2, c3, h0, h1, h2, h3);
      epi_unit(p, nt, lm, lg, p.hf, 0, 2, c0, c1, c2, c3, h0, h1, h2, h3);
    }
    gbar(cnt, gen);

    // L1: s1 = sigmoid-step(s0 @ Ws[0])
    if (wid < 54) {
      const unsigned short* A0 = p.Sbf + ((size_t)0 * 64 + lm) * 864 + (size_t)lg * 8;
      thin_unit(p, wid, A0, 2, p.Sf + 0 * 64 * 850, 1, 0, lm, lg, l);
    }
    gbar(cnt, gen);

    // L2: s2,s3,s4 from s1 (relu, relu, identity)
    if (wid < 162) {
      int nt = wid % 54, mi = wid / 54;
      const unsigned short* A1 = p.Sbf + ((size_t)1 * 64 + lm) * 864 + (size_t)lg * 8;
      thin_unit(p, nt, A1, 3 + mi, p.Sf + 1 * 64 * 850, 2 + mi, (mi == 2) ? 3 : 1, lm, lg, l);
    }
    gbar(cnt, gen);

    // L3: s5 = tanh-step(s2 @ Ws[4]); s7 = tanh-step(s3 @ Ws[6])
    if (wid < 108) {
      int nt = wid % 54, mi = wid / 54;
      int src = mi ? 3 : 2;
      const unsigned short* As = p.Sbf + ((size_t)src * 64 + lm) * 864 + (size_t)lg * 8;
      thin_unit(p, nt, As, mi ? 8 : 6, p.Sf + (size_t)src * 64 * 850, mi ? 7 : 5, 2, lm, lg, l);
    }
    gbar(cnt, gen);

    // L4: s6 = sig-step(s5@Ws[5]); s8 = relu-step(s5@Ws[7]); fused out/mean/h
    if (wid < 54) {
      int nt = wid;
      f32x4 z = {0.f, 0.f, 0.f, 0.f};
      f32x4 cA0 = z, cA1 = z, cA2 = z, cA3 = z, hA0 = z, hA1 = z, hA2 = z, hA3 = z;
      f32x4 cB0 = z, cB1 = z, cB2 = z, cB3 = z, hB0 = z, hB1 = z, hB2 = z, hB3 = z;
      const unsigned short* A5 = p.Sbf + ((size_t)5 * 64 + lm) * 864 + (size_t)lg * 8;
      kloop_pair4(p, A5, 7, nt, l, cA0, cA1, cA2, cA3, hA0, hA1, hA2, hA3);
      kloop_pair4(p, A5, 9, nt, l, cB0, cB1, cB2, cB3, hB0, hB1, hB2, hB3);
      int n = nt * 16 + lm;
      if (n < 850) {
#define L4EPI(mt, cA, hA, cB, hB)                                              \
        { _Pragma("unroll") for (int i = 0; i < 4; ++i) {                      \
            int b = (mt) * 16 + lg * 4 + i;                                    \
            float s5v = p.Sf[(5 * 64 + b) * 850 + n];                          \
            float s6 = s5v + sigm((cA)[i]) * (sigm((hA)[i]) - s5v);            \
            float s8 = s5v + sigm((cB)[i]) * (fmaxf((hB)[i], 0.f) - s5v);      \
            float sum = p.Sf[(1 * 64 + b) * 850 + n]                           \
                      + p.Sf[(2 * 64 + b) * 850 + n]                           \
                      + p.Sf[(3 * 64 + b) * 850 + n]                           \
                      + p.Sf[(4 * 64 + b) * 850 + n]                           \
                      + s5v                                                    \
                      + p.Sf[(7 * 64 + b) * 850 + n] + s6 + s8;                \
            float outv = sum * 0.125f;                                         \
            float mk = ldf(p.masks, b * 128 + t, bf);                          \
            p.accr[b * 850 + n] += outv * mk;                                  \
            if (t == 127) stout(p.out, 2688 + (size_t)b * 850 + n, outv * mk, bf); \
            p.hf[b * 850 + n] = outv;                                          \
            p.hbf[(size_t)b * 864 + n] = f2bf(outv);                           \
          } }
        L4EPI(0, cA0, hA0, cB0, hB0)
        L4EPI(1, cA1, hA1, cB1, hB1)
        L4EPI(2, cA2, hA2, cB2, hB2)
        L4EPI(3, cA3, hA3, cB3, hB3)
#undef L4EPI
      }
    }
    gbar(cnt, gen);
  }

  // decoder + log_softmax: one wave per batch row
  if (wid < 64) {
    int b = wid;
    float myval = 0.0f;
    for (int c = 0; c < 42; ++c) {
      float part = 0.0f;
      for (int d = l; d < 850; d += 64)
        part += p.accr[b * 850 + d] * ldf(p.dec_W, c * 850 + d, bf);
      for (int off = 32; off > 0; off >>= 1) part += __shfl_xor(part, off);
      if (l == c) myval = part * (1.0f / 128.0f) + ldf(p.dec_b, c, bf);
    }
    float mx = (l < 42) ? myval : -INFINITY;
    for (int off = 32; off > 0; off >>= 1) mx = fmaxf(mx, __shfl_xor(mx, off));
    float ex = (l < 42) ? expf(myval - mx) : 0.0f;
    float sm = ex;
    for (int off = 32; off > 0; off >>= 1) sm += __shfl_xor(sm, off);
    if (l < 42) stout(p.out, (size_t)b * 42 + l, myval - mx - logf(sm), bf);
  }
}

// ---------------- launch ----------------

extern "C" void kernel_launch(void* const* d_in, const int* in_sizes, int n_in,
                              void* d_out, int out_size, void* d_ws, size_t ws_size,
                              hipStream_t stream) {
  (void)in_sizes; (void)n_in; (void)out_size;
  P p;
  p.tokens = (const int*)d_in[0];
  p.masks  = d_in[1];
  p.pos    = (const int*)d_in[2];
  p.ner    = (const int*)d_in[3];
  p.hidden = d_in[4];
  p.enc_W  = d_in[5];
  p.ner_W  = d_in[6];
  p.pos_W  = d_in[7];
  p.agg_W  = d_in[8];
  p.agg_b  = d_in[9];
  p.W0     = d_in[10];
  p.Ws     = d_in[11];
  p.dec_W  = d_in[12];
  p.dec_b  = d_in[13];
  p.out    = d_out;

  unsigned char* ws = (unsigned char*)d_ws;
  p.ctrl = (int*)ws;
  unsigned char* R0 = ws + 256;
  // R0 region (29,859,840 B): holds PK_agg+comb during phase A, then PK_rec.
  p.PK_agg = (unsigned short*)R0;
  p.comb   = (unsigned short*)(R0 + 1603584);
  p.PK_rec = (unsigned short*)R0;
  unsigned char* q = R0 + 29859840;
  p.xbf  = (unsigned short*)q; q += 14155776;
  p.Sbf  = (unsigned short*)q; q += 995328;
  p.hbf  = (unsigned short*)q; q += 110592;
  p.Sf   = (float*)q;          q += 1958400;
  p.hf   = (float*)q;          q += 217600;
  p.accr = (float*)q;          q += 217600;

  size_t need = (size_t)(q - ws);
  if (ws_size < need) { // sentinel: workspace too small (absmax ~2004 or ~500)
    hipLaunchKernelGGL(k_diag, dim3(1), dim3(64), 0, stream, p);
    return;
  }

  hipLaunchKernelGGL(k_detect,   dim3(1),    dim3(64),  0, stream, p);
  hipLaunchKernelGGL(k_init,     dim3(256),  dim3(256), 0, stream, p);
  hipLaunchKernelGGL(k_pack_agg, dim3(512),  dim3(256), 0, stream, p);
  hipLaunchKernelGGL(k_comb,     dim3(4096), dim3(256), 0, stream, p);
  hipLaunchKernelGGL(k_phaseA,   dim3(256),  dim3(256), 0, stream, p);
  hipLaunchKernelGGL(k_pack_rec, dim3(4096), dim3(256), 0, stream, p);
  hipLaunchKernelGGL(k_scan,     dim3(NBLK), dim3(256), 0, stream, p);
}

// Round 3
// 15816.595 us; speedup vs baseline: 2.9096x; 2.9096x over previous
//
#include <hip/hip_runtime.h>
#include <math.h>

typedef float f32x4 __attribute__((ext_vector_type(4)));
typedef short s16x8 __attribute__((ext_vector_type(8)));
typedef unsigned short u16;

#define MFMA_BF16(a,b,c) __builtin_amdgcn_mfma_f32_16x16x32_bf16((a),(b),(c),0,0,0)
#define NBLK 243
#define PAIR_U16 13824   // one half-matrix tile: 27 kb * 512
#define SLOT_U16 27648   // c+h halves
#define LDS_BYTES 110592 // 2 slots * 27648 u16 * 2B

// Geometry: D=850 pad 864 (27 kb of 32), 54 n-tiles of 16. Phase A: K=910 pad 928.
// PK_rec[mat][half][nt][kb][lane][8]; mat: 0=W0 lo, 1=W0 hi, 2+i=Ws[i].
// Scan: 243 persistent blocks, all weights (mats 1..9) resident in LDS:
//   blk 0..53:    slot0 = mat1[nt=blk]      (L0), slot1 = mat3[nt] (L2, s2)
//   blk 54..107:  slot0 = mat2[nt=blk-54]   (L1), slot1 = mat4[nt] (L2, s3)
//   blk 108..161: slot0 = mat6[nt=blk-108]  (L3, s5), slot1 = mat5[nt] (L2, s4)
//   blk 162..215: slot0 = mat7[nt=blk-162]  (L4, s6), slot1 = mat9[nt] (L4, s8)
//   blk 216..242: slot0/1 = mat8[2i],[2i+1] (L3, s7)
// mat0 (x @ W0_lo) is read from global each timestep (LLC-hot, 3 MB).

struct P {
  const int* tokens; const void* masks; const int* pos; const int* ner;
  const void* hidden;
  const void* enc_W; const void* ner_W; const void* pos_W;
  const void* agg_W; const void* agg_b;
  const void* W0; const void* Ws;
  const void* dec_W; const void* dec_b;
  void* out;
  unsigned short* PK_agg; unsigned short* PK_rec; unsigned short* comb;
  unsigned short* xbf; unsigned short* Sbf; unsigned short* hbf;
  float* Sf; float* hf; float* accr;
  int* ctrl; // [0]=bf16 flag, [64]=gen, [128]=root cnt, [256+g*64]=group cnt
};

__device__ __forceinline__ unsigned short f2bf(float f) {
  union { float f; unsigned u; } v; v.f = f;
  return (unsigned short)((v.u + 0x7FFFu + ((v.u >> 16) & 1u)) >> 16);
}
__device__ __forceinline__ float ldf(const void* q, size_t i, int bf) {
  if (bf) { union { unsigned x; float f; } v;
            v.x = (unsigned)((const unsigned short*)q)[i] << 16; return v.f; }
  return ((const float*)q)[i];
}
__device__ __forceinline__ void stout(void* o, size_t i, float v, int bf) {
  if (bf) ((unsigned short*)o)[i] = f2bf(v);
  else    ((float*)o)[i] = v;
}
__device__ __forceinline__ float sigm(float x) { return 1.0f / (1.0f + expf(-x)); }
__device__ __forceinline__ float actf(int a, float x) {
  if (a == 0) return sigm(x);
  if (a == 1) return fmaxf(x, 0.0f);
  if (a == 2) return tanhf(x);
  return x;
}

// Tree grid barrier: 9 groups x 27 blocks. Relaxed spin (no per-poll L2 inv);
// release fence on arrival, acquire fence on exit (all threads).
__device__ __forceinline__ void gbar(int* ctrl) {
  __syncthreads();
  if (threadIdx.x == 0) {
    int* gen = ctrl + 64;
    int g = __hip_atomic_load(gen, __ATOMIC_RELAXED, __HIP_MEMORY_SCOPE_AGENT);
    __builtin_amdgcn_fence(__ATOMIC_RELEASE, "agent"); // flush this block's state writes
    int* gc = ctrl + 256 + (blockIdx.x / 27) * 64;
    int a = __hip_atomic_fetch_add(gc, 1, __ATOMIC_RELAXED, __HIP_MEMORY_SCOPE_AGENT);
    bool iam_last = false;
    if (a == 26) {
      __hip_atomic_store(gc, 0, __ATOMIC_RELAXED, __HIP_MEMORY_SCOPE_AGENT);
      int r = __hip_atomic_fetch_add(ctrl + 128, 1, __ATOMIC_ACQ_REL, __HIP_MEMORY_SCOPE_AGENT);
      if (r == 8) {
        __hip_atomic_store(ctrl + 128, 0, __ATOMIC_RELAXED, __HIP_MEMORY_SCOPE_AGENT);
        __hip_atomic_store(gen, g + 1, __ATOMIC_RELEASE, __HIP_MEMORY_SCOPE_AGENT);
        iam_last = true;
      }
    }
    if (!iam_last) {
      int spins = 0;
      while (__hip_atomic_load(gen, __ATOMIC_RELAXED, __HIP_MEMORY_SCOPE_AGENT) == g) {
        __builtin_amdgcn_s_sleep(1);
        if (++spins > 100000) break; // bounded diagnostic escape
      }
    }
  }
  __syncthreads();
  __builtin_amdgcn_fence(__ATOMIC_ACQUIRE, "agent"); // invalidate stale cached state
}

// ---------------- prep kernels (proven in round 2) ----------------

__global__ void k_detect(P p) {
  for (int j = threadIdx.x; j < 1024; j += 64) p.ctrl[j] = 0;
  __syncthreads();
  if (threadIdx.x == 0) {
    const unsigned short* u = (const unsigned short*)p.W0;
    int good = 0;
    for (int i = 0; i < 256; ++i) {
      int e = (u[i] >> 7) & 0xFF;
      if (e >= 90 && e <= 126) ++good;
    }
    p.ctrl[0] = (good >= 192) ? 1 : 0;
  }
}

__global__ __launch_bounds__(256) void k_init(P p) {
  const int bf = p.ctrl[0];
  const int total = 54400 + 896 + 8064 + 114688;
  for (int e = blockIdx.x * blockDim.x + threadIdx.x; e < total;
       e += gridDim.x * blockDim.x) {
    if (e < 54400) {
      int b = e / 850, n = e % 850;
      float h0 = ldf(p.hidden, e, bf);
      p.hf[e] = h0; p.accr[e] = 0.0f;
      p.hbf[(size_t)b * 864 + n] = f2bf(h0);
    } else if (e < 54400 + 896) {
      int e2 = e - 54400; int b = e2 / 14, n = 850 + e2 % 14;
      p.hbf[(size_t)b * 864 + n] = 0;
    } else if (e < 54400 + 896 + 8064) {
      int e3 = e - 54400 - 896; int s = e3 / 896, r = e3 % 896;
      int b = r / 14, n = 850 + r % 14;
      p.Sbf[((size_t)s * 64 + b) * 864 + n] = 0;
    } else {
      int e4 = e - 54400 - 896 - 8064; int t = e4 / 896, r = e4 % 896;
      int b = r / 14, n = 850 + r % 14;
      p.xbf[((size_t)t * 64 + b) * 864 + n] = 0;
    }
  }
}

__global__ __launch_bounds__(256) void k_pack_agg(P p) {
  const int bf = p.ctrl[0];
  const long total = 801792L;
  for (long e = (long)blockIdx.x * blockDim.x + threadIdx.x; e < total;
       e += (long)gridDim.x * blockDim.x) {
    int j = (int)(e & 7), l = (int)((e >> 3) & 63);
    long q9 = e >> 9;
    int kb = (int)(q9 % 29), nt = (int)(q9 / 29);
    int n = nt * 16 + (l & 15);
    int k = kb * 32 + ((l >> 4) << 3) + j;
    float v = 0.0f;
    if (n < 850 && k < 910) v = ldf(p.agg_W, (size_t)n * 910 + k, bf);
    p.PK_agg[e] = f2bf(v);
  }
}

__global__ __launch_bounds__(256) void k_comb(P p) {
  const int bf = p.ctrl[0];
  const long total = 7602176L;
  for (long e = (long)blockIdx.x * blockDim.x + threadIdx.x; e < total;
       e += (long)gridDim.x * blockDim.x) {
    int k = (int)(e % 928);
    int r = (int)(e / 928);
    int t = r >> 6, b = r & 63;
    float v = 0.0f;
    if (k < 850)      { int tok = p.tokens[b * 128 + t]; v = ldf(p.enc_W, (size_t)tok * 850 + k, bf); }
    else if (k < 880) { int nv = p.ner[b * 128 + t];     v = ldf(p.ner_W, nv * 30 + (k - 850), bf); }
    else if (k < 910) { int pv = p.pos[b * 128 + t];     v = ldf(p.pos_W, pv * 30 + (k - 880), bf); }
    p.comb[e] = f2bf(v);
  }
}

__global__ __launch_bounds__(256) void k_pack_rec(P p) {
  const int bf = p.ctrl[0];
  const long total = 14929920L;
  for (long e = (long)blockIdx.x * blockDim.x + threadIdx.x; e < total;
       e += (long)gridDim.x * blockDim.x) {
    int j = (int)(e & 7), l = (int)((e >> 3) & 63);
    long q9 = e >> 9;
    int kb = (int)(q9 % 27);
    long q = q9 / 27;
    int nt = (int)(q % 54);
    int mh = (int)(q / 54);
    int half = mh & 1, mat = mh >> 1;
    int nl = nt * 16 + (l & 15);
    int col = half ? nl + 850 : nl;
    int k = kb * 32 + ((l >> 4) << 3) + j;
    float v = 0.0f;
    if (nl < 850 && k < 850) {
      if (mat == 0)      v = ldf(p.W0, (size_t)k * 1700 + col, bf);
      else if (mat == 1) v = ldf(p.W0, (size_t)(k + 850) * 1700 + col, bf);
      else               v = ldf(p.Ws, (size_t)(mat - 2) * 850 * 1700 + (size_t)k * 1700 + col, bf);
    }
    p.PK_rec[e] = f2bf(v);
  }
}

__global__ void k_diag(P p) {
  if (blockIdx.x == 0 && threadIdx.x == 0)
    for (int i = 0; i < 64; ++i) ((float*)p.out)[i] = 2000.0f;
}

__global__ __launch_bounds__(256) void k_phaseA(P p) {
  const int tid = threadIdx.x;
  const int l = tid & 63, lm = l & 15, lg = l >> 4;
  const int wid = (blockIdx.x << 2) | (tid >> 6);
  const int bf = p.ctrl[0];
  for (int u = wid; u < 512 * 54; u += 1024) {
    int mt = u / 54, nt = u - mt * 54;
    int r0 = mt << 4;
    f32x4 acc = {0.f, 0.f, 0.f, 0.f};
    const unsigned short* Arow = p.comb + (size_t)(r0 + lm) * 928 + (size_t)lg * 8;
    const unsigned short* Bp = p.PK_agg + (size_t)nt * 29 * 512 + (size_t)l * 8;
    for (int kb = 0; kb < 29; ++kb) {
      s16x8 a = *(const s16x8*)(Arow + (size_t)kb * 32);
      s16x8 b = *(const s16x8*)(Bp + (size_t)kb * 512);
      acc = MFMA_BF16(a, b, acc);
    }
    int n = nt * 16 + lm;
    if (n < 850) {
      float bias = ldf(p.agg_b, n, bf);
#pragma unroll
      for (int i = 0; i < 4; ++i) {
        int r = r0 + lg * 4 + i;
        p.xbf[(size_t)r * 864 + n] = f2bf(acc[i] + bias);
      }
    }
  }
}

// ---------------- scan (persistent, LDS-resident weights) ----------------

__device__ __forceinline__ void unit_lds(
    const u16* lds, const u16* Asrc, int mt, int l, f32x4& cc, f32x4& hh) {
  int lm = l & 15, lg = l >> 4;
  const u16* A  = Asrc + (size_t)(mt * 16 + lm) * 864 + (size_t)lg * 8;
  const u16* Bc = lds + l * 8;
  const u16* Bh = lds + PAIR_U16 + l * 8;
  for (int kb = 0; kb < 27; ++kb) {
    s16x8 a  = *(const s16x8*)(A + (size_t)kb * 32);
    s16x8 bc = *(const s16x8*)(Bc + (size_t)kb * 512);
    s16x8 bh = *(const s16x8*)(Bh + (size_t)kb * 512);
    cc = MFMA_BF16(a, bc, cc);
    hh = MFMA_BF16(a, bh, hh);
  }
}

__device__ __forceinline__ void epi(
    const P& p, int nt, int mt, int l, const float* prevb, int dst, int act,
    f32x4 c, f32x4 h) {
  int lm = l & 15, lg = l >> 4, n = nt * 16 + lm;
  if (n >= 850) return;
#pragma unroll
  for (int i = 0; i < 4; ++i) {
    int b = mt * 16 + lg * 4 + i;
    float prev = prevb[b * 850 + n];
    float s = prev + sigm(c[i]) * (actf(act, h[i]) - prev);
    p.Sf[((size_t)dst * 64 + b) * 850 + n] = s;
    p.Sbf[((size_t)dst * 64 + b) * 864 + n] = f2bf(s);
  }
}

__global__ __launch_bounds__(256) void k_scan(P p) {
  extern __shared__ u16 ldsw[];
  const int tid = threadIdx.x;
  const int l = tid & 63, lm = l & 15, lg = l >> 4, mt = tid >> 6;
  const int blk = blockIdx.x;
  const int bf = p.ctrl[0];

  int role, matA, ntA, matB, ntB;
  if (blk < 54)       { role = 0; matA = 1; ntA = blk;       matB = 3; ntB = ntA; }
  else if (blk < 108) { role = 1; matA = 2; ntA = blk - 54;  matB = 4; ntB = ntA; }
  else if (blk < 162) { role = 2; matA = 6; ntA = blk - 108; matB = 5; ntB = ntA; }
  else if (blk < 216) { role = 3; matA = 7; ntA = blk - 162; matB = 9; ntB = ntA; }
  else                { role = 4; matA = 8; ntA = 2 * (blk - 216); matB = 8; ntB = ntA + 1; }

  // stage this block's two weight pairs into LDS (persistent all 128 steps)
  for (int s = 0; s < 2; ++s) {
    int m = s ? matB : matA, nt = s ? ntB : ntA;
    for (int h = 0; h < 2; ++h) {
      const uint4* src = (const uint4*)(p.PK_rec + ((size_t)(m * 2 + h) * 54 + nt) * PAIR_U16);
      uint4* dst = (uint4*)(ldsw + s * SLOT_U16 + h * PAIR_U16);
      for (int i = tid; i < PAIR_U16 / 8; i += 256) dst[i] = src[i];
    }
  }
  __syncthreads();

  const f32x4 z = {0.f, 0.f, 0.f, 0.f};
  for (int t = 0; t < 128; ++t) {
    // L0: s0 = h + sig(c)*(tanh(hh)-h); c|hh = x_t@W0_lo (global B) + h@W0_hi (LDS)
    if (role == 0) {
      f32x4 cc = z, hh = z;
      const u16* B0 = p.PK_rec + (size_t)(0 * 54 + ntA) * PAIR_U16 + l * 8;
      const u16* B1 = p.PK_rec + (size_t)(1 * 54 + ntA) * PAIR_U16 + l * 8;
      const u16* Ax = p.xbf + ((size_t)t * 64 + mt * 16 + lm) * 864 + (size_t)lg * 8;
      for (int kb = 0; kb < 27; ++kb) {
        s16x8 a = *(const s16x8*)(Ax + (size_t)kb * 32);
        cc = MFMA_BF16(a, *(const s16x8*)(B0 + (size_t)kb * 512), cc);
        hh = MFMA_BF16(a, *(const s16x8*)(B1 + (size_t)kb * 512), hh);
      }
      unit_lds(ldsw, p.hbf, mt, l, cc, hh);
      epi(p, ntA, mt, l, p.hf, 0, 2, cc, hh);
    }
    gbar(p.ctrl);

    // L1: s1 = sigmoid-step(s0 @ Ws[0])
    if (role == 1) {
      f32x4 cc = z, hh = z;
      unit_lds(ldsw, p.Sbf + (size_t)0 * 64 * 864, mt, l, cc, hh);
      epi(p, ntA, mt, l, p.Sf + 0 * 64 * 850, 1, 0, cc, hh);
    }
    gbar(p.ctrl);

    // L2: s2/s3/s4 from s1 (relu/relu/identity) — slot1 of roles 0/1/2
    if (role <= 2) {
      f32x4 cc = z, hh = z;
      unit_lds(ldsw + SLOT_U16, p.Sbf + (size_t)1 * 64 * 864, mt, l, cc, hh);
      int dst = (role == 0) ? 2 : (role == 1) ? 3 : 4;
      int act = (role == 2) ? 3 : 1;
      epi(p, ntB, mt, l, p.Sf + 1 * 64 * 850, dst, act, cc, hh);
    }
    gbar(p.ctrl);

    // L3: s5 = tanh-step(s2@Ws[4]) [role2 slot0]; s7 = tanh-step(s3@Ws[6]) [role4 both]
    if (role == 2) {
      f32x4 cc = z, hh = z;
      unit_lds(ldsw, p.Sbf + (size_t)2 * 64 * 864, mt, l, cc, hh);
      epi(p, ntA, mt, l, p.Sf + 2 * 64 * 850, 5, 2, cc, hh);
    } else if (role == 4) {
      f32x4 cc = z, hh = z;
      unit_lds(ldsw, p.Sbf + (size_t)3 * 64 * 864, mt, l, cc, hh);
      epi(p, ntA, mt, l, p.Sf + 3 * 64 * 850, 7, 2, cc, hh);
      f32x4 c2 = z, h2 = z;
      unit_lds(ldsw + SLOT_U16, p.Sbf + (size_t)3 * 64 * 864, mt, l, c2, h2);
      epi(p, ntB, mt, l, p.Sf + 3 * 64 * 850, 7, 2, c2, h2);
    }
    gbar(p.ctrl);

    // L4: s6 = sig-step(s5@Ws[5]); s8 = relu-step(s5@Ws[7]); fused out/mean/h
    if (role == 3) {
      f32x4 cA = z, hA = z, cB = z, hB = z;
      unit_lds(ldsw, p.Sbf + (size_t)5 * 64 * 864, mt, l, cA, hA);
      unit_lds(ldsw + SLOT_U16, p.Sbf + (size_t)5 * 64 * 864, mt, l, cB, hB);
      int n = ntA * 16 + lm;
      if (n < 850) {
#pragma unroll
        for (int i = 0; i < 4; ++i) {
          int b = mt * 16 + lg * 4 + i;
          float s5v = p.Sf[(5 * 64 + b) * 850 + n];
          float s6 = s5v + sigm(cA[i]) * (sigm(hA[i]) - s5v);
          float s8 = s5v + sigm(cB[i]) * (fmaxf(hB[i], 0.f) - s5v);
          float sum = p.Sf[(1 * 64 + b) * 850 + n]
                    + p.Sf[(2 * 64 + b) * 850 + n]
                    + p.Sf[(3 * 64 + b) * 850 + n]
                    + p.Sf[(4 * 64 + b) * 850 + n]
                    + s5v
                    + p.Sf[(7 * 64 + b) * 850 + n] + s6 + s8;
          float outv = sum * 0.125f;
          float mk = ldf(p.masks, b * 128 + t, bf);
          p.accr[b * 850 + n] += outv * mk;
          if (t == 127) stout(p.out, 2688 + (size_t)b * 850 + n, outv * mk, bf);
          p.hf[b * 850 + n] = outv;
          p.hbf[(size_t)b * 864 + n] = f2bf(outv);
        }
      }
    }
    gbar(p.ctrl);
  }

  // decoder + log_softmax: one wave per batch row (blocks 0..15)
  int wid = blk * 4 + mt;
  if (wid < 64) {
    int b = wid;
    float myval = 0.0f;
    for (int c = 0; c < 42; ++c) {
      float part = 0.0f;
      for (int d = l; d < 850; d += 64)
        part += p.accr[b * 850 + d] * ldf(p.dec_W, c * 850 + d, bf);
      for (int off = 32; off > 0; off >>= 1) part += __shfl_xor(part, off);
      if (l == c) myval = part * (1.0f / 128.0f) + ldf(p.dec_b, c, bf);
    }
    float mx = (l < 42) ? myval : -INFINITY;
    for (int off = 32; off > 0; off >>= 1) mx = fmaxf(mx, __shfl_xor(mx, off));
    float ex = (l < 42) ? expf(myval - mx) : 0.0f;
    float sm = ex;
    for (int off = 32; off > 0; off >>= 1) sm += __shfl_xor(sm, off);
    if (l < 42) stout(p.out, (size_t)b * 42 + l, myval - mx - logf(sm), bf);
  }
}

// ---------------- launch ----------------

extern "C" void kernel_launch(void* const* d_in, const int* in_sizes, int n_in,
                              void* d_out, int out_size, void* d_ws, size_t ws_size,
                              hipStream_t stream) {
  (void)in_sizes; (void)n_in; (void)out_size;
  P p;
  p.tokens = (const int*)d_in[0];
  p.masks  = d_in[1];
  p.pos    = (const int*)d_in[2];
  p.ner    = (const int*)d_in[3];
  p.hidden = d_in[4];
  p.enc_W  = d_in[5];
  p.ner_W  = d_in[6];
  p.pos_W  = d_in[7];
  p.agg_W  = d_in[8];
  p.agg_b  = d_in[9];
  p.W0     = d_in[10];
  p.Ws     = d_in[11];
  p.dec_W  = d_in[12];
  p.dec_b  = d_in[13];
  p.out    = d_out;

  unsigned char* ws = (unsigned char*)d_ws;
  p.ctrl = (int*)ws;
  unsigned char* R0 = ws + 4096;
  // R0 (29,859,840 B): PK_agg+comb during phase A, then PK_rec.
  p.PK_agg = (unsigned short*)R0;
  p.comb   = (unsigned short*)(R0 + 1603584);
  p.PK_rec = (unsigned short*)R0;
  unsigned char* q = R0 + 29859840;
  p.xbf  = (unsigned short*)q; q += 14155776;
  p.Sbf  = (unsigned short*)q; q += 995328;
  p.hbf  = (unsigned short*)q; q += 110592;
  p.Sf   = (float*)q;          q += 1958400;
  p.hf   = (float*)q;          q += 217600;
  p.accr = (float*)q;          q += 217600;

  size_t need = (size_t)(q - ws);
  if (ws_size < need) {
    hipLaunchKernelGGL(k_diag, dim3(1), dim3(64), 0, stream, p);
    return;
  }

  static int lds_attr_set = 0;
  if (!lds_attr_set) { // host-side attribute, graph-capture safe, idempotent
    (void)hipFuncSetAttribute((const void*)k_scan,
                              hipFuncAttributeMaxDynamicSharedMemorySize, LDS_BYTES);
    lds_attr_set = 1;
  }

  hipLaunchKernelGGL(k_detect,   dim3(1),    dim3(64),  0, stream, p);
  hipLaunchKernelGGL(k_init,     dim3(256),  dim3(256), 0, stream, p);
  hipLaunchKernelGGL(k_pack_agg, dim3(512),  dim3(256), 0, stream, p);
  hipLaunchKernelGGL(k_comb,     dim3(4096), dim3(256), 0, stream, p);
  hipLaunchKernelGGL(k_phaseA,   dim3(256),  dim3(256), 0, stream, p);
  hipLaunchKernelGGL(k_pack_rec, dim3(4096), dim3(256), 0, stream, p);
  hipLaunchKernelGGL(k_scan,     dim3(NBLK), dim3(256), LDS_BYTES, stream, p);
}

// Round 4
// 10529.705 us; speedup vs baseline: 4.3705x; 1.5021x over previous
//
#include <hip/hip_runtime.h>
#include <math.h>

typedef float f32x4 __attribute__((ext_vector_type(4)));
typedef short s16x8 __attribute__((ext_vector_type(8)));
typedef unsigned short u16;

#define MFMA_BF16(a,b,c) __builtin_amdgcn_mfma_f32_16x16x32_bf16((a),(b),(c),0,0,0)
#define NBLK 243
#define MASTER 242
#define PAIR_U16 13824   // one half-matrix tile: 27 kb * 512
#define SLOT_U16 27648   // c+h halves
#define LDS_BYTES 110592 // 2 slots * 27648 u16 * 2B

// Geometry: D=850 pad 864 (27 kb of 32), 54 n-tiles of 16. Phase A: K=910 pad 928.
// PK_rec[mat][half][nt][kb][lane][8]; mat: 0=W0 lo, 1=W0 hi, 2+i=Ws[i].
// Scan: 243 persistent blocks, weights (mats 1..9) LDS-resident.
// Cross-block state (Sf/Sbf/hf/hbf) uses relaxed agent atomics (sc1, LLC-coherent)
// -> barrier needs NO fences (no buffer_inv / wbl2); L2 keeps read-only data hot.
// Barrier: arrive-flag array + master poll + per-block gen cachelines.

struct P {
  const int* tokens; const void* masks; const int* pos; const int* ner;
  const void* hidden;
  const void* enc_W; const void* ner_W; const void* pos_W;
  const void* agg_W; const void* agg_b;
  const void* W0; const void* Ws;
  const void* dec_W; const void* dec_b;
  void* out;
  unsigned short* PK_agg; unsigned short* PK_rec; unsigned short* comb;
  unsigned short* xbf; unsigned short* Sbf; unsigned short* hbf;
  float* Sf; float* hf; float* accr;
  int* ctrl; // [0]=bf16 flag; [256+i]=arrive[i]; [1024+i*16]=gen[i]
};

__device__ __forceinline__ unsigned short f2bf(float f) {
  union { float f; unsigned u; } v; v.f = f;
  return (unsigned short)((v.u + 0x7FFFu + ((v.u >> 16) & 1u)) >> 16);
}
__device__ __forceinline__ float ldf(const void* q, size_t i, int bf) {
  if (bf) { union { unsigned x; float f; } v;
            v.x = (unsigned)((const unsigned short*)q)[i] << 16; return v.f; }
  return ((const float*)q)[i];
}
__device__ __forceinline__ void stout(void* o, size_t i, float v, int bf) {
  if (bf) ((unsigned short*)o)[i] = f2bf(v);
  else    ((float*)o)[i] = v;
}
__device__ __forceinline__ float sigm(float x) { return 1.0f / (1.0f + expf(-x)); }
__device__ __forceinline__ float actf(int a, float x) {
  if (a == 0) return sigm(x);
  if (a == 1) return fmaxf(x, 0.0f);
  if (a == 2) return tanhf(x);
  return x;
}

// ---- LLC-coherent (sc1) accessors: relaxed agent-scope atomics ----
__device__ __forceinline__ s16x8 ldA16(const u16* p) {
  unsigned long long lo = __hip_atomic_load((const unsigned long long*)p,
      __ATOMIC_RELAXED, __HIP_MEMORY_SCOPE_AGENT);
  unsigned long long hi = __hip_atomic_load((const unsigned long long*)(p + 4),
      __ATOMIC_RELAXED, __HIP_MEMORY_SCOPE_AGENT);
  union { unsigned long long q[2]; s16x8 v; } u; u.q[0] = lo; u.q[1] = hi;
  return u.v;
}
__device__ __forceinline__ float ldc_f32(const float* p) {
  unsigned x = __hip_atomic_load((const unsigned*)p, __ATOMIC_RELAXED,
                                 __HIP_MEMORY_SCOPE_AGENT);
  union { unsigned u; float f; } v; v.u = x; return v.f;
}
__device__ __forceinline__ void stc_f32(float* p, float f) {
  union { float f; unsigned u; } v; v.f = f;
  __hip_atomic_store((unsigned*)p, v.u, __ATOMIC_RELAXED, __HIP_MEMORY_SCOPE_AGENT);
}
__device__ __forceinline__ void stc_u16(u16* p, u16 x) {
  __hip_atomic_store(p, x, __ATOMIC_RELAXED, __HIP_MEMORY_SCOPE_AGENT);
}
__device__ __forceinline__ void stc_i32(int* p, int x) {
  __hip_atomic_store(p, x, __ATOMIC_RELAXED, __HIP_MEMORY_SCOPE_AGENT);
}
__device__ __forceinline__ int ldc_i32(const int* p) {
  return __hip_atomic_load(p, __ATOMIC_RELAXED, __HIP_MEMORY_SCOPE_AGENT);
}

// Fence-free grid barrier. Entry __syncthreads drains each wave's vmcnt
// (compiler emits s_waitcnt vmcnt(0) before s_barrier) so all sc1 state
// stores are at the LLC before the arrive flag is stored.
__device__ __forceinline__ void gbar2(int* ctrl, int epoch) {
  __syncthreads();
  const int tid = threadIdx.x;
  if (blockIdx.x == MASTER) {
    if (tid == 0) stc_i32(ctrl + 256 + MASTER, epoch);
    for (;;) {
      int ok = 1;
      if (tid < NBLK) ok = (ldc_i32(ctrl + 256 + tid) >= epoch);
      if (__syncthreads_count(ok) == 256) break;
      __builtin_amdgcn_s_sleep(1);
    }
    if (tid < NBLK) stc_i32(ctrl + 1024 + tid * 16, epoch);
    __syncthreads();
  } else {
    if (tid == 0) {
      stc_i32(ctrl + 256 + blockIdx.x, epoch);
      int spins = 0;
      while (ldc_i32(ctrl + 1024 + blockIdx.x * 16) < epoch) {
        __builtin_amdgcn_s_sleep(2);
        if (++spins > 3000000) break; // bounded diagnostic escape
      }
    }
    __syncthreads();
  }
}

// ---------------- prep kernels (proven) ----------------

__global__ void k_detect(P p) {
  for (int j = threadIdx.x; j < 8192; j += 64) p.ctrl[j] = 0;
  __syncthreads();
  if (threadIdx.x == 0) {
    const unsigned short* u = (const unsigned short*)p.W0;
    int good = 0;
    for (int i = 0; i < 256; ++i) {
      int e = (u[i] >> 7) & 0xFF;
      if (e >= 90 && e <= 126) ++good;
    }
    p.ctrl[0] = (good >= 192) ? 1 : 0;
  }
}

__global__ __launch_bounds__(256) void k_init(P p) {
  const int bf = p.ctrl[0];
  const int total = 54400 + 896 + 8064 + 114688;
  for (int e = blockIdx.x * blockDim.x + threadIdx.x; e < total;
       e += gridDim.x * blockDim.x) {
    if (e < 54400) {
      int b = e / 850, n = e % 850;
      float h0 = ldf(p.hidden, e, bf);
      p.hf[e] = h0;
      p.hbf[(size_t)b * 864 + n] = f2bf(h0);
    } else if (e < 54400 + 896) {
      int e2 = e - 54400; int b = e2 / 14, n = 850 + e2 % 14;
      p.hbf[(size_t)b * 864 + n] = 0;
    } else if (e < 54400 + 896 + 8064) {
      int e3 = e - 54400 - 896; int s = e3 / 896, r = e3 % 896;
      int b = r / 14, n = 850 + r % 14;
      p.Sbf[((size_t)s * 64 + b) * 864 + n] = 0;
    } else {
      int e4 = e - 54400 - 896 - 8064; int t = e4 / 896, r = e4 % 896;
      int b = r / 14, n = 850 + r % 14;
      p.xbf[((size_t)t * 64 + b) * 864 + n] = 0;
    }
  }
}

__global__ __launch_bounds__(256) void k_pack_agg(P p) {
  const int bf = p.ctrl[0];
  const long total = 801792L;
  for (long e = (long)blockIdx.x * blockDim.x + threadIdx.x; e < total;
       e += (long)gridDim.x * blockDim.x) {
    int j = (int)(e & 7), l = (int)((e >> 3) & 63);
    long q9 = e >> 9;
    int kb = (int)(q9 % 29), nt = (int)(q9 / 29);
    int n = nt * 16 + (l & 15);
    int k = kb * 32 + ((l >> 4) << 3) + j;
    float v = 0.0f;
    if (n < 850 && k < 910) v = ldf(p.agg_W, (size_t)n * 910 + k, bf);
    p.PK_agg[e] = f2bf(v);
  }
}

__global__ __launch_bounds__(256) void k_comb(P p) {
  const int bf = p.ctrl[0];
  const long total = 7602176L;
  for (long e = (long)blockIdx.x * blockDim.x + threadIdx.x; e < total;
       e += (long)gridDim.x * blockDim.x) {
    int k = (int)(e % 928);
    int r = (int)(e / 928);
    int t = r >> 6, b = r & 63;
    float v = 0.0f;
    if (k < 850)      { int tok = p.tokens[b * 128 + t]; v = ldf(p.enc_W, (size_t)tok * 850 + k, bf); }
    else if (k < 880) { int nv = p.ner[b * 128 + t];     v = ldf(p.ner_W, nv * 30 + (k - 850), bf); }
    else if (k < 910) { int pv = p.pos[b * 128 + t];     v = ldf(p.pos_W, pv * 30 + (k - 880), bf); }
    p.comb[e] = f2bf(v);
  }
}

__global__ __launch_bounds__(256) void k_pack_rec(P p) {
  const int bf = p.ctrl[0];
  const long total = 14929920L;
  for (long e = (long)blockIdx.x * blockDim.x + threadIdx.x; e < total;
       e += (long)gridDim.x * blockDim.x) {
    int j = (int)(e & 7), l = (int)((e >> 3) & 63);
    long q9 = e >> 9;
    int kb = (int)(q9 % 27);
    long q = q9 / 27;
    int nt = (int)(q % 54);
    int mh = (int)(q / 54);
    int half = mh & 1, mat = mh >> 1;
    int nl = nt * 16 + (l & 15);
    int col = half ? nl + 850 : nl;
    int k = kb * 32 + ((l >> 4) << 3) + j;
    float v = 0.0f;
    if (nl < 850 && k < 850) {
      if (mat == 0)      v = ldf(p.W0, (size_t)k * 1700 + col, bf);
      else if (mat == 1) v = ldf(p.W0, (size_t)(k + 850) * 1700 + col, bf);
      else               v = ldf(p.Ws, (size_t)(mat - 2) * 850 * 1700 + (size_t)k * 1700 + col, bf);
    }
    p.PK_rec[e] = f2bf(v);
  }
}

__global__ void k_diag(P p) {
  if (blockIdx.x == 0 && threadIdx.x == 0)
    for (int i = 0; i < 64; ++i) ((float*)p.out)[i] = 2000.0f;
}

__global__ __launch_bounds__(256) void k_phaseA(P p) {
  const int tid = threadIdx.x;
  const int l = tid & 63, lm = l & 15, lg = l >> 4;
  const int wid = (blockIdx.x << 2) | (tid >> 6);
  const int bf = p.ctrl[0];
  for (int u = wid; u < 512 * 54; u += 1024) {
    int mt = u / 54, nt = u - mt * 54;
    int r0 = mt << 4;
    f32x4 acc = {0.f, 0.f, 0.f, 0.f};
    const unsigned short* Arow = p.comb + (size_t)(r0 + lm) * 928 + (size_t)lg * 8;
    const unsigned short* Bp = p.PK_agg + (size_t)nt * 29 * 512 + (size_t)l * 8;
    for (int kb = 0; kb < 29; ++kb) {
      s16x8 a = *(const s16x8*)(Arow + (size_t)kb * 32);
      s16x8 b = *(const s16x8*)(Bp + (size_t)kb * 512);
      acc = MFMA_BF16(a, b, acc);
    }
    int n = nt * 16 + lm;
    if (n < 850) {
      float bias = ldf(p.agg_b, n, bf);
#pragma unroll
      for (int i = 0; i < 4; ++i) {
        int r = r0 + lg * 4 + i;
        p.xbf[(size_t)r * 864 + n] = f2bf(acc[i] + bias);
      }
    }
  }
}

// ---------------- scan (persistent, LDS weights, sc1 state) ----------------

// A-operand from LLC-coherent state (Sbf/hbf), B from LDS.
__device__ __forceinline__ void unit_coh(
    const u16* lds, const u16* Asrc, int mt, int l, f32x4& cc, f32x4& hh) {
  int lm = l & 15, lg = l >> 4;
  const u16* A  = Asrc + (size_t)(mt * 16 + lm) * 864 + (size_t)lg * 8;
  const u16* Bc = lds + l * 8;
  const u16* Bh = lds + PAIR_U16 + l * 8;
  for (int kb = 0; kb < 27; ++kb) {
    s16x8 a  = ldA16(A + (size_t)kb * 32);
    s16x8 bc = *(const s16x8*)(Bc + (size_t)kb * 512);
    s16x8 bh = *(const s16x8*)(Bh + (size_t)kb * 512);
    cc = MFMA_BF16(a, bc, cc);
    hh = MFMA_BF16(a, bh, hh);
  }
}

__device__ __forceinline__ void epi(
    const P& p, int nt, int mt, int l, const float* prevb, int dst, int act,
    f32x4 c, f32x4 h) {
  int lm = l & 15, lg = l >> 4, n = nt * 16 + lm;
  if (n >= 850) return;
#pragma unroll
  for (int i = 0; i < 4; ++i) {
    int b = mt * 16 + lg * 4 + i;
    float prev = ldc_f32(prevb + b * 850 + n);
    float s = prev + sigm(c[i]) * (actf(act, h[i]) - prev);
    stc_f32(p.Sf + ((size_t)dst * 64 + b) * 850 + n, s);
    stc_u16(p.Sbf + ((size_t)dst * 64 + b) * 864 + n, f2bf(s));
  }
}

__global__ __launch_bounds__(256) void k_scan(P p) {
  extern __shared__ u16 ldsw[];
  const int tid = threadIdx.x;
  const int l = tid & 63, lm = l & 15, lg = l >> 4, mt = tid >> 6;
  const int blk = blockIdx.x;
  const int bf = p.ctrl[0];

  int role, matA, ntA, matB, ntB;
  if (blk < 54)       { role = 0; matA = 1; ntA = blk;       matB = 3; ntB = ntA; }
  else if (blk < 108) { role = 1; matA = 2; ntA = blk - 54;  matB = 4; ntB = ntA; }
  else if (blk < 162) { role = 2; matA = 6; ntA = blk - 108; matB = 5; ntB = ntA; }
  else if (blk < 216) { role = 3; matA = 7; ntA = blk - 162; matB = 9; ntB = ntA; }
  else                { role = 4; matA = 8; ntA = 2 * (blk - 216); matB = 8; ntB = ntA + 1; }

  for (int s = 0; s < 2; ++s) {
    int m = s ? matB : matA, nt = s ? ntB : ntA;
    for (int h = 0; h < 2; ++h) {
      const uint4* src = (const uint4*)(p.PK_rec + ((size_t)(m * 2 + h) * 54 + nt) * PAIR_U16);
      uint4* dst = (uint4*)(ldsw + s * SLOT_U16 + h * PAIR_U16);
      for (int i = tid; i < PAIR_U16 / 8; i += 256) dst[i] = src[i];
    }
  }
  __syncthreads();

  float areg[4] = {0.f, 0.f, 0.f, 0.f}; // role3: accr in registers
  const f32x4 z = {0.f, 0.f, 0.f, 0.f};
  int ep = 0;

  for (int t = 0; t < 128; ++t) {
    // L0: s0 = h + sig(c)*(tanh(hh)-h); c|hh = x_t@W0_lo (cached B) + h@W0_hi (LDS)
    if (role == 0) {
      f32x4 cc = z, hh = z;
      const u16* B0 = p.PK_rec + (size_t)(0 * 54 + ntA) * PAIR_U16 + l * 8;
      const u16* B1 = p.PK_rec + (size_t)(1 * 54 + ntA) * PAIR_U16 + l * 8;
      const u16* Ax = p.xbf + ((size_t)t * 64 + mt * 16 + lm) * 864 + (size_t)lg * 8;
      for (int kb = 0; kb < 27; ++kb) {
        s16x8 a = *(const s16x8*)(Ax + (size_t)kb * 32);
        cc = MFMA_BF16(a, *(const s16x8*)(B0 + (size_t)kb * 512), cc);
        hh = MFMA_BF16(a, *(const s16x8*)(B1 + (size_t)kb * 512), hh);
      }
      unit_coh(ldsw, p.hbf, mt, l, cc, hh);
      epi(p, ntA, mt, l, p.hf, 0, 2, cc, hh);
    }
    gbar2(p.ctrl, ++ep);

    // L1: s1 = sigmoid-step(s0 @ Ws[0])
    if (role == 1) {
      f32x4 cc = z, hh = z;
      unit_coh(ldsw, p.Sbf + (size_t)0 * 64 * 864, mt, l, cc, hh);
      epi(p, ntA, mt, l, p.Sf + 0 * 64 * 850, 1, 0, cc, hh);
    }
    gbar2(p.ctrl, ++ep);

    // L2: s2/s3/s4 from s1 (relu/relu/identity) — slot1 of roles 0/1/2
    if (role <= 2) {
      f32x4 cc = z, hh = z;
      unit_coh(ldsw + SLOT_U16, p.Sbf + (size_t)1 * 64 * 864, mt, l, cc, hh);
      int dst = (role == 0) ? 2 : (role == 1) ? 3 : 4;
      int act = (role == 2) ? 3 : 1;
      epi(p, ntB, mt, l, p.Sf + 1 * 64 * 850, dst, act, cc, hh);
    }
    gbar2(p.ctrl, ++ep);

    // L3: s5 = tanh-step(s2@Ws[4]) [role2]; s7 = tanh-step(s3@Ws[6]) [role4, 2 tiles]
    if (role == 2) {
      f32x4 cc = z, hh = z;
      unit_coh(ldsw, p.Sbf + (size_t)2 * 64 * 864, mt, l, cc, hh);
      epi(p, ntA, mt, l, p.Sf + 2 * 64 * 850, 5, 2, cc, hh);
    } else if (role == 4) {
      f32x4 cc = z, hh = z;
      unit_coh(ldsw, p.Sbf + (size_t)3 * 64 * 864, mt, l, cc, hh);
      epi(p, ntA, mt, l, p.Sf + 3 * 64 * 850, 7, 2, cc, hh);
      f32x4 c2 = z, h2 = z;
      unit_coh(ldsw + SLOT_U16, p.Sbf + (size_t)3 * 64 * 864, mt, l, c2, h2);
      epi(p, ntB, mt, l, p.Sf + 3 * 64 * 850, 7, 2, c2, h2);
    }
    gbar2(p.ctrl, ++ep);

    // L4: s6 = sig-step(s5@Ws[5]); s8 = relu-step(s5@Ws[7]); fused out/mean/h
    if (role == 3) {
      f32x4 cA = z, hA = z, cB = z, hB = z;
      unit_coh(ldsw, p.Sbf + (size_t)5 * 64 * 864, mt, l, cA, hA);
      unit_coh(ldsw + SLOT_U16, p.Sbf + (size_t)5 * 64 * 864, mt, l, cB, hB);
      int n = ntA * 16 + lm;
      if (n < 850) {
#pragma unroll
        for (int i = 0; i < 4; ++i) {
          int b = mt * 16 + lg * 4 + i;
          float s5v = ldc_f32(p.Sf + (5 * 64 + b) * 850 + n);
          float s6 = s5v + sigm(cA[i]) * (sigm(hA[i]) - s5v);
          float s8 = s5v + sigm(cB[i]) * (fmaxf(hB[i], 0.f) - s5v);
          float sum = ldc_f32(p.Sf + (1 * 64 + b) * 850 + n)
                    + ldc_f32(p.Sf + (2 * 64 + b) * 850 + n)
                    + ldc_f32(p.Sf + (3 * 64 + b) * 850 + n)
                    + ldc_f32(p.Sf + (4 * 64 + b) * 850 + n)
                    + s5v
                    + ldc_f32(p.Sf + (7 * 64 + b) * 850 + n) + s6 + s8;
          float outv = sum * 0.125f;
          float mk = ldf(p.masks, b * 128 + t, bf);
          areg[i] += outv * mk;
          if (t == 127) {
            stout(p.out, 2688 + (size_t)b * 850 + n, outv * mk, bf);
            stc_f32(p.accr + b * 850 + n, areg[i]);
          }
          stc_f32(p.hf + b * 850 + n, outv);
          stc_u16(p.hbf + (size_t)b * 864 + n, f2bf(outv));
        }
      }
    }
    gbar2(p.ctrl, ++ep);
  }

  // decoder + log_softmax: one wave per batch row (blocks 0..15)
  int wid = blk * 4 + mt;
  if (wid < 64) {
    int b = wid;
    float myval = 0.0f;
    for (int c = 0; c < 42; ++c) {
      float part = 0.0f;
      for (int d = l; d < 850; d += 64)
        part += ldc_f32(p.accr + b * 850 + d) * ldf(p.dec_W, c * 850 + d, bf);
      for (int off = 32; off > 0; off >>= 1) part += __shfl_xor(part, off);
      if (l == c) myval = part * (1.0f / 128.0f) + ldf(p.dec_b, c, bf);
    }
    float mx = (l < 42) ? myval : -INFINITY;
    for (int off = 32; off > 0; off >>= 1) mx = fmaxf(mx, __shfl_xor(mx, off));
    float ex = (l < 42) ? expf(myval - mx) : 0.0f;
    float sm = ex;
    for (int off = 32; off > 0; off >>= 1) sm += __shfl_xor(sm, off);
    if (l < 42) stout(p.out, (size_t)b * 42 + l, myval - mx - logf(sm), bf);
  }
}

// ---------------- launch ----------------

extern "C" void kernel_launch(void* const* d_in, const int* in_sizes, int n_in,
                              void* d_out, int out_size, void* d_ws, size_t ws_size,
                              hipStream_t stream) {
  (void)in_sizes; (void)n_in; (void)out_size;
  P p;
  p.tokens = (const int*)d_in[0];
  p.masks  = d_in[1];
  p.pos    = (const int*)d_in[2];
  p.ner    = (const int*)d_in[3];
  p.hidden = d_in[4];
  p.enc_W  = d_in[5];
  p.ner_W  = d_in[6];
  p.pos_W  = d_in[7];
  p.agg_W  = d_in[8];
  p.agg_b  = d_in[9];
  p.W0     = d_in[10];
  p.Ws     = d_in[11];
  p.dec_W  = d_in[12];
  p.dec_b  = d_in[13];
  p.out    = d_out;

  unsigned char* ws = (unsigned char*)d_ws;
  p.ctrl = (int*)ws;
  unsigned char* R0 = ws + 32768;
  // R0 (29,859,840 B): PK_agg+comb during phase A, then PK_rec.
  p.PK_agg = (unsigned short*)R0;
  p.comb   = (unsigned short*)(R0 + 1603584);
  p.PK_rec = (unsigned short*)R0;
  unsigned char* q = R0 + 29859840;
  p.xbf  = (unsigned short*)q; q += 14155776;
  p.Sbf  = (unsigned short*)q; q += 995328;
  p.hbf  = (unsigned short*)q; q += 110592;
  p.Sf   = (float*)q;          q += 1958400;
  p.hf   = (float*)q;          q += 217600;
  p.accr = (float*)q;          q += 217600;

  size_t need = (size_t)(q - ws);
  if (ws_size < need) {
    hipLaunchKernelGGL(k_diag, dim3(1), dim3(64), 0, stream, p);
    return;
  }

  static int lds_attr_set = 0;
  if (!lds_attr_set) { // host-side attribute, graph-capture safe, idempotent
    (void)hipFuncSetAttribute((const void*)k_scan,
                              hipFuncAttributeMaxDynamicSharedMemorySize, LDS_BYTES);
    lds_attr_set = 1;
  }

  hipLaunchKernelGGL(k_detect,   dim3(1),    dim3(64),  0, stream, p);
  hipLaunchKernelGGL(k_init,     dim3(256),  dim3(256), 0, stream, p);
  hipLaunchKernelGGL(k_pack_agg, dim3(512),  dim3(256), 0, stream, p);
  hipLaunchKernelGGL(k_comb,     dim3(4096), dim3(256), 0, stream, p);
  hipLaunchKernelGGL(k_phaseA,   dim3(256),  dim3(256), 0, stream, p);
  hipLaunchKernelGGL(k_pack_rec, dim3(4096), dim3(256), 0, stream, p);
  hipLaunchKernelGGL(k_scan,     dim3(NBLK), dim3(256), LDS_BYTES, stream, p);
}

// Round 5
// 8922.520 us; speedup vs baseline: 5.1578x; 1.1801x over previous
//
#include <hip/hip_runtime.h>
#include <math.h>

typedef float f32x4 __attribute__((ext_vector_type(4)));
typedef short s16x8 __attribute__((ext_vector_type(8)));
typedef unsigned short u16;

#define MFMA_BF16(a,b,c) __builtin_amdgcn_mfma_f32_16x16x32_bf16((a),(b),(c),0,0,0)
#define NBLK 243
#define PAIR_U16 13824   // one half-matrix tile: 27 kb * 512
#define SLOT_U16 27648   // c+h halves
#define LDS_BYTES 110592 // 2 slots * 27648 u16 * 2B

// Geometry: D=850 pad 864 (27 kb of 32), 54 n-tiles of 16. Phase A: K=910 pad 928.
// PK_rec[mat][half][nt][kb][lane][8]; mat: 0=W0 lo, 1=W0 hi, 2+i=Ws[i].
// Scan: 243 persistent blocks (1/CU, LDS=110KB), weights (mats 1..9) LDS-resident.
// Cross-block state via relaxed agent atomics (sc1, LLC-coherent); A-operands are
// PRELOADED in a fully-unrolled burst (one LLC latency per unit, not 27).
// Barrier: symmetric arrive-flag array, every block lane-polls all flags.

struct P {
  const int* tokens; const void* masks; const int* pos; const int* ner;
  const void* hidden;
  const void* enc_W; const void* ner_W; const void* pos_W;
  const void* agg_W; const void* agg_b;
  const void* W0; const void* Ws;
  const void* dec_W; const void* dec_b;
  void* out;
  unsigned short* PK_agg; unsigned short* PK_rec; unsigned short* comb;
  unsigned short* xbf; unsigned short* Sbf; unsigned short* hbf;
  float* Sf; float* hf; float* accr;
  int* ctrl; // [0]=bf16 flag; [256+i]=arrive[i]
};

__device__ __forceinline__ unsigned short f2bf(float f) {
  union { float f; unsigned u; } v; v.f = f;
  return (unsigned short)((v.u + 0x7FFFu + ((v.u >> 16) & 1u)) >> 16);
}
__device__ __forceinline__ float ldf(const void* q, size_t i, int bf) {
  if (bf) { union { unsigned x; float f; } v;
            v.x = (unsigned)((const unsigned short*)q)[i] << 16; return v.f; }
  return ((const float*)q)[i];
}
__device__ __forceinline__ void stout(void* o, size_t i, float v, int bf) {
  if (bf) ((unsigned short*)o)[i] = f2bf(v);
  else    ((float*)o)[i] = v;
}
__device__ __forceinline__ float sigm(float x) { return 1.0f / (1.0f + expf(-x)); }
__device__ __forceinline__ float actf(int a, float x) {
  if (a == 0) return sigm(x);
  if (a == 1) return fmaxf(x, 0.0f);
  if (a == 2) return tanhf(x);
  return x;
}

// ---- LLC-coherent (sc1) accessors: relaxed agent-scope atomics ----
__device__ __forceinline__ s16x8 ldA16(const u16* p) {
  unsigned long long lo = __hip_atomic_load((const unsigned long long*)p,
      __ATOMIC_RELAXED, __HIP_MEMORY_SCOPE_AGENT);
  unsigned long long hi = __hip_atomic_load((const unsigned long long*)(p + 4),
      __ATOMIC_RELAXED, __HIP_MEMORY_SCOPE_AGENT);
  union { unsigned long long q[2]; s16x8 v; } u; u.q[0] = lo; u.q[1] = hi;
  return u.v;
}
__device__ __forceinline__ float ldc_f32(const float* p) {
  unsigned x = __hip_atomic_load((const unsigned*)p, __ATOMIC_RELAXED,
                                 __HIP_MEMORY_SCOPE_AGENT);
  union { unsigned u; float f; } v; v.u = x; return v.f;
}
__device__ __forceinline__ void stc_f32(float* p, float f) {
  union { float f; unsigned u; } v; v.f = f;
  __hip_atomic_store((unsigned*)p, v.u, __ATOMIC_RELAXED, __HIP_MEMORY_SCOPE_AGENT);
}
__device__ __forceinline__ void stc_u16(u16* p, u16 x) {
  __hip_atomic_store(p, x, __ATOMIC_RELAXED, __HIP_MEMORY_SCOPE_AGENT);
}
__device__ __forceinline__ void stc_i32(int* p, int x) {
  __hip_atomic_store(p, x, __ATOMIC_RELAXED, __HIP_MEMORY_SCOPE_AGENT);
}
__device__ __forceinline__ int ldc_i32(const int* p) {
  return __hip_atomic_load(p, __ATOMIC_RELAXED, __HIP_MEMORY_SCOPE_AGENT);
}

// Symmetric fence-free grid barrier. Entry __syncthreads drains vmcnt so all
// sc1 state stores are at the LLC before the arrive flag is stored; every
// block polls all flags itself (one LLC trip after last arrival).
__device__ __forceinline__ void gbar3(int* ctrl, int epoch) {
  __syncthreads();
  if (threadIdx.x == 0) stc_i32(ctrl + 256 + blockIdx.x, epoch);
  int spins = 0;
  for (;;) {
    int ok = 1;
    if (threadIdx.x < NBLK) ok = (ldc_i32(ctrl + 256 + threadIdx.x) >= epoch);
    if (__syncthreads_count(ok) == 256) break;
    if (++spins > 2000000) break; // bounded diagnostic escape
    __builtin_amdgcn_s_sleep(1);
  }
}

// ---------------- prep kernels (proven) ----------------

__global__ void k_detect(P p) {
  for (int j = threadIdx.x; j < 8192; j += 64) p.ctrl[j] = 0;
  __syncthreads();
  if (threadIdx.x == 0) {
    const unsigned short* u = (const unsigned short*)p.W0;
    int good = 0;
    for (int i = 0; i < 256; ++i) {
      int e = (u[i] >> 7) & 0xFF;
      if (e >= 90 && e <= 126) ++good;
    }
    p.ctrl[0] = (good >= 192) ? 1 : 0;
  }
}

__global__ __launch_bounds__(256) void k_init(P p) {
  const int bf = p.ctrl[0];
  const int total = 54400 + 896 + 8064 + 114688;
  for (int e = blockIdx.x * blockDim.x + threadIdx.x; e < total;
       e += gridDim.x * blockDim.x) {
    if (e < 54400) {
      int b = e / 850, n = e % 850;
      float h0 = ldf(p.hidden, e, bf);
      p.hf[e] = h0;
      p.hbf[(size_t)b * 864 + n] = f2bf(h0);
    } else if (e < 54400 + 896) {
      int e2 = e - 54400; int b = e2 / 14, n = 850 + e2 % 14;
      p.hbf[(size_t)b * 864 + n] = 0;
    } else if (e < 54400 + 896 + 8064) {
      int e3 = e - 54400 - 896; int s = e3 / 896, r = e3 % 896;
      int b = r / 14, n = 850 + r % 14;
      p.Sbf[((size_t)s * 64 + b) * 864 + n] = 0;
    } else {
      int e4 = e - 54400 - 896 - 8064; int t = e4 / 896, r = e4 % 896;
      int b = r / 14, n = 850 + r % 14;
      p.xbf[((size_t)t * 64 + b) * 864 + n] = 0;
    }
  }
}

__global__ __launch_bounds__(256) void k_pack_agg(P p) {
  const int bf = p.ctrl[0];
  const long total = 801792L;
  for (long e = (long)blockIdx.x * blockDim.x + threadIdx.x; e < total;
       e += (long)gridDim.x * blockDim.x) {
    int j = (int)(e & 7), l = (int)((e >> 3) & 63);
    long q9 = e >> 9;
    int kb = (int)(q9 % 29), nt = (int)(q9 / 29);
    int n = nt * 16 + (l & 15);
    int k = kb * 32 + ((l >> 4) << 3) + j;
    float v = 0.0f;
    if (n < 850 && k < 910) v = ldf(p.agg_W, (size_t)n * 910 + k, bf);
    p.PK_agg[e] = f2bf(v);
  }
}

__global__ __launch_bounds__(256) void k_comb(P p) {
  const int bf = p.ctrl[0];
  const long total = 7602176L;
  for (long e = (long)blockIdx.x * blockDim.x + threadIdx.x; e < total;
       e += (long)gridDim.x * blockDim.x) {
    int k = (int)(e % 928);
    int r = (int)(e / 928);
    int t = r >> 6, b = r & 63;
    float v = 0.0f;
    if (k < 850)      { int tok = p.tokens[b * 128 + t]; v = ldf(p.enc_W, (size_t)tok * 850 + k, bf); }
    else if (k < 880) { int nv = p.ner[b * 128 + t];     v = ldf(p.ner_W, nv * 30 + (k - 850), bf); }
    else if (k < 910) { int pv = p.pos[b * 128 + t];     v = ldf(p.pos_W, pv * 30 + (k - 880), bf); }
    p.comb[e] = f2bf(v);
  }
}

__global__ __launch_bounds__(256) void k_pack_rec(P p) {
  const int bf = p.ctrl[0];
  const long total = 14929920L;
  for (long e = (long)blockIdx.x * blockDim.x + threadIdx.x; e < total;
       e += (long)gridDim.x * blockDim.x) {
    int j = (int)(e & 7), l = (int)((e >> 3) & 63);
    long q9 = e >> 9;
    int kb = (int)(q9 % 27);
    long q = q9 / 27;
    int nt = (int)(q % 54);
    int mh = (int)(q / 54);
    int half = mh & 1, mat = mh >> 1;
    int nl = nt * 16 + (l & 15);
    int col = half ? nl + 850 : nl;
    int k = kb * 32 + ((l >> 4) << 3) + j;
    float v = 0.0f;
    if (nl < 850 && k < 850) {
      if (mat == 0)      v = ldf(p.W0, (size_t)k * 1700 + col, bf);
      else if (mat == 1) v = ldf(p.W0, (size_t)(k + 850) * 1700 + col, bf);
      else               v = ldf(p.Ws, (size_t)(mat - 2) * 850 * 1700 + (size_t)k * 1700 + col, bf);
    }
    p.PK_rec[e] = f2bf(v);
  }
}

__global__ void k_diag(P p) {
  if (blockIdx.x == 0 && threadIdx.x == 0)
    for (int i = 0; i < 64; ++i) ((float*)p.out)[i] = 2000.0f;
}

__global__ __launch_bounds__(256) void k_phaseA(P p) {
  const int tid = threadIdx.x;
  const int l = tid & 63, lm = l & 15, lg = l >> 4;
  const int wid = (blockIdx.x << 2) | (tid >> 6);
  const int bf = p.ctrl[0];
  for (int u = wid; u < 512 * 54; u += 1024) {
    int mt = u / 54, nt = u - mt * 54;
    int r0 = mt << 4;
    f32x4 acc = {0.f, 0.f, 0.f, 0.f};
    const unsigned short* Arow = p.comb + (size_t)(r0 + lm) * 928 + (size_t)lg * 8;
    const unsigned short* Bp = p.PK_agg + (size_t)nt * 29 * 512 + (size_t)l * 8;
    for (int kb = 0; kb < 29; ++kb) {
      s16x8 a = *(const s16x8*)(Arow + (size_t)kb * 32);
      s16x8 b = *(const s16x8*)(Bp + (size_t)kb * 512);
      acc = MFMA_BF16(a, b, acc);
    }
    int n = nt * 16 + lm;
    if (n < 850) {
      float bias = ldf(p.agg_b, n, bf);
#pragma unroll
      for (int i = 0; i < 4; ++i) {
        int r = r0 + lg * 4 + i;
        p.xbf[(size_t)r * 864 + n] = f2bf(acc[i] + bias);
      }
    }
  }
}

// ---------------- scan units (batched A preloads) ----------------

// A from LLC (sc1) — preloaded burst; B c/h from LDS. Adds into cc,hh.
__device__ __forceinline__ void unit1(const u16* lds, const u16* Asrc, int mt, int l,
                                      f32x4& cc, f32x4& hh) {
  const int lm = l & 15, lg = l >> 4;
  const u16* A = Asrc + (size_t)(mt * 16 + lm) * 864 + (size_t)lg * 8;
  s16x8 ab[27];
#pragma unroll
  for (int kb = 0; kb < 27; ++kb) ab[kb] = ldA16(A + (size_t)kb * 32);
  const f32x4 z = {0.f, 0.f, 0.f, 0.f};
  f32x4 c0 = z, c1 = z, h0 = z, h1 = z;
#pragma unroll
  for (int kb = 0; kb < 27; ++kb) {
    s16x8 bc = *(const s16x8*)(lds + l * 8 + (size_t)kb * 512);
    s16x8 bh = *(const s16x8*)(lds + PAIR_U16 + l * 8 + (size_t)kb * 512);
    if (kb & 1) { c1 = MFMA_BF16(ab[kb], bc, c1); h1 = MFMA_BF16(ab[kb], bh, h1); }
    else        { c0 = MFMA_BF16(ab[kb], bc, c0); h0 = MFMA_BF16(ab[kb], bh, h0); }
  }
  cc += c0 + c1; hh += h0 + h1;
}

// One shared A preload, two B slots (4 MFMAs/kb). A from LLC (sc1).
__device__ __forceinline__ void unit2(const u16* lds0, const u16* lds1, const u16* Asrc,
                                      int mt, int l,
                                      f32x4& cA, f32x4& hA, f32x4& cB, f32x4& hB) {
  const int lm = l & 15, lg = l >> 4;
  const u16* A = Asrc + (size_t)(mt * 16 + lm) * 864 + (size_t)lg * 8;
  s16x8 ab[27];
#pragma unroll
  for (int kb = 0; kb < 27; ++kb) ab[kb] = ldA16(A + (size_t)kb * 32);
#pragma unroll
  for (int kb = 0; kb < 27; ++kb) {
    cA = MFMA_BF16(ab[kb], *(const s16x8*)(lds0 + l * 8 + (size_t)kb * 512), cA);
    hA = MFMA_BF16(ab[kb], *(const s16x8*)(lds0 + PAIR_U16 + l * 8 + (size_t)kb * 512), hA);
    cB = MFMA_BF16(ab[kb], *(const s16x8*)(lds1 + l * 8 + (size_t)kb * 512), cB);
    hB = MFMA_BF16(ab[kb], *(const s16x8*)(lds1 + PAIR_U16 + l * 8 + (size_t)kb * 512), hB);
  }
}

// x-part of L0: plain (L2-cached) A from xbf, B = W0_lo c/h from global PK_rec.
__device__ __forceinline__ void unit_x(const P& p, int nt, int t, int mt, int l,
                                       f32x4& cc, f32x4& hh) {
  const int lm = l & 15, lg = l >> 4;
  const u16* Ax = p.xbf + ((size_t)t * 64 + mt * 16 + lm) * 864 + (size_t)lg * 8;
  const u16* B0 = p.PK_rec + (size_t)(0 * 54 + nt) * PAIR_U16 + l * 8;
  const u16* B1 = p.PK_rec + (size_t)(1 * 54 + nt) * PAIR_U16 + l * 8;
  s16x8 ab[27];
#pragma unroll
  for (int kb = 0; kb < 27; ++kb) ab[kb] = *(const s16x8*)(Ax + (size_t)kb * 32);
  const f32x4 z = {0.f, 0.f, 0.f, 0.f};
  f32x4 c0 = z, c1 = z, h0 = z, h1 = z;
#pragma unroll
  for (int kb = 0; kb < 27; ++kb) {
    s16x8 bc = *(const s16x8*)(B0 + (size_t)kb * 512);
    s16x8 bh = *(const s16x8*)(B1 + (size_t)kb * 512);
    if (kb & 1) { c1 = MFMA_BF16(ab[kb], bc, c1); h1 = MFMA_BF16(ab[kb], bh, h1); }
    else        { c0 = MFMA_BF16(ab[kb], bc, c0); h0 = MFMA_BF16(ab[kb], bh, h0); }
  }
  cc += c0 + c1; hh += h0 + h1;
}

__device__ __forceinline__ void epi(
    const P& p, int nt, int mt, int l, const float* prevb, int dst, int act,
    f32x4 c, f32x4 h) {
  int lm = l & 15, lg = l >> 4, n = nt * 16 + lm;
  if (n >= 850) return;
#pragma unroll
  for (int i = 0; i < 4; ++i) {
    int b = mt * 16 + lg * 4 + i;
    float prev = ldc_f32(prevb + b * 850 + n);
    float s = prev + sigm(c[i]) * (actf(act, h[i]) - prev);
    stc_f32(p.Sf + ((size_t)dst * 64 + b) * 850 + n, s);
    stc_u16(p.Sbf + ((size_t)dst * 64 + b) * 864 + n, f2bf(s));
  }
}

__global__ __launch_bounds__(256, 1) void k_scan(P p) {
  extern __shared__ u16 ldsw[];
  const int tid = threadIdx.x;
  const int l = tid & 63, lm = l & 15, lg = l >> 4, mt = tid >> 6;
  const int blk = blockIdx.x;
  const int bf = p.ctrl[0];

  int role, matA, ntA, matB, ntB;
  if (blk < 54)       { role = 0; matA = 1; ntA = blk;       matB = 3; ntB = ntA; }
  else if (blk < 108) { role = 1; matA = 2; ntA = blk - 54;  matB = 4; ntB = ntA; }
  else if (blk < 162) { role = 2; matA = 6; ntA = blk - 108; matB = 5; ntB = ntA; }
  else if (blk < 216) { role = 3; matA = 7; ntA = blk - 162; matB = 9; ntB = ntA; }
  else                { role = 4; matA = 8; ntA = 2 * (blk - 216); matB = 8; ntB = ntA + 1; }

  for (int s = 0; s < 2; ++s) {
    int m = s ? matB : matA, nt = s ? ntB : ntA;
    for (int h = 0; h < 2; ++h) {
      const uint4* src = (const uint4*)(p.PK_rec + ((size_t)(m * 2 + h) * 54 + nt) * PAIR_U16);
      uint4* dst = (uint4*)(ldsw + s * SLOT_U16 + h * PAIR_U16);
      for (int i = tid; i < PAIR_U16 / 8; i += 256) dst[i] = src[i];
    }
  }
  __syncthreads();

  float areg[4] = {0.f, 0.f, 0.f, 0.f}; // role3: accr in registers
  const f32x4 z = {0.f, 0.f, 0.f, 0.f};
  int ep = 0;

  for (int t = 0; t < 128; ++t) {
    // L0: s0 = h + sig(c)*(tanh(hh)-h); c|hh = x_t@W0_lo (global) + h@W0_hi (LDS)
    if (role == 0) {
      f32x4 cc = z, hh = z;
      unit_x(p, ntA, t, mt, l, cc, hh);
      unit1(ldsw, p.hbf, mt, l, cc, hh);
      epi(p, ntA, mt, l, p.hf, 0, 2, cc, hh);
    }
    gbar3(p.ctrl, ++ep);

    // L1: s1 = sigmoid-step(s0 @ Ws[0])
    if (role == 1) {
      f32x4 cc = z, hh = z;
      unit1(ldsw, p.Sbf + (size_t)0 * 64 * 864, mt, l, cc, hh);
      epi(p, ntA, mt, l, p.Sf + 0 * 64 * 850, 1, 0, cc, hh);
    }
    gbar3(p.ctrl, ++ep);

    // L2: s2/s3/s4 from s1 (relu/relu/identity) — slot1 of roles 0/1/2
    if (role <= 2) {
      f32x4 cc = z, hh = z;
      unit1(ldsw + SLOT_U16, p.Sbf + (size_t)1 * 64 * 864, mt, l, cc, hh);
      int dst = (role == 0) ? 2 : (role == 1) ? 3 : 4;
      int act = (role == 2) ? 3 : 1;
      epi(p, ntB, mt, l, p.Sf + 1 * 64 * 850, dst, act, cc, hh);
    }
    gbar3(p.ctrl, ++ep);

    // L3: s5 = tanh-step(s2@Ws[4]) [role2]; s7 = tanh-step(s3@Ws[6]) [role4, 2 tiles]
    if (role == 2) {
      f32x4 cc = z, hh = z;
      unit1(ldsw, p.Sbf + (size_t)2 * 64 * 864, mt, l, cc, hh);
      epi(p, ntA, mt, l, p.Sf + 2 * 64 * 850, 5, 2, cc, hh);
    } else if (role == 4) {
      f32x4 cA = z, hA = z, cB = z, hB = z;
      unit2(ldsw, ldsw + SLOT_U16, p.Sbf + (size_t)3 * 64 * 864, mt, l, cA, hA, cB, hB);
      epi(p, ntA, mt, l, p.Sf + 3 * 64 * 850, 7, 2, cA, hA);
      epi(p, ntB, mt, l, p.Sf + 3 * 64 * 850, 7, 2, cB, hB);
    }
    gbar3(p.ctrl, ++ep);

    // L4: s6 = sig-step(s5@Ws[5]); s8 = relu-step(s5@Ws[7]); fused out/mean/h
    if (role == 3) {
      f32x4 cA = z, hA = z, cB = z, hB = z;
      unit2(ldsw, ldsw + SLOT_U16, p.Sbf + (size_t)5 * 64 * 864, mt, l, cA, hA, cB, hB);
      int n = ntA * 16 + lm;
      if (n < 850) {
#pragma unroll
        for (int i = 0; i < 4; ++i) {
          int b = mt * 16 + lg * 4 + i;
          float s5v = ldc_f32(p.Sf + (5 * 64 + b) * 850 + n);
          float s6 = s5v + sigm(cA[i]) * (sigm(hA[i]) - s5v);
          float s8 = s5v + sigm(cB[i]) * (fmaxf(hB[i], 0.f) - s5v);
          float sum = ldc_f32(p.Sf + (1 * 64 + b) * 850 + n)
                    + ldc_f32(p.Sf + (2 * 64 + b) * 850 + n)
                    + ldc_f32(p.Sf + (3 * 64 + b) * 850 + n)
                    + ldc_f32(p.Sf + (4 * 64 + b) * 850 + n)
                    + s5v
                    + ldc_f32(p.Sf + (7 * 64 + b) * 850 + n) + s6 + s8;
          float outv = sum * 0.125f;
          float mk = ldf(p.masks, b * 128 + t, bf);
          areg[i] += outv * mk;
          if (t == 127) {
            stout(p.out, 2688 + (size_t)b * 850 + n, outv * mk, bf);
            stc_f32(p.accr + b * 850 + n, areg[i]);
          }
          stc_f32(p.hf + b * 850 + n, outv);
          stc_u16(p.hbf + (size_t)b * 864 + n, f2bf(outv));
        }
      }
    }
    gbar3(p.ctrl, ++ep);
  }

  // decoder + log_softmax: one wave per batch row (blocks 0..15)
  int wid = blk * 4 + mt;
  if (wid < 64) {
    int b = wid;
    float myval = 0.0f;
    for (int c = 0; c < 42; ++c) {
      float part = 0.0f;
      for (int d = l; d < 850; d += 64)
        part += ldc_f32(p.accr + b * 850 + d) * ldf(p.dec_W, c * 850 + d, bf);
      for (int off = 32; off > 0; off >>= 1) part += __shfl_xor(part, off);
      if (l == c) myval = part * (1.0f / 128.0f) + ldf(p.dec_b, c, bf);
    }
    float mx = (l < 42) ? myval : -INFINITY;
    for (int off = 32; off > 0; off >>= 1) mx = fmaxf(mx, __shfl_xor(mx, off));
    float ex = (l < 42) ? expf(myval - mx) : 0.0f;
    float sm = ex;
    for (int off = 32; off > 0; off >>= 1) sm += __shfl_xor(sm, off);
    if (l < 42) stout(p.out, (size_t)b * 42 + l, myval - mx - logf(sm), bf);
  }
}

// ---------------- launch ----------------

extern "C" void kernel_launch(void* const* d_in, const int* in_sizes, int n_in,
                              void* d_out, int out_size, void* d_ws, size_t ws_size,
                              hipStream_t stream) {
  (void)in_sizes; (void)n_in; (void)out_size;
  P p;
  p.tokens = (const int*)d_in[0];
  p.masks  = d_in[1];
  p.pos    = (const int*)d_in[2];
  p.ner    = (const int*)d_in[3];
  p.hidden = d_in[4];
  p.enc_W  = d_in[5];
  p.ner_W  = d_in[6];
  p.pos_W  = d_in[7];
  p.agg_W  = d_in[8];
  p.agg_b  = d_in[9];
  p.W0     = d_in[10];
  p.Ws     = d_in[11];
  p.dec_W  = d_in[12];
  p.dec_b  = d_in[13];
  p.out    = d_out;

  unsigned char* ws = (unsigned char*)d_ws;
  p.ctrl = (int*)ws;
  unsigned char* R0 = ws + 32768;
  // R0 (29,859,840 B): PK_agg+comb during phase A, then PK_rec.
  p.PK_agg = (unsigned short*)R0;
  p.comb   = (unsigned short*)(R0 + 1603584);
  p.PK_rec = (unsigned short*)R0;
  unsigned char* q = R0 + 29859840;
  p.xbf  = (unsigned short*)q; q += 14155776;
  p.Sbf  = (unsigned short*)q; q += 995328;
  p.hbf  = (unsigned short*)q; q += 110592;
  p.Sf   = (float*)q;          q += 1958400;
  p.hf   = (float*)q;          q += 217600;
  p.accr = (float*)q;          q += 217600;

  size_t need = (size_t)(q - ws);
  if (ws_size < need) {
    hipLaunchKernelGGL(k_diag, dim3(1), dim3(64), 0, stream, p);
    return;
  }

  static int lds_attr_set = 0;
  if (!lds_attr_set) { // host-side attribute, graph-capture safe, idempotent
    (void)hipFuncSetAttribute((const void*)k_scan,
                              hipFuncAttributeMaxDynamicSharedMemorySize, LDS_BYTES);
    lds_attr_set = 1;
  }

  hipLaunchKernelGGL(k_detect,   dim3(1),    dim3(64),  0, stream, p);
  hipLaunchKernelGGL(k_init,     dim3(256),  dim3(256), 0, stream, p);
  hipLaunchKernelGGL(k_pack_agg, dim3(512),  dim3(256), 0, stream, p);
  hipLaunchKernelGGL(k_comb,     dim3(4096), dim3(256), 0, stream, p);
  hipLaunchKernelGGL(k_phaseA,   dim3(256),  dim3(256), 0, stream, p);
  hipLaunchKernelGGL(k_pack_rec, dim3(4096), dim3(256), 0, stream, p);
  hipLaunchKernelGGL(k_scan,     dim3(NBLK), dim3(256), LDS_BYTES, stream, p);
}

// Round 6
// 6128.413 us; speedup vs baseline: 7.5094x; 1.4559x over previous
//
#include <hip/hip_runtime.h>
#include <math.h>

typedef float f32x4 __attribute__((ext_vector_type(4)));
typedef short s16x8 __attribute__((ext_vector_type(8)));
typedef unsigned short u16;

#define MFMA_BF16(a,b,c) __builtin_amdgcn_mfma_f32_16x16x32_bf16((a),(b),(c),0,0,0)
#define NBLK 243
#define PAIR_U16 13824   // one half-matrix tile: 27 kb * 512
#define SLOT_U16 27648   // c+h halves
#define LDS_BYTES 110592 // 2 slots * 27648 u16 * 2B
#define ST_SLOT 55296    // u16 per state slot (64*864)

// Dataflow scan: 243 persistent blocks (1/CU), weights LDS-resident.
// State slots (bf16, [parity][slot][64][864]): 0=s0 1=s1 2=s2 3=s3 4=s4 5=s5 6=s7 7=h
// Roles: 0(blk0-53): L0->s0, L2->s2 | 1(54-107): L1->s1, L2->s3
//        2(108-161): L2->s4, L3->s5 | 3(162-215): L4->s6,s8,out,h | 4(216-242): L3->s7 (2 nt)
// Sync: per-producer-group epoch flags; consumers poll ONLY their producers.
// All cross-block data = relaxed agent atomics (sc1, LLC); no fences anywhere.

struct P {
  const int* tokens; const void* masks; const int* pos; const int* ner;
  const void* hidden;
  const void* enc_W; const void* ner_W; const void* pos_W;
  const void* agg_W; const void* agg_b;
  const void* W0; const void* Ws;
  const void* dec_W; const void* dec_b;
  void* out;
  unsigned short* PK_agg; unsigned short* PK_rec; unsigned short* comb;
  unsigned short* xbf; unsigned short* Sbf;
  float* accr;
  int* ctrl; // [0]=bf16 flag; flags: F0@512 F1@1024 F2A@1536 F2B@2048 F2C@2560 F3A@3072 F3B@3584 F4@4096
};

__device__ __forceinline__ unsigned short f2bf(float f) {
  union { float f; unsigned u; } v; v.f = f;
  return (unsigned short)((v.u + 0x7FFFu + ((v.u >> 16) & 1u)) >> 16);
}
__device__ __forceinline__ float bf2f(u16 x) {
  union { unsigned u; float f; } v; v.u = (unsigned)x << 16; return v.f;
}
__device__ __forceinline__ float ldf(const void* q, size_t i, int bf) {
  if (bf) return bf2f(((const u16*)q)[i]);
  return ((const float*)q)[i];
}
__device__ __forceinline__ void stout(void* o, size_t i, float v, int bf) {
  if (bf) ((u16*)o)[i] = f2bf(v);
  else    ((float*)o)[i] = v;
}
__device__ __forceinline__ float sigm(float x) { return 1.0f / (1.0f + expf(-x)); }
__device__ __forceinline__ float actf(int a, float x) {
  if (a == 0) return sigm(x);
  if (a == 1) return fmaxf(x, 0.0f);
  if (a == 2) return tanhf(x);
  return x;
}

// ---- LLC-coherent (sc1) accessors ----
__device__ __forceinline__ s16x8 ldA16(const u16* p) {
  unsigned long long lo = __hip_atomic_load((const unsigned long long*)p,
      __ATOMIC_RELAXED, __HIP_MEMORY_SCOPE_AGENT);
  unsigned long long hi = __hip_atomic_load((const unsigned long long*)(p + 4),
      __ATOMIC_RELAXED, __HIP_MEMORY_SCOPE_AGENT);
  union { unsigned long long q[2]; s16x8 v; } u; u.q[0] = lo; u.q[1] = hi;
  return u.v;
}
__device__ __forceinline__ u16 ldc_u16(const u16* p) {
  return __hip_atomic_load(p, __ATOMIC_RELAXED, __HIP_MEMORY_SCOPE_AGENT);
}
__device__ __forceinline__ float ldc_f32(const float* p) {
  unsigned x = __hip_atomic_load((const unsigned*)p, __ATOMIC_RELAXED,
                                 __HIP_MEMORY_SCOPE_AGENT);
  union { unsigned u; float f; } v; v.u = x; return v.f;
}
__device__ __forceinline__ void stc_f32(float* p, float f) {
  union { float f; unsigned u; } v; v.f = f;
  __hip_atomic_store((unsigned*)p, v.u, __ATOMIC_RELAXED, __HIP_MEMORY_SCOPE_AGENT);
}
__device__ __forceinline__ void stc_u16(u16* p, u16 x) {
  __hip_atomic_store(p, x, __ATOMIC_RELAXED, __HIP_MEMORY_SCOPE_AGENT);
}
__device__ __forceinline__ void stc_i32(int* p, int x) {
  __hip_atomic_store(p, x, __ATOMIC_RELAXED, __HIP_MEMORY_SCOPE_AGENT);
}
__device__ __forceinline__ int ldc_i32(const int* p) {
  return __hip_atomic_load(p, __ATOMIC_RELAXED, __HIP_MEMORY_SCOPE_AGENT);
}

// Consumer wait: wave 0 polls producer-group flags; __syncthreads releases block.
__device__ __forceinline__ void waitf(const int* fl, int n, int e) {
  if (threadIdx.x < 64) {
    int l = threadIdx.x, spins = 0;
    for (;;) {
      int ok = (l < n) ? (ldc_i32(fl + l) >= e) : 1;
      if (__all(ok)) break;
      if (++spins > 4000000) break; // bounded diagnostic escape
    }
  }
  __syncthreads();
  asm volatile("" ::: "memory");
}
__device__ __forceinline__ void waitf3(const int* fa, const int* fb, const int* fc,
                                       int n, int e) {
  if (threadIdx.x < 64) {
    int l = threadIdx.x, spins = 0;
    for (;;) {
      int ok = 1;
      if (l < n) ok = (ldc_i32(fa + l) >= e) & (ldc_i32(fb + l) >= e) &
                      (ldc_i32(fc + l) >= e);
      if (__all(ok)) break;
      if (++spins > 4000000) break;
    }
  }
  __syncthreads();
  asm volatile("" ::: "memory");
}
__device__ __forceinline__ void waitf2(const int* fa, int na, const int* fb, int nb, int e) {
  if (threadIdx.x < 64) {
    int l = threadIdx.x, spins = 0;
    for (;;) {
      int ok = ((l < na) ? (ldc_i32(fa + l) >= e) : 1) &
               ((l < nb) ? (ldc_i32(fb + l) >= e) : 1);
      if (__all(ok)) break;
      if (++spins > 4000000) break;
    }
  }
  __syncthreads();
  asm volatile("" ::: "memory");
}
// Producer flag: __syncthreads drains all waves' sc1 stores (vmcnt0) first.
__device__ __forceinline__ void setf(int* fl, int idx, int e) {
  __syncthreads();
  if (threadIdx.x == 0) stc_i32(fl + idx, e);
}

// ---------------- prep kernels ----------------

__global__ void k_detect(P p) {
  for (int j = threadIdx.x; j < 8192; j += 64) p.ctrl[j] = 0;
  __syncthreads();
  if (threadIdx.x == 0) {
    const u16* u = (const u16*)p.W0;
    int good = 0;
    for (int i = 0; i < 256; ++i) {
      int e = (u[i] >> 7) & 0xFF;
      if (e >= 90 && e <= 126) ++good;
    }
    p.ctrl[0] = (good >= 192) ? 1 : 0;
  }
}

__global__ __launch_bounds__(256) void k_init0(P p) { // zero Sbf + xbf pads
  const int total = 442368 + 114688;
  for (int e = blockIdx.x * blockDim.x + threadIdx.x; e < total;
       e += gridDim.x * blockDim.x) {
    if (e < 442368) {
      ((unsigned*)p.Sbf)[e] = 0u;
    } else {
      int e4 = e - 442368; int t = e4 / 896, r = e4 % 896;
      int b = r / 14, n = 850 + r % 14;
      p.xbf[((size_t)t * 64 + b) * 864 + n] = 0;
    }
  }
}

__global__ __launch_bounds__(256) void k_init1(P p) { // h(0) -> Sbf[par0][slot7]
  const int bf = p.ctrl[0];
  for (int e = blockIdx.x * blockDim.x + threadIdx.x; e < 54400;
       e += gridDim.x * blockDim.x) {
    int b = e / 850, n = e % 850;
    p.Sbf[(size_t)7 * ST_SLOT + (size_t)b * 864 + n] = f2bf(ldf(p.hidden, e, bf));
  }
}

__global__ __launch_bounds__(256) void k_pack_agg(P p) {
  const int bf = p.ctrl[0];
  const long total = 801792L;
  for (long e = (long)blockIdx.x * blockDim.x + threadIdx.x; e < total;
       e += (long)gridDim.x * blockDim.x) {
    int j = (int)(e & 7), l = (int)((e >> 3) & 63);
    long q9 = e >> 9;
    int kb = (int)(q9 % 29), nt = (int)(q9 / 29);
    int n = nt * 16 + (l & 15);
    int k = kb * 32 + ((l >> 4) << 3) + j;
    float v = 0.0f;
    if (n < 850 && k < 910) v = ldf(p.agg_W, (size_t)n * 910 + k, bf);
    p.PK_agg[e] = f2bf(v);
  }
}

__global__ __launch_bounds__(256) void k_comb(P p) {
  const int bf = p.ctrl[0];
  const long total = 7602176L;
  for (long e = (long)blockIdx.x * blockDim.x + threadIdx.x; e < total;
       e += (long)gridDim.x * blockDim.x) {
    int k = (int)(e % 928);
    int r = (int)(e / 928);
    int t = r >> 6, b = r & 63;
    float v = 0.0f;
    if (k < 850)      { int tok = p.tokens[b * 128 + t]; v = ldf(p.enc_W, (size_t)tok * 850 + k, bf); }
    else if (k < 880) { int nv = p.ner[b * 128 + t];     v = ldf(p.ner_W, nv * 30 + (k - 850), bf); }
    else if (k < 910) { int pv = p.pos[b * 128 + t];     v = ldf(p.pos_W, pv * 30 + (k - 880), bf); }
    p.comb[e] = f2bf(v);
  }
}

__global__ __launch_bounds__(256) void k_pack_rec(P p) {
  const int bf = p.ctrl[0];
  const long total = 14929920L;
  for (long e = (long)blockIdx.x * blockDim.x + threadIdx.x; e < total;
       e += (long)gridDim.x * blockDim.x) {
    int j = (int)(e & 7), l = (int)((e >> 3) & 63);
    long q9 = e >> 9;
    int kb = (int)(q9 % 27);
    long q = q9 / 27;
    int nt = (int)(q % 54);
    int mh = (int)(q / 54);
    int half = mh & 1, mat = mh >> 1;
    int nl = nt * 16 + (l & 15);
    int col = half ? nl + 850 : nl;
    int k = kb * 32 + ((l >> 4) << 3) + j;
    float v = 0.0f;
    if (nl < 850 && k < 850) {
      if (mat == 0)      v = ldf(p.W0, (size_t)k * 1700 + col, bf);
      else if (mat == 1) v = ldf(p.W0, (size_t)(k + 850) * 1700 + col, bf);
      else               v = ldf(p.Ws, (size_t)(mat - 2) * 850 * 1700 + (size_t)k * 1700 + col, bf);
    }
    p.PK_rec[e] = f2bf(v);
  }
}

__global__ void k_diag(P p) {
  if (blockIdx.x == 0 && threadIdx.x == 0)
    for (int i = 0; i < 64; ++i) ((float*)p.out)[i] = 2000.0f;
}

__global__ __launch_bounds__(256) void k_phaseA(P p) {
  const int tid = threadIdx.x;
  const int l = tid & 63, lm = l & 15, lg = l >> 4;
  const int wid = (blockIdx.x << 2) | (tid >> 6);
  const int bf = p.ctrl[0];
  for (int u = wid; u < 512 * 54; u += 1024) {
    int mt = u / 54, nt = u - mt * 54;
    int r0 = mt << 4;
    f32x4 acc = {0.f, 0.f, 0.f, 0.f};
    const u16* Arow = p.comb + (size_t)(r0 + lm) * 928 + (size_t)lg * 8;
    const u16* Bp = p.PK_agg + (size_t)nt * 29 * 512 + (size_t)l * 8;
    for (int kb = 0; kb < 29; ++kb) {
      s16x8 a = *(const s16x8*)(Arow + (size_t)kb * 32);
      s16x8 b = *(const s16x8*)(Bp + (size_t)kb * 512);
      acc = MFMA_BF16(a, b, acc);
    }
    int n = nt * 16 + lm;
    if (n < 850) {
      float bias = ldf(p.agg_b, n, bf);
#pragma unroll
      for (int i = 0; i < 4; ++i) {
        int r = r0 + lg * 4 + i;
        p.xbf[(size_t)r * 864 + n] = f2bf(acc[i] + bias);
      }
    }
  }
}

// ---------------- scan units ----------------

// A+prev burst from state slot (sc1); B c/h from one LDS slot. Adds into cc,hh.
__device__ __forceinline__ void unitS(const u16* lds, const u16* st, int nt, int mt,
                                      int l, f32x4& cc, f32x4& hh, float* prev) {
  const int lm = l & 15, lg = l >> 4;
  const u16* A = st + (size_t)(mt * 16 + lm) * 864 + (size_t)lg * 8;
  s16x8 ab[27];
#pragma unroll
  for (int kb = 0; kb < 27; ++kb) ab[kb] = ldA16(A + (size_t)kb * 32);
  u16 pv[4];
#pragma unroll
  for (int i = 0; i < 4; ++i)
    pv[i] = ldc_u16(st + (size_t)(mt * 16 + lg * 4 + i) * 864 + nt * 16 + lm);
  const f32x4 z = {0.f, 0.f, 0.f, 0.f};
  f32x4 c0 = z, c1 = z, h0 = z, h1 = z;
#pragma unroll
  for (int kb = 0; kb < 27; ++kb) {
    s16x8 bc = *(const s16x8*)(lds + l * 8 + (size_t)kb * 512);
    s16x8 bh = *(const s16x8*)(lds + PAIR_U16 + l * 8 + (size_t)kb * 512);
    if (kb & 1) { c1 = MFMA_BF16(ab[kb], bc, c1); h1 = MFMA_BF16(ab[kb], bh, h1); }
    else        { c0 = MFMA_BF16(ab[kb], bc, c0); h0 = MFMA_BF16(ab[kb], bh, h0); }
  }
  cc += c0 + c1; hh += h0 + h1;
#pragma unroll
  for (int i = 0; i < 4; ++i) prev[i] = bf2f(pv[i]);
}

// One shared A burst, two LDS B slots; prev at two column sets (ntA, ntB).
__device__ __forceinline__ void unit2S(const u16* lds0, const u16* lds1, const u16* st,
                                       int ntA, int ntB, int mt, int l,
                                       f32x4& cA, f32x4& hA, f32x4& cB, f32x4& hB,
                                       float* prevA, float* prevB) {
  const int lm = l & 15, lg = l >> 4;
  const u16* A = st + (size_t)(mt * 16 + lm) * 864 + (size_t)lg * 8;
  s16x8 ab[27];
#pragma unroll
  for (int kb = 0; kb < 27; ++kb) ab[kb] = ldA16(A + (size_t)kb * 32);
  u16 pa[4], pb[4];
#pragma unroll
  for (int i = 0; i < 4; ++i) {
    size_t row = (size_t)(mt * 16 + lg * 4 + i) * 864;
    pa[i] = ldc_u16(st + row + ntA * 16 + lm);
    pb[i] = ldc_u16(st + row + ntB * 16 + lm);
  }
#pragma unroll
  for (int kb = 0; kb < 27; ++kb) {
    cA = MFMA_BF16(ab[kb], *(const s16x8*)(lds0 + l * 8 + (size_t)kb * 512), cA);
    hA = MFMA_BF16(ab[kb], *(const s16x8*)(lds0 + PAIR_U16 + l * 8 + (size_t)kb * 512), hA);
    cB = MFMA_BF16(ab[kb], *(const s16x8*)(lds1 + l * 8 + (size_t)kb * 512), cB);
    hB = MFMA_BF16(ab[kb], *(const s16x8*)(lds1 + PAIR_U16 + l * 8 + (size_t)kb * 512), hB);
  }
#pragma unroll
  for (int i = 0; i < 4; ++i) { prevA[i] = bf2f(pa[i]); prevB[i] = bf2f(pb[i]); }
}

// x-part of L0: plain loads (L2-hot), B = W0_lo c/h from global PK_rec.
__device__ __forceinline__ void unit_x(const P& p, int nt, int t, int mt, int l,
                                       f32x4& cc, f32x4& hh) {
  const int lm = l & 15, lg = l >> 4;
  const u16* Ax = p.xbf + ((size_t)t * 64 + mt * 16 + lm) * 864 + (size_t)lg * 8;
  const u16* B0 = p.PK_rec + (size_t)(0 * 54 + nt) * PAIR_U16 + l * 8;
  const u16* B1 = p.PK_rec + (size_t)(1 * 54 + nt) * PAIR_U16 + l * 8;
  s16x8 ab[27];
#pragma unroll
  for (int kb = 0; kb < 27; ++kb) ab[kb] = *(const s16x8*)(Ax + (size_t)kb * 32);
  const f32x4 z = {0.f, 0.f, 0.f, 0.f};
  f32x4 c0 = z, c1 = z, h0 = z, h1 = z;
#pragma unroll
  for (int kb = 0; kb < 27; ++kb) {
    s16x8 bc = *(const s16x8*)(B0 + (size_t)kb * 512);
    s16x8 bh = *(const s16x8*)(B1 + (size_t)kb * 512);
    if (kb & 1) { c1 = MFMA_BF16(ab[kb], bc, c1); h1 = MFMA_BF16(ab[kb], bh, h1); }
    else        { c0 = MFMA_BF16(ab[kb], bc, c0); h0 = MFMA_BF16(ab[kb], bh, h0); }
  }
  cc += c0 + c1; hh += h0 + h1;
}

// gates + bf16 state store
__device__ __forceinline__ void epiS(const P& p, int par, int slot, int nt, int mt,
                                     int l, const float* prev, int act,
                                     f32x4 c, f32x4 h) {
  int lm = l & 15, lg = l >> 4, n = nt * 16 + lm;
  if (n >= 850) return;
  u16* dst = p.Sbf + (size_t)(par * 8 + slot) * ST_SLOT;
#pragma unroll
  for (int i = 0; i < 4; ++i) {
    int b = mt * 16 + lg * 4 + i;
    float s = prev[i] + sigm(c[i]) * (actf(act, h[i]) - prev[i]);
    stc_u16(dst + (size_t)b * 864 + n, f2bf(s));
  }
}

__global__ __launch_bounds__(256, 1) void k_scan(P p) {
  extern __shared__ u16 ldsw[];
  const int tid = threadIdx.x;
  const int l = tid & 63, lm = l & 15, lg = l >> 4, mt = tid >> 6;
  const int blk = blockIdx.x;
  const int bf = p.ctrl[0];
  int* F0  = p.ctrl + 512;  int* F1  = p.ctrl + 1024;
  int* F2A = p.ctrl + 1536; int* F2B = p.ctrl + 2048; int* F2C = p.ctrl + 2560;
  int* F3A = p.ctrl + 3072; int* F3B = p.ctrl + 3584; int* F4  = p.ctrl + 4096;
  const u16* SB = p.Sbf;
#define STP(par, slot) (p.Sbf + (size_t)((par) * 8 + (slot)) * ST_SLOT)

  int role, matA, ntA, matB, ntB;
  if (blk < 54)       { role = 0; matA = 1; ntA = blk;       matB = 3; ntB = ntA; }
  else if (blk < 108) { role = 1; matA = 2; ntA = blk - 54;  matB = 4; ntB = ntA; }
  else if (blk < 162) { role = 2; matA = 6; ntA = blk - 108; matB = 5; ntB = ntA; }
  else if (blk < 216) { role = 3; matA = 7; ntA = blk - 162; matB = 9; ntB = ntA; }
  else                { role = 4; matA = 8; ntA = 2 * (blk - 216); matB = 8; ntB = ntA + 1; }

  // stage this block's two weight pairs into LDS
  for (int s = 0; s < 2; ++s) {
    int m = s ? matB : matA, nt = s ? ntB : ntA;
    for (int h = 0; h < 2; ++h) {
      const uint4* src = (const uint4*)(p.PK_rec + ((size_t)(m * 2 + h) * 54 + nt) * PAIR_U16);
      uint4* dst = (uint4*)(ldsw + s * SLOT_U16 + h * PAIR_U16);
      for (int i = tid; i < PAIR_U16 / 8; i += 256) dst[i] = src[i];
    }
  }
  __syncthreads();

  const f32x4 z = {0.f, 0.f, 0.f, 0.f};

  if (role == 0) {
    const int fi = blk;
    for (int t = 0; t < 128; ++t) {
      int par = t & 1;
      f32x4 cc = z, hh = z;
      unit_x(p, ntA, t, mt, l, cc, hh);      // x@W0_lo, independent of h
      waitf(F4, 54, t);                       // h(t) ready
      float pv[4];
      unitS(ldsw, STP(par, 7), ntA, mt, l, cc, hh, pv);  // + h@W0_hi
      epiS(p, par, 0, ntA, mt, l, pv, 2, cc, hh);        // s0 (tanh)
      setf(F0, fi, t + 1);
      waitf(F1, 54, t + 1);
      f32x4 c2 = z, h2 = z; float p2[4];
      unitS(ldsw + SLOT_U16, STP(par, 1), ntA, mt, l, c2, h2, p2); // s1@Ws[1]
      epiS(p, par, 2, ntA, mt, l, p2, 1, c2, h2);        // s2 (relu)
      setf(F2A, fi, t + 1);
    }
    // decoder + log_softmax: blocks 0..15, one wave per batch row
    if (blk < 16) {
      waitf(F4, 54, 128);
      int b = blk * 4 + mt;
      float myval = 0.0f;
      for (int c = 0; c < 42; ++c) {
        float part = 0.0f;
        for (int d = l; d < 850; d += 64)
          part += ldc_f32(p.accr + b * 850 + d) * ldf(p.dec_W, c * 850 + d, bf);
        for (int off = 32; off > 0; off >>= 1) part += __shfl_xor(part, off);
        if (l == c) myval = part * (1.0f / 128.0f) + ldf(p.dec_b, c, bf);
      }
      float mx = (l < 42) ? myval : -INFINITY;
      for (int off = 32; off > 0; off >>= 1) mx = fmaxf(mx, __shfl_xor(mx, off));
      float ex = (l < 42) ? expf(myval - mx) : 0.0f;
      float sm = ex;
      for (int off = 32; off > 0; off >>= 1) sm += __shfl_xor(sm, off);
      if (l < 42) stout(p.out, (size_t)b * 42 + l, myval - mx - logf(sm), bf);
    }
  } else if (role == 1) {
    const int fi = blk - 54;
    for (int t = 0; t < 128; ++t) {
      int par = t & 1;
      waitf(F0, 54, t + 1);
      f32x4 cc = z, hh = z; float pv[4];
      unitS(ldsw, STP(par, 0), ntA, mt, l, cc, hh, pv);  // s0@Ws[0]
      epiS(p, par, 1, ntA, mt, l, pv, 0, cc, hh);        // s1 (sigmoid)
      setf(F1, fi, t + 1);
      f32x4 c2 = z, h2 = z; float p2[4];                 // own s1: no wait
      unitS(ldsw + SLOT_U16, STP(par, 1), ntA, mt, l, c2, h2, p2); // s1@Ws[2]
      epiS(p, par, 3, ntA, mt, l, p2, 1, c2, h2);        // s3 (relu)
      setf(F2B, fi, t + 1);
    }
  } else if (role == 2) {
    const int fi = blk - 108;
    for (int t = 0; t < 128; ++t) {
      int par = t & 1;
      waitf(F1, 54, t + 1);
      f32x4 cc = z, hh = z; float pv[4];
      unitS(ldsw + SLOT_U16, STP(par, 1), ntA, mt, l, cc, hh, pv); // s1@Ws[3]
      epiS(p, par, 4, ntA, mt, l, pv, 3, cc, hh);        // s4 (identity)
      setf(F2C, fi, t + 1);
      waitf(F2A, 54, t + 1);
      f32x4 c2 = z, h2 = z; float p2[4];
      unitS(ldsw, STP(par, 2), ntA, mt, l, c2, h2, p2);  // s2@Ws[4]
      epiS(p, par, 5, ntA, mt, l, p2, 2, c2, h2);        // s5 (tanh)
      setf(F3A, fi, t + 1);
    }
  } else if (role == 4) {
    const int fi = blk - 216;
    for (int t = 0; t < 128; ++t) {
      int par = t & 1;
      waitf(F2B, 54, t + 1);
      f32x4 cA = z, hA = z, cB = z, hB = z; float pa[4], pb[4];
      unit2S(ldsw, ldsw + SLOT_U16, STP(par, 3), ntA, ntB, mt, l,
             cA, hA, cB, hB, pa, pb);                    // s3@Ws[6], 2 nt
      epiS(p, par, 6, ntA, mt, l, pa, 2, cA, hA);        // s7 (tanh)
      epiS(p, par, 6, ntB, mt, l, pb, 2, cB, hB);
      setf(F3B, fi, t + 1);
    }
  } else { // role 3
    const int fi = blk - 162;
    float areg[4] = {0.f, 0.f, 0.f, 0.f};
    const int n = ntA * 16 + lm;
    for (int t = 0; t < 128; ++t) {
      int par = t & 1, par2 = (t + 1) & 1;
      waitf3(F2A, F2B, F2C, 54, t + 1);
      float psum[4];                                     // prefetch s1+s2+s3+s4
      {
        u16 q1[4], q2[4], q3[4], q4[4];
#pragma unroll
        for (int i = 0; i < 4; ++i) {
          size_t row = (size_t)(mt * 16 + lg * 4 + i) * 864 + n;
          q1[i] = ldc_u16(STP(par, 1) + row); q2[i] = ldc_u16(STP(par, 2) + row);
          q3[i] = ldc_u16(STP(par, 3) + row); q4[i] = ldc_u16(STP(par, 4) + row);
        }
#pragma unroll
        for (int i = 0; i < 4; ++i)
          psum[i] = bf2f(q1[i]) + bf2f(q2[i]) + bf2f(q3[i]) + bf2f(q4[i]);
      }
      waitf2(F3A, 54, F3B, 27, t + 1);
      f32x4 cA = z, hA = z, cB = z, hB = z; float s5v[4], s5d[4];
      unit2S(ldsw, ldsw + SLOT_U16, STP(par, 5), ntA, ntA, mt, l,
             cA, hA, cB, hB, s5v, s5d);                  // s5@Ws[5], s5@Ws[7]
      float s7v[4];
#pragma unroll
      for (int i = 0; i < 4; ++i)
        s7v[i] = bf2f(ldc_u16(STP(par, 6) + (size_t)(mt * 16 + lg * 4 + i) * 864 + n));
      if (n < 850) {
        u16* hdst = STP(par2, 7);
#pragma unroll
        for (int i = 0; i < 4; ++i) {
          int b = mt * 16 + lg * 4 + i;
          float s6 = s5v[i] + sigm(cA[i]) * (sigm(hA[i]) - s5v[i]);
          float s8 = s5v[i] + sigm(cB[i]) * (fmaxf(hB[i], 0.f) - s5v[i]);
          float sum = psum[i] + s5v[i] + s7v[i] + s6 + s8;
          float outv = sum * 0.125f;
          float mk = ldf(p.masks, b * 128 + t, bf);
          areg[i] += outv * mk;
          stc_u16(hdst + (size_t)b * 864 + n, f2bf(outv));
          if (t == 127) {
            stout(p.out, 2688 + (size_t)b * 850 + n, outv * mk, bf);
            stc_f32(p.accr + b * 850 + n, areg[i]);
          }
        }
      }
      setf(F4, fi, t + 1);
    }
  }
#undef STP
}

// ---------------- launch ----------------

extern "C" void kernel_launch(void* const* d_in, const int* in_sizes, int n_in,
                              void* d_out, int out_size, void* d_ws, size_t ws_size,
                              hipStream_t stream) {
  (void)in_sizes; (void)n_in; (void)out_size;
  P p;
  p.tokens = (const int*)d_in[0];
  p.masks  = d_in[1];
  p.pos    = (const int*)d_in[2];
  p.ner    = (const int*)d_in[3];
  p.hidden = d_in[4];
  p.enc_W  = d_in[5];
  p.ner_W  = d_in[6];
  p.pos_W  = d_in[7];
  p.agg_W  = d_in[8];
  p.agg_b  = d_in[9];
  p.W0     = d_in[10];
  p.Ws     = d_in[11];
  p.dec_W  = d_in[12];
  p.dec_b  = d_in[13];
  p.out    = d_out;

  unsigned char* ws = (unsigned char*)d_ws;
  p.ctrl = (int*)ws;
  unsigned char* R0 = ws + 32768;
  p.PK_agg = (unsigned short*)R0;
  p.comb   = (unsigned short*)(R0 + 1603584);
  p.PK_rec = (unsigned short*)R0;
  unsigned char* q = R0 + 29859840;
  p.xbf  = (unsigned short*)q; q += 14155776;
  p.Sbf  = (unsigned short*)q; q += 1769472;
  p.accr = (float*)q;          q += 217600;

  size_t need = (size_t)(q - ws);
  if (ws_size < need) {
    hipLaunchKernelGGL(k_diag, dim3(1), dim3(64), 0, stream, p);
    return;
  }

  static int lds_attr_set = 0;
  if (!lds_attr_set) { // host-side attribute, idempotent, graph-capture safe
    (void)hipFuncSetAttribute((const void*)k_scan,
                              hipFuncAttributeMaxDynamicSharedMemorySize, LDS_BYTES);
    lds_attr_set = 1;
  }

  hipLaunchKernelGGL(k_detect,   dim3(1),    dim3(64),  0, stream, p);
  hipLaunchKernelGGL(k_init0,    dim3(256),  dim3(256), 0, stream, p);
  hipLaunchKernelGGL(k_init1,    dim3(64),   dim3(256), 0, stream, p);
  hipLaunchKernelGGL(k_pack_agg, dim3(512),  dim3(256), 0, stream, p);
  hipLaunchKernelGGL(k_comb,     dim3(4096), dim3(256), 0, stream, p);
  hipLaunchKernelGGL(k_phaseA,   dim3(256),  dim3(256), 0, stream, p);
  hipLaunchKernelGGL(k_pack_rec, dim3(4096), dim3(256), 0, stream, p);
  hipLaunchKernelGGL(k_scan,     dim3(NBLK), dim3(256), LDS_BYTES, stream, p);
}

// Round 7
// 4858.749 us; speedup vs baseline: 9.4717x; 1.2613x over previous
//
#include <hip/hip_runtime.h>
#include <math.h>

typedef float f32x4 __attribute__((ext_vector_type(4)));
typedef short s16x8 __attribute__((ext_vector_type(8)));
typedef unsigned short u16;

#define MFMA_BF16(a,b,c) __builtin_amdgcn_mfma_f32_16x16x32_bf16((a),(b),(c),0,0,0)
#define NBLK 243
#define PAIR_U16 13824   // one half-matrix tile: 27 kb * 512
#define SLOT_U16 27648   // c+h halves
#define LDS_BYTES 110592 // 2 slots * 27648 u16 * 2B
#define ST_SLOT 55296    // u16 per state slot (64*864)

// Dataflow scan: 243 persistent blocks (1/CU), weights LDS-resident.
// State slots (bf16, [parity][slot][64][864]): 0=s0 1=s1 2=s2 3=s3 4=s4 5=s5 6=s7 7=h
// Roles: 0(blk0-53): L0->s0, L2->s2 | 1(54-107): L1->s1, L2->s3
//        2(108-161): L2->s4, L3->s5 | 3(162-215): L4->s6,s8,out,h | 4(216-242): L3->s7 (2 nt)
// Sync: per-producer-group epoch flags; consumers poll ONLY their producers.
// Cross-block state loads = inline-asm global_load_dwordx4 sc1 bursts (LLC-coherent,
// guaranteed pipelined: single vmcnt(0) drain + sched_barrier). Stores = relaxed
// agent atomics (sc1). No fences anywhere.

struct P {
  const int* tokens; const void* masks; const int* pos; const int* ner;
  const void* hidden;
  const void* enc_W; const void* ner_W; const void* pos_W;
  const void* agg_W; const void* agg_b;
  const void* W0; const void* Ws;
  const void* dec_W; const void* dec_b;
  void* out;
  unsigned short* PK_agg; unsigned short* PK_rec; unsigned short* comb;
  unsigned short* xbf; unsigned short* Sbf;
  float* accr;
  int* ctrl; // [0]=bf16 flag; flags: F0@512 F1@1024 F2A@1536 F2B@2048 F2C@2560 F3A@3072 F3B@3584 F4@4096
};

__device__ __forceinline__ unsigned short f2bf(float f) {
  union { float f; unsigned u; } v; v.f = f;
  return (unsigned short)((v.u + 0x7FFFu + ((v.u >> 16) & 1u)) >> 16);
}
__device__ __forceinline__ float bf2f(u16 x) {
  union { unsigned u; float f; } v; v.u = (unsigned)x << 16; return v.f;
}
__device__ __forceinline__ float ldf(const void* q, size_t i, int bf) {
  if (bf) return bf2f(((const u16*)q)[i]);
  return ((const float*)q)[i];
}
__device__ __forceinline__ void stout(void* o, size_t i, float v, int bf) {
  if (bf) ((u16*)o)[i] = f2bf(v);
  else    ((float*)o)[i] = v;
}
__device__ __forceinline__ float sigm(float x) { return 1.0f / (1.0f + expf(-x)); }
__device__ __forceinline__ float actf(int a, float x) {
  if (a == 0) return sigm(x);
  if (a == 1) return fmaxf(x, 0.0f);
  if (a == 2) return tanhf(x);
  return x;
}

// ---- LLC-coherent accessors ----
// 16B sc1 load, issued raw; result INVALID until vmfence(). Burst-friendly.
__device__ __forceinline__ s16x8 ldg16_sc1(const u16* p) {
  s16x8 r;
  asm volatile("global_load_dwordx4 %0, %1, off sc1" : "=v"(r) : "v"(p) : "memory");
  return r;
}
__device__ __forceinline__ void vmfence() {
  asm volatile("s_waitcnt vmcnt(0)" ::: "memory");
  __builtin_amdgcn_sched_barrier(0); // rule #18: keep MFMAs below the wait
}
__device__ __forceinline__ u16 ldc_u16(const u16* p) {
  return __hip_atomic_load(p, __ATOMIC_RELAXED, __HIP_MEMORY_SCOPE_AGENT);
}
__device__ __forceinline__ float ldc_f32(const float* p) {
  unsigned x = __hip_atomic_load((const unsigned*)p, __ATOMIC_RELAXED,
                                 __HIP_MEMORY_SCOPE_AGENT);
  union { unsigned u; float f; } v; v.u = x; return v.f;
}
__device__ __forceinline__ void stc_f32(float* p, float f) {
  union { float f; unsigned u; } v; v.f = f;
  __hip_atomic_store((unsigned*)p, v.u, __ATOMIC_RELAXED, __HIP_MEMORY_SCOPE_AGENT);
}
__device__ __forceinline__ void stc_u16(u16* p, u16 x) {
  __hip_atomic_store(p, x, __ATOMIC_RELAXED, __HIP_MEMORY_SCOPE_AGENT);
}
__device__ __forceinline__ void stc_i32(int* p, int x) {
  __hip_atomic_store(p, x, __ATOMIC_RELAXED, __HIP_MEMORY_SCOPE_AGENT);
}
__device__ __forceinline__ int ldc_i32(const int* p) {
  return __hip_atomic_load(p, __ATOMIC_RELAXED, __HIP_MEMORY_SCOPE_AGENT);
}

// Consumer wait: wave 0 polls producer-group flags; __syncthreads releases block.
__device__ __forceinline__ void waitf(const int* fl, int n, int e) {
  if (threadIdx.x < 64) {
    int l = threadIdx.x, spins = 0;
    for (;;) {
      int ok = (l < n) ? (ldc_i32(fl + l) >= e) : 1;
      if (__all(ok)) break;
      if (++spins > 4000000) break; // bounded diagnostic escape
    }
  }
  __syncthreads();
  asm volatile("" ::: "memory");
}
__device__ __forceinline__ void waitf3(const int* fa, const int* fb, const int* fc,
                                       int n, int e) {
  if (threadIdx.x < 64) {
    int l = threadIdx.x, spins = 0;
    for (;;) {
      int ok = 1;
      if (l < n) ok = (ldc_i32(fa + l) >= e) & (ldc_i32(fb + l) >= e) &
                      (ldc_i32(fc + l) >= e);
      if (__all(ok)) break;
      if (++spins > 4000000) break;
    }
  }
  __syncthreads();
  asm volatile("" ::: "memory");
}
__device__ __forceinline__ void waitf2(const int* fa, int na, const int* fb, int nb, int e) {
  if (threadIdx.x < 64) {
    int l = threadIdx.x, spins = 0;
    for (;;) {
      int ok = ((l < na) ? (ldc_i32(fa + l) >= e) : 1) &
               ((l < nb) ? (ldc_i32(fb + l) >= e) : 1);
      if (__all(ok)) break;
      if (++spins > 4000000) break;
    }
  }
  __syncthreads();
  asm volatile("" ::: "memory");
}
// Producer flag: __syncthreads drains all waves' sc1 stores (vmcnt0) first.
__device__ __forceinline__ void setf(int* fl, int idx, int e) {
  __syncthreads();
  if (threadIdx.x == 0) stc_i32(fl + idx, e);
}

// ---------------- prep kernels ----------------

__global__ void k_detect(P p) {
  for (int j = threadIdx.x; j < 8192; j += 64) p.ctrl[j] = 0;
  __syncthreads();
  if (threadIdx.x == 0) {
    const u16* u = (const u16*)p.W0;
    int good = 0;
    for (int i = 0; i < 256; ++i) {
      int e = (u[i] >> 7) & 0xFF;
      if (e >= 90 && e <= 126) ++good;
    }
    p.ctrl[0] = (good >= 192) ? 1 : 0;
  }
}

__global__ __launch_bounds__(256) void k_init0(P p) { // zero Sbf + xbf pads
  const int total = 442368 + 114688;
  for (int e = blockIdx.x * blockDim.x + threadIdx.x; e < total;
       e += gridDim.x * blockDim.x) {
    if (e < 442368) {
      ((unsigned*)p.Sbf)[e] = 0u;
    } else {
      int e4 = e - 442368; int t = e4 / 896, r = e4 % 896;
      int b = r / 14, n = 850 + r % 14;
      p.xbf[((size_t)t * 64 + b) * 864 + n] = 0;
    }
  }
}

__global__ __launch_bounds__(256) void k_init1(P p) { // h(0) -> Sbf[par0][slot7]
  const int bf = p.ctrl[0];
  for (int e = blockIdx.x * blockDim.x + threadIdx.x; e < 54400;
       e += gridDim.x * blockDim.x) {
    int b = e / 850, n = e % 850;
    p.Sbf[(size_t)7 * ST_SLOT + (size_t)b * 864 + n] = f2bf(ldf(p.hidden, e, bf));
  }
}

__global__ __launch_bounds__(256) void k_pack_agg(P p) {
  const int bf = p.ctrl[0];
  const long total = 801792L;
  for (long e = (long)blockIdx.x * blockDim.x + threadIdx.x; e < total;
       e += (long)gridDim.x * blockDim.x) {
    int j = (int)(e & 7), l = (int)((e >> 3) & 63);
    long q9 = e >> 9;
    int kb = (int)(q9 % 29), nt = (int)(q9 / 29);
    int n = nt * 16 + (l & 15);
    int k = kb * 32 + ((l >> 4) << 3) + j;
    float v = 0.0f;
    if (n < 850 && k < 910) v = ldf(p.agg_W, (size_t)n * 910 + k, bf);
    p.PK_agg[e] = f2bf(v);
  }
}

__global__ __launch_bounds__(256) void k_comb(P p) {
  const int bf = p.ctrl[0];
  const long total = 7602176L;
  for (long e = (long)blockIdx.x * blockDim.x + threadIdx.x; e < total;
       e += (long)gridDim.x * blockDim.x) {
    int k = (int)(e % 928);
    int r = (int)(e / 928);
    int t = r >> 6, b = r & 63;
    float v = 0.0f;
    if (k < 850)      { int tok = p.tokens[b * 128 + t]; v = ldf(p.enc_W, (size_t)tok * 850 + k, bf); }
    else if (k < 880) { int nv = p.ner[b * 128 + t];     v = ldf(p.ner_W, nv * 30 + (k - 850), bf); }
    else if (k < 910) { int pv = p.pos[b * 128 + t];     v = ldf(p.pos_W, pv * 30 + (k - 880), bf); }
    p.comb[e] = f2bf(v);
  }
}

__global__ __launch_bounds__(256) void k_pack_rec(P p) {
  const int bf = p.ctrl[0];
  const long total = 14929920L;
  for (long e = (long)blockIdx.x * blockDim.x + threadIdx.x; e < total;
       e += (long)gridDim.x * blockDim.x) {
    int j = (int)(e & 7), l = (int)((e >> 3) & 63);
    long q9 = e >> 9;
    int kb = (int)(q9 % 27);
    long q = q9 / 27;
    int nt = (int)(q % 54);
    int mh = (int)(q / 54);
    int half = mh & 1, mat = mh >> 1;
    int nl = nt * 16 + (l & 15);
    int col = half ? nl + 850 : nl;
    int k = kb * 32 + ((l >> 4) << 3) + j;
    float v = 0.0f;
    if (nl < 850 && k < 850) {
      if (mat == 0)      v = ldf(p.W0, (size_t)k * 1700 + col, bf);
      else if (mat == 1) v = ldf(p.W0, (size_t)(k + 850) * 1700 + col, bf);
      else               v = ldf(p.Ws, (size_t)(mat - 2) * 850 * 1700 + (size_t)k * 1700 + col, bf);
    }
    p.PK_rec[e] = f2bf(v);
  }
}

__global__ void k_diag(P p) {
  if (blockIdx.x == 0 && threadIdx.x == 0)
    for (int i = 0; i < 64; ++i) ((float*)p.out)[i] = 2000.0f;
}

__global__ __launch_bounds__(256) void k_phaseA(P p) {
  const int tid = threadIdx.x;
  const int l = tid & 63, lm = l & 15, lg = l >> 4;
  const int wid = (blockIdx.x << 2) | (tid >> 6);
  const int bf = p.ctrl[0];
  for (int u = wid; u < 512 * 54; u += 1024) {
    int mt = u / 54, nt = u - mt * 54;
    int r0 = mt << 4;
    f32x4 acc = {0.f, 0.f, 0.f, 0.f};
    const u16* Arow = p.comb + (size_t)(r0 + lm) * 928 + (size_t)lg * 8;
    const u16* Bp = p.PK_agg + (size_t)nt * 29 * 512 + (size_t)l * 8;
    for (int kb = 0; kb < 29; ++kb) {
      s16x8 a = *(const s16x8*)(Arow + (size_t)kb * 32);
      s16x8 b = *(const s16x8*)(Bp + (size_t)kb * 512);
      acc = MFMA_BF16(a, b, acc);
    }
    int n = nt * 16 + lm;
    if (n < 850) {
      float bias = ldf(p.agg_b, n, bf);
#pragma unroll
      for (int i = 0; i < 4; ++i) {
        int r = r0 + lg * 4 + i;
        p.xbf[(size_t)r * 864 + n] = f2bf(acc[i] + bias);
      }
    }
  }
}

// ---------------- scan units (asm sc1 bursts) ----------------

// A+prev burst from state slot (sc1 asm); B c/h from one LDS slot. Adds into cc,hh.
__device__ __forceinline__ void unitS(const u16* lds, const u16* st, int nt, int mt,
                                      int l, f32x4& cc, f32x4& hh, float* prev) {
  const int lm = l & 15, lg = l >> 4;
  const u16* A = st + (size_t)(mt * 16 + lm) * 864 + (size_t)lg * 8;
  s16x8 ab[27];
#pragma unroll
  for (int kb = 0; kb < 27; ++kb) ab[kb] = ldg16_sc1(A + (size_t)kb * 32);
  u16 pv[4];
#pragma unroll
  for (int i = 0; i < 4; ++i)
    pv[i] = ldc_u16(st + (size_t)(mt * 16 + lg * 4 + i) * 864 + nt * 16 + lm);
  vmfence();
  const f32x4 z = {0.f, 0.f, 0.f, 0.f};
  f32x4 c0 = z, c1 = z, h0 = z, h1 = z;
#pragma unroll
  for (int kb = 0; kb < 27; ++kb) {
    s16x8 bc = *(const s16x8*)(lds + l * 8 + (size_t)kb * 512);
    s16x8 bh = *(const s16x8*)(lds + PAIR_U16 + l * 8 + (size_t)kb * 512);
    if (kb & 1) { c1 = MFMA_BF16(ab[kb], bc, c1); h1 = MFMA_BF16(ab[kb], bh, h1); }
    else        { c0 = MFMA_BF16(ab[kb], bc, c0); h0 = MFMA_BF16(ab[kb], bh, h0); }
  }
  cc += c0 + c1; hh += h0 + h1;
#pragma unroll
  for (int i = 0; i < 4; ++i) prev[i] = bf2f(pv[i]);
}

// One shared A burst, two LDS B slots; prev at two column sets (ntA, ntB).
__device__ __forceinline__ void unit2S(const u16* lds0, const u16* lds1, const u16* st,
                                       int ntA, int ntB, int mt, int l,
                                       f32x4& cA, f32x4& hA, f32x4& cB, f32x4& hB,
                                       float* prevA, float* prevB) {
  const int lm = l & 15, lg = l >> 4;
  const u16* A = st + (size_t)(mt * 16 + lm) * 864 + (size_t)lg * 8;
  s16x8 ab[27];
#pragma unroll
  for (int kb = 0; kb < 27; ++kb) ab[kb] = ldg16_sc1(A + (size_t)kb * 32);
  u16 pa[4], pb[4];
#pragma unroll
  for (int i = 0; i < 4; ++i) {
    size_t row = (size_t)(mt * 16 + lg * 4 + i) * 864;
    pa[i] = ldc_u16(st + row + ntA * 16 + lm);
    pb[i] = ldc_u16(st + row + ntB * 16 + lm);
  }
  vmfence();
#pragma unroll
  for (int kb = 0; kb < 27; ++kb) {
    cA = MFMA_BF16(ab[kb], *(const s16x8*)(lds0 + l * 8 + (size_t)kb * 512), cA);
    hA = MFMA_BF16(ab[kb], *(const s16x8*)(lds0 + PAIR_U16 + l * 8 + (size_t)kb * 512), hA);
    cB = MFMA_BF16(ab[kb], *(const s16x8*)(lds1 + l * 8 + (size_t)kb * 512), cB);
    hB = MFMA_BF16(ab[kb], *(const s16x8*)(lds1 + PAIR_U16 + l * 8 + (size_t)kb * 512), hB);
  }
#pragma unroll
  for (int i = 0; i < 4; ++i) { prevA[i] = bf2f(pa[i]); prevB[i] = bf2f(pb[i]); }
}

// x-part of L0: plain loads (L2-hot), B = W0_lo c/h from global PK_rec.
__device__ __forceinline__ void unit_x(const P& p, int nt, int t, int mt, int l,
                                       f32x4& cc, f32x4& hh) {
  const int lm = l & 15, lg = l >> 4;
  const u16* Ax = p.xbf + ((size_t)t * 64 + mt * 16 + lm) * 864 + (size_t)lg * 8;
  const u16* B0 = p.PK_rec + (size_t)(0 * 54 + nt) * PAIR_U16 + l * 8;
  const u16* B1 = p.PK_rec + (size_t)(1 * 54 + nt) * PAIR_U16 + l * 8;
  s16x8 ab[27];
#pragma unroll
  for (int kb = 0; kb < 27; ++kb) ab[kb] = *(const s16x8*)(Ax + (size_t)kb * 32);
  const f32x4 z = {0.f, 0.f, 0.f, 0.f};
  f32x4 c0 = z, c1 = z, h0 = z, h1 = z;
#pragma unroll
  for (int kb = 0; kb < 27; ++kb) {
    s16x8 bc = *(const s16x8*)(B0 + (size_t)kb * 512);
    s16x8 bh = *(const s16x8*)(B1 + (size_t)kb * 512);
    if (kb & 1) { c1 = MFMA_BF16(ab[kb], bc, c1); h1 = MFMA_BF16(ab[kb], bh, h1); }
    else        { c0 = MFMA_BF16(ab[kb], bc, c0); h0 = MFMA_BF16(ab[kb], bh, h0); }
  }
  cc += c0 + c1; hh += h0 + h1;
}

// gates + bf16 state store
__device__ __forceinline__ void epiS(const P& p, int par, int slot, int nt, int mt,
                                     int l, const float* prev, int act,
                                     f32x4 c, f32x4 h) {
  int lm = l & 15, lg = l >> 4, n = nt * 16 + lm;
  if (n >= 850) return;
  u16* dst = p.Sbf + (size_t)(par * 8 + slot) * ST_SLOT;
#pragma unroll
  for (int i = 0; i < 4; ++i) {
    int b = mt * 16 + lg * 4 + i;
    float s = prev[i] + sigm(c[i]) * (actf(act, h[i]) - prev[i]);
    stc_u16(dst + (size_t)b * 864 + n, f2bf(s));
  }
}

__global__ __launch_bounds__(256, 1) void k_scan(P p) {
  extern __shared__ u16 ldsw[];
  const int tid = threadIdx.x;
  const int l = tid & 63, lm = l & 15, lg = l >> 4, mt = tid >> 6;
  const int blk = blockIdx.x;
  const int bf = p.ctrl[0];
  int* F0  = p.ctrl + 512;  int* F1  = p.ctrl + 1024;
  int* F2A = p.ctrl + 1536; int* F2B = p.ctrl + 2048; int* F2C = p.ctrl + 2560;
  int* F3A = p.ctrl + 3072; int* F3B = p.ctrl + 3584; int* F4  = p.ctrl + 4096;
#define STP(par, slot) (p.Sbf + (size_t)((par) * 8 + (slot)) * ST_SLOT)

  int role, matA, ntA, matB, ntB;
  if (blk < 54)       { role = 0; matA = 1; ntA = blk;       matB = 3; ntB = ntA; }
  else if (blk < 108) { role = 1; matA = 2; ntA = blk - 54;  matB = 4; ntB = ntA; }
  else if (blk < 162) { role = 2; matA = 6; ntA = blk - 108; matB = 5; ntB = ntA; }
  else if (blk < 216) { role = 3; matA = 7; ntA = blk - 162; matB = 9; ntB = ntA; }
  else                { role = 4; matA = 8; ntA = 2 * (blk - 216); matB = 8; ntB = ntA + 1; }

  // stage this block's two weight pairs into LDS
  for (int s = 0; s < 2; ++s) {
    int m = s ? matB : matA, nt = s ? ntB : ntA;
    for (int h = 0; h < 2; ++h) {
      const uint4* src = (const uint4*)(p.PK_rec + ((size_t)(m * 2 + h) * 54 + nt) * PAIR_U16);
      uint4* dst = (uint4*)(ldsw + s * SLOT_U16 + h * PAIR_U16);
      for (int i = tid; i < PAIR_U16 / 8; i += 256) dst[i] = src[i];
    }
  }
  __syncthreads();

  const f32x4 z = {0.f, 0.f, 0.f, 0.f};

  if (role == 0) {
    const int fi = blk;
    for (int t = 0; t < 128; ++t) {
      int par = t & 1;
      f32x4 cc = z, hh = z;
      unit_x(p, ntA, t, mt, l, cc, hh);      // x@W0_lo, independent of h
      waitf(F4, 54, t);                       // h(t) ready
      float pv[4];
      unitS(ldsw, STP(par, 7), ntA, mt, l, cc, hh, pv);  // + h@W0_hi
      epiS(p, par, 0, ntA, mt, l, pv, 2, cc, hh);        // s0 (tanh)
      setf(F0, fi, t + 1);
      waitf(F1, 54, t + 1);
      f32x4 c2 = z, h2 = z; float p2[4];
      unitS(ldsw + SLOT_U16, STP(par, 1), ntA, mt, l, c2, h2, p2); // s1@Ws[1]
      epiS(p, par, 2, ntA, mt, l, p2, 1, c2, h2);        // s2 (relu)
      setf(F2A, fi, t + 1);
    }
    // decoder + log_softmax: blocks 0..15, one wave per batch row
    if (blk < 16) {
      waitf(F4, 54, 128);
      int b = blk * 4 + mt;
      float myval = 0.0f;
      for (int c = 0; c < 42; ++c) {
        float part = 0.0f;
        for (int d = l; d < 850; d += 64)
          part += ldc_f32(p.accr + b * 850 + d) * ldf(p.dec_W, c * 850 + d, bf);
        for (int off = 32; off > 0; off >>= 1) part += __shfl_xor(part, off);
        if (l == c) myval = part * (1.0f / 128.0f) + ldf(p.dec_b, c, bf);
      }
      float mx = (l < 42) ? myval : -INFINITY;
      for (int off = 32; off > 0; off >>= 1) mx = fmaxf(mx, __shfl_xor(mx, off));
      float ex = (l < 42) ? expf(myval - mx) : 0.0f;
      float sm = ex;
      for (int off = 32; off > 0; off >>= 1) sm += __shfl_xor(sm, off);
      if (l < 42) stout(p.out, (size_t)b * 42 + l, myval - mx - logf(sm), bf);
    }
  } else if (role == 1) {
    const int fi = blk - 54;
    for (int t = 0; t < 128; ++t) {
      int par = t & 1;
      waitf(F0, 54, t + 1);
      f32x4 cc = z, hh = z; float pv[4];
      unitS(ldsw, STP(par, 0), ntA, mt, l, cc, hh, pv);  // s0@Ws[0]
      epiS(p, par, 1, ntA, mt, l, pv, 0, cc, hh);        // s1 (sigmoid)
      setf(F1, fi, t + 1);
      f32x4 c2 = z, h2 = z; float p2[4];                 // own s1: no wait
      unitS(ldsw + SLOT_U16, STP(par, 1), ntA, mt, l, c2, h2, p2); // s1@Ws[2]
      epiS(p, par, 3, ntA, mt, l, p2, 1, c2, h2);        // s3 (relu)
      setf(F2B, fi, t + 1);
    }
  } else if (role == 2) {
    const int fi = blk - 108;
    for (int t = 0; t < 128; ++t) {
      int par = t & 1;
      waitf(F1, 54, t + 1);
      f32x4 cc = z, hh = z; float pv[4];
      unitS(ldsw + SLOT_U16, STP(par, 1), ntA, mt, l, cc, hh, pv); // s1@Ws[3]
      epiS(p, par, 4, ntA, mt, l, pv, 3, cc, hh);        // s4 (identity)
      setf(F2C, fi, t + 1);
      waitf(F2A, 54, t + 1);
      f32x4 c2 = z, h2 = z; float p2[4];
      unitS(ldsw, STP(par, 2), ntA, mt, l, c2, h2, p2);  // s2@Ws[4]
      epiS(p, par, 5, ntA, mt, l, p2, 2, c2, h2);        // s5 (tanh)
      setf(F3A, fi, t + 1);
    }
  } else if (role == 4) {
    const int fi = blk - 216;
    for (int t = 0; t < 128; ++t) {
      int par = t & 1;
      waitf(F2B, 54, t + 1);
      f32x4 cA = z, hA = z, cB = z, hB = z; float pa[4], pb[4];
      unit2S(ldsw, ldsw + SLOT_U16, STP(par, 3), ntA, ntB, mt, l,
             cA, hA, cB, hB, pa, pb);                    // s3@Ws[6], 2 nt
      epiS(p, par, 6, ntA, mt, l, pa, 2, cA, hA);        // s7 (tanh)
      epiS(p, par, 6, ntB, mt, l, pb, 2, cB, hB);
      setf(F3B, fi, t + 1);
    }
  } else { // role 3
    const int fi = blk - 162;
    float areg[4] = {0.f, 0.f, 0.f, 0.f};
    const int n = ntA * 16 + lm;
    for (int t = 0; t < 128; ++t) {
      int par = t & 1, par2 = (t + 1) & 1;
      waitf3(F2A, F2B, F2C, 54, t + 1);
      float psum[4];                                     // prefetch s1+s2+s3+s4
      {
        u16 q1[4], q2[4], q3[4], q4[4];
#pragma unroll
        for (int i = 0; i < 4; ++i) {
          size_t row = (size_t)(mt * 16 + lg * 4 + i) * 864 + n;
          q1[i] = ldc_u16(STP(par, 1) + row); q2[i] = ldc_u16(STP(par, 2) + row);
          q3[i] = ldc_u16(STP(par, 3) + row); q4[i] = ldc_u16(STP(par, 4) + row);
        }
#pragma unroll
        for (int i = 0; i < 4; ++i)
          psum[i] = bf2f(q1[i]) + bf2f(q2[i]) + bf2f(q3[i]) + bf2f(q4[i]);
      }
      waitf2(F3A, 54, F3B, 27, t + 1);
      u16 q7[4];                                         // s7 loads ride the burst
#pragma unroll
      for (int i = 0; i < 4; ++i)
        q7[i] = ldc_u16(STP(par, 6) + (size_t)(mt * 16 + lg * 4 + i) * 864 + n);
      f32x4 cA = z, hA = z, cB = z, hB = z; float s5v[4], s5d[4];
      unit2S(ldsw, ldsw + SLOT_U16, STP(par, 5), ntA, ntA, mt, l,
             cA, hA, cB, hB, s5v, s5d);                  // s5@Ws[5], s5@Ws[7]
      if (n < 850) {
        u16* hdst = STP(par2, 7);
#pragma unroll
        for (int i = 0; i < 4; ++i) {
          int b = mt * 16 + lg * 4 + i;
          float s6 = s5v[i] + sigm(cA[i]) * (sigm(hA[i]) - s5v[i]);
          float s8 = s5v[i] + sigm(cB[i]) * (fmaxf(hB[i], 0.f) - s5v[i]);
          float sum = psum[i] + s5v[i] + bf2f(q7[i]) + s6 + s8;
          float outv = sum * 0.125f;
          float mk = ldf(p.masks, b * 128 + t, bf);
          areg[i] += outv * mk;
          stc_u16(hdst + (size_t)b * 864 + n, f2bf(outv));
          if (t == 127) {
            stout(p.out, 2688 + (size_t)b * 850 + n, outv * mk, bf);
            stc_f32(p.accr + b * 850 + n, areg[i]);
          }
        }
      }
      setf(F4, fi, t + 1);
    }
  }
#undef STP
}

// ---------------- launch ----------------

extern "C" void kernel_launch(void* const* d_in, const int* in_sizes, int n_in,
                              void* d_out, int out_size, void* d_ws, size_t ws_size,
                              hipStream_t stream) {
  (void)in_sizes; (void)n_in; (void)out_size;
  P p;
  p.tokens = (const int*)d_in[0];
  p.masks  = d_in[1];
  p.pos    = (const int*)d_in[2];
  p.ner    = (const int*)d_in[3];
  p.hidden = d_in[4];
  p.enc_W  = d_in[5];
  p.ner_W  = d_in[6];
  p.pos_W  = d_in[7];
  p.agg_W  = d_in[8];
  p.agg_b  = d_in[9];
  p.W0     = d_in[10];
  p.Ws     = d_in[11];
  p.dec_W  = d_in[12];
  p.dec_b  = d_in[13];
  p.out    = d_out;

  unsigned char* ws = (unsigned char*)d_ws;
  p.ctrl = (int*)ws;
  unsigned char* R0 = ws + 32768;
  p.PK_agg = (unsigned short*)R0;
  p.comb   = (unsigned short*)(R0 + 1603584);
  p.PK_rec = (unsigned short*)R0;
  unsigned char* q = R0 + 29859840;
  p.xbf  = (unsigned short*)q; q += 14155776;
  p.Sbf  = (unsigned short*)q; q += 1769472;
  p.accr = (float*)q;          q += 217600;

  size_t need = (size_t)(q - ws);
  if (ws_size < need) {
    hipLaunchKernelGGL(k_diag, dim3(1), dim3(64), 0, stream, p);
    return;
  }

  static int lds_attr_set = 0;
  if (!lds_attr_set) { // host-side attribute, idempotent, graph-capture safe
    (void)hipFuncSetAttribute((const void*)k_scan,
                              hipFuncAttributeMaxDynamicSharedMemorySize, LDS_BYTES);
    lds_attr_set = 1;
  }

  hipLaunchKernelGGL(k_detect,   dim3(1),    dim3(64),  0, stream, p);
  hipLaunchKernelGGL(k_init0,    dim3(256),  dim3(256), 0, stream, p);
  hipLaunchKernelGGL(k_init1,    dim3(64),   dim3(256), 0, stream, p);
  hipLaunchKernelGGL(k_pack_agg, dim3(512),  dim3(256), 0, stream, p);
  hipLaunchKernelGGL(k_comb,     dim3(4096), dim3(256), 0, stream, p);
  hipLaunchKernelGGL(k_phaseA,   dim3(256),  dim3(256), 0, stream, p);
  hipLaunchKernelGGL(k_pack_rec, dim3(4096), dim3(256), 0, stream, p);
  hipLaunchKernelGGL(k_scan,     dim3(NBLK), dim3(256), LDS_BYTES, stream, p);
}

// Round 8
// 4674.348 us; speedup vs baseline: 9.8453x; 1.0394x over previous
//
#include <hip/hip_runtime.h>
#include <math.h>

typedef float f32x4 __attribute__((ext_vector_type(4)));
typedef short s16x8 __attribute__((ext_vector_type(8)));
typedef unsigned short u16;

#define MFMA_BF16(a,b,c) __builtin_amdgcn_mfma_f32_16x16x32_bf16((a),(b),(c),0,0,0)
#define NBLK 243
#define PAIR_U16 13824   // one half-matrix tile: 27 kb * 512
#define SLOT_U16 27648   // c+h halves
#define LDS_BYTES 110592 // 2 slots * 27648 u16 * 2B
#define ST_SLOT 55296    // u16 per state slot (54 nt * 64 rows * 16 cols)

// Dataflow scan: 243 persistent blocks (1/CU), weights LDS-resident.
// State (bf16) [parity][slot][nt][64][16]: slots 0=s0 1=s1 2=s2 3=s3 4=s4 5=s5 6=s7 7=h
// Tile-contiguous: producer tile = 2KB contiguous (full-line HBM write-through);
// consumer A-fragment (row, k..k+7) = 16B contiguous.
// Roles: 0(blk0-53): L0->s0, L2->s2 | 1(54-107): L1->s1, L2->s3
//        2(108-161): L2->s4, L3->s5 | 3(162-215): L4->s6,s8,out,h | 4(216-242): L3->s7 (2 nt)
// Sync: PER-WAVE epoch flags F[group][mt][fi] (wave mt only touches rows mt*16..+15,
// so the 4 m-tile pipelines are independent; no __syncthreads in the scan loop).
// Loads = inline-asm global_load_dwordx4 sc1 bursts; stores = relaxed agent atomics.

struct P {
  const int* tokens; const void* masks; const int* pos; const int* ner;
  const void* hidden;
  const void* enc_W; const void* ner_W; const void* pos_W;
  const void* agg_W; const void* agg_b;
  const void* W0; const void* Ws;
  const void* dec_W; const void* dec_b;
  void* out;
  unsigned short* PK_agg; unsigned short* PK_rec; unsigned short* comb;
  unsigned short* xbf; unsigned short* Sbf;
  float* accr;
  int* ctrl; // [0]=bf16 flag; flags at 512: F[g][mt][fi], stride 64 per (g,mt)
};

#define FB(pp, g, mtv) ((pp).ctrl + 512 + (((g) * 4 + (mtv)) * 64))

__device__ __forceinline__ unsigned short f2bf(float f) {
  union { float f; unsigned u; } v; v.f = f;
  return (unsigned short)((v.u + 0x7FFFu + ((v.u >> 16) & 1u)) >> 16);
}
__device__ __forceinline__ float bf2f(u16 x) {
  union { unsigned u; float f; } v; v.u = (unsigned)x << 16; return v.f;
}
__device__ __forceinline__ float ldf(const void* q, size_t i, int bf) {
  if (bf) return bf2f(((const u16*)q)[i]);
  return ((const float*)q)[i];
}
__device__ __forceinline__ void stout(void* o, size_t i, float v, int bf) {
  if (bf) ((u16*)o)[i] = f2bf(v);
  else    ((float*)o)[i] = v;
}
__device__ __forceinline__ float sigm(float x) { return 1.0f / (1.0f + expf(-x)); }
__device__ __forceinline__ float actf(int a, float x) {
  if (a == 0) return sigm(x);
  if (a == 1) return fmaxf(x, 0.0f);
  if (a == 2) return tanhf(x);
  return x;
}

// ---- LLC-coherent accessors ----
__device__ __forceinline__ s16x8 ldg16_sc1(const u16* p) {
  s16x8 r;
  asm volatile("global_load_dwordx4 %0, %1, off sc1" : "=v"(r) : "v"(p) : "memory");
  return r;
}
__device__ __forceinline__ void vmfence() {
  asm volatile("s_waitcnt vmcnt(0)" ::: "memory");
  __builtin_amdgcn_sched_barrier(0); // rule #18
}
__device__ __forceinline__ u16 ldc_u16(const u16* p) {
  return __hip_atomic_load(p, __ATOMIC_RELAXED, __HIP_MEMORY_SCOPE_AGENT);
}
__device__ __forceinline__ float ldc_f32(const float* p) {
  unsigned x = __hip_atomic_load((const unsigned*)p, __ATOMIC_RELAXED,
                                 __HIP_MEMORY_SCOPE_AGENT);
  union { unsigned u; float f; } v; v.u = x; return v.f;
}
__device__ __forceinline__ void stc_f32(float* p, float f) {
  union { float f; unsigned u; } v; v.f = f;
  __hip_atomic_store((unsigned*)p, v.u, __ATOMIC_RELAXED, __HIP_MEMORY_SCOPE_AGENT);
}
__device__ __forceinline__ void stc_u16(u16* p, u16 x) {
  __hip_atomic_store(p, x, __ATOMIC_RELAXED, __HIP_MEMORY_SCOPE_AGENT);
}
__device__ __forceinline__ void stc_i32(int* p, int x) {
  __hip_atomic_store(p, x, __ATOMIC_RELAXED, __HIP_MEMORY_SCOPE_AGENT);
}
__device__ __forceinline__ int ldc_i32(const int* p) {
  return __hip_atomic_load(p, __ATOMIC_RELAXED, __HIP_MEMORY_SCOPE_AGENT);
}

// ---- per-wave sync ----
// Producer: drain own wave's stores, then lane0 sets flag.
__device__ __forceinline__ void setfW(int* fb, int fi, int e) {
  asm volatile("s_waitcnt vmcnt(0)" ::: "memory");
  if ((threadIdx.x & 63) == 0) stc_i32(fb + fi, e);
}
// Consumer: this wave's lanes poll producer-group flags.
__device__ __forceinline__ void waitW(const int* fb, int n, int e) {
  int l = threadIdx.x & 63, spins = 0;
  for (;;) {
    int ok = (l < n) ? (ldc_i32(fb + l) >= e) : 1;
    if (__all(ok)) break;
    if (++spins > 4000000) break; // bounded diagnostic escape
  }
  asm volatile("" ::: "memory");
}
__device__ __forceinline__ void waitW2(const int* fa, int na, const int* fb, int nb, int e) {
  int l = threadIdx.x & 63, spins = 0;
  for (;;) {
    int ok = ((l < na) ? (ldc_i32(fa + l) >= e) : 1) &
             ((l < nb) ? (ldc_i32(fb + l) >= e) : 1);
    if (__all(ok)) break;
    if (++spins > 4000000) break;
  }
  asm volatile("" ::: "memory");
}
__device__ __forceinline__ void waitW3(const int* fa, const int* fb, const int* fc,
                                       int n, int e) {
  int l = threadIdx.x & 63, spins = 0;
  for (;;) {
    int ok = 1;
    if (l < n) ok = (ldc_i32(fa + l) >= e) & (ldc_i32(fb + l) >= e) &
                    (ldc_i32(fc + l) >= e);
    if (__all(ok)) break;
    if (++spins > 4000000) break;
  }
  asm volatile("" ::: "memory");
}

// ---------------- prep kernels ----------------

__global__ void k_detect(P p) {
  for (int j = threadIdx.x; j < 8192; j += 64) p.ctrl[j] = 0;
  __syncthreads();
  if (threadIdx.x == 0) {
    const u16* u = (const u16*)p.W0;
    int good = 0;
    for (int i = 0; i < 256; ++i) {
      int e = (u[i] >> 7) & 0xFF;
      if (e >= 90 && e <= 126) ++good;
    }
    p.ctrl[0] = (good >= 192) ? 1 : 0;
  }
}

__global__ __launch_bounds__(256) void k_init0(P p) { // zero Sbf + xbf pads
  const int total = 442368 + 114688;
  for (int e = blockIdx.x * blockDim.x + threadIdx.x; e < total;
       e += gridDim.x * blockDim.x) {
    if (e < 442368) {
      ((unsigned*)p.Sbf)[e] = 0u;
    } else {
      int e4 = e - 442368; int t = e4 / 896, r = e4 % 896;
      int b = r / 14, n = 850 + r % 14;
      p.xbf[((size_t)t * 64 + b) * 864 + n] = 0;
    }
  }
}

__global__ __launch_bounds__(256) void k_init1(P p) { // h(0) -> slot7 par0, new layout
  const int bf = p.ctrl[0];
  for (int e = blockIdx.x * blockDim.x + threadIdx.x; e < 54400;
       e += gridDim.x * blockDim.x) {
    int b = e / 850, n = e % 850;
    p.Sbf[(size_t)7 * ST_SLOT + (((size_t)(n >> 4) * 64 + b) << 4) + (n & 15)] =
        f2bf(ldf(p.hidden, e, bf));
  }
}

__global__ __launch_bounds__(256) void k_pack_agg(P p) {
  const int bf = p.ctrl[0];
  const long total = 801792L;
  for (long e = (long)blockIdx.x * blockDim.x + threadIdx.x; e < total;
       e += (long)gridDim.x * blockDim.x) {
    int j = (int)(e & 7), l = (int)((e >> 3) & 63);
    long q9 = e >> 9;
    int kb = (int)(q9 % 29), nt = (int)(q9 / 29);
    int n = nt * 16 + (l & 15);
    int k = kb * 32 + ((l >> 4) << 3) + j;
    float v = 0.0f;
    if (n < 850 && k < 910) v = ldf(p.agg_W, (size_t)n * 910 + k, bf);
    p.PK_agg[e] = f2bf(v);
  }
}

__global__ __launch_bounds__(256) void k_comb(P p) {
  const int bf = p.ctrl[0];
  const long total = 7602176L;
  for (long e = (long)blockIdx.x * blockDim.x + threadIdx.x; e < total;
       e += (long)gridDim.x * blockDim.x) {
    int k = (int)(e % 928);
    int r = (int)(e / 928);
    int t = r >> 6, b = r & 63;
    float v = 0.0f;
    if (k < 850)      { int tok = p.tokens[b * 128 + t]; v = ldf(p.enc_W, (size_t)tok * 850 + k, bf); }
    else if (k < 880) { int nv = p.ner[b * 128 + t];     v = ldf(p.ner_W, nv * 30 + (k - 850), bf); }
    else if (k < 910) { int pv = p.pos[b * 128 + t];     v = ldf(p.pos_W, pv * 30 + (k - 880), bf); }
    p.comb[e] = f2bf(v);
  }
}

__global__ __launch_bounds__(256) void k_pack_rec(P p) {
  const int bf = p.ctrl[0];
  const long total = 14929920L;
  for (long e = (long)blockIdx.x * blockDim.x + threadIdx.x; e < total;
       e += (long)gridDim.x * blockDim.x) {
    int j = (int)(e & 7), l = (int)((e >> 3) & 63);
    long q9 = e >> 9;
    int kb = (int)(q9 % 27);
    long q = q9 / 27;
    int nt = (int)(q % 54);
    int mh = (int)(q / 54);
    int half = mh & 1, mat = mh >> 1;
    int nl = nt * 16 + (l & 15);
    int col = half ? nl + 850 : nl;
    int k = kb * 32 + ((l >> 4) << 3) + j;
    float v = 0.0f;
    if (nl < 850 && k < 850) {
      if (mat == 0)      v = ldf(p.W0, (size_t)k * 1700 + col, bf);
      else if (mat == 1) v = ldf(p.W0, (size_t)(k + 850) * 1700 + col, bf);
      else               v = ldf(p.Ws, (size_t)(mat - 2) * 850 * 1700 + (size_t)k * 1700 + col, bf);
    }
    p.PK_rec[e] = f2bf(v);
  }
}

__global__ void k_diag(P p) {
  if (blockIdx.x == 0 && threadIdx.x == 0)
    for (int i = 0; i < 64; ++i) ((float*)p.out)[i] = 2000.0f;
}

__global__ __launch_bounds__(256) void k_phaseA(P p) {
  const int tid = threadIdx.x;
  const int l = tid & 63, lm = l & 15, lg = l >> 4;
  const int wid = (blockIdx.x << 2) | (tid >> 6);
  const int bf = p.ctrl[0];
  for (int u = wid; u < 512 * 54; u += 1024) {
    int mt = u / 54, nt = u - mt * 54;
    int r0 = mt << 4;
    f32x4 acc = {0.f, 0.f, 0.f, 0.f};
    const u16* Arow = p.comb + (size_t)(r0 + lm) * 928 + (size_t)lg * 8;
    const u16* Bp = p.PK_agg + (size_t)nt * 29 * 512 + (size_t)l * 8;
    for (int kb = 0; kb < 29; ++kb) {
      s16x8 a = *(const s16x8*)(Arow + (size_t)kb * 32);
      s16x8 b = *(const s16x8*)(Bp + (size_t)kb * 512);
      acc = MFMA_BF16(a, b, acc);
    }
    int n = nt * 16 + lm;
    if (n < 850) {
      float bias = ldf(p.agg_b, n, bf);
#pragma unroll
      for (int i = 0; i < 4; ++i) {
        int r = r0 + lg * 4 + i;
        p.xbf[(size_t)r * 864 + n] = f2bf(acc[i] + bias);
      }
    }
  }
}

// ---------------- scan units ----------------

// A burst from tiled state slot: fragment (row, k..k+7) at ((2kb+(lg>>1))*64+row)*16+(lg&1)*8
__device__ __forceinline__ void burstA(const u16* st, int mt, int l, s16x8* ab) {
  const int lm = l & 15, lg = l >> 4;
  const int row = mt * 16 + lm;
  const u16* A = st + (((size_t)(lg >> 1) * 64 + row) << 4) + ((lg & 1) << 3);
#pragma unroll
  for (int kb = 0; kb < 27; ++kb) ab[kb] = ldg16_sc1(A + (size_t)kb * 2048);
}

// A+prev from state slot (sc1); B c/h from one LDS slot. Adds into cc,hh.
__device__ __forceinline__ void unitS(const u16* lds, const u16* st, int nt, int mt,
                                      int l, f32x4& cc, f32x4& hh, float* prev) {
  const int lm = l & 15, lg = l >> 4;
  s16x8 ab[27];
  burstA(st, mt, l, ab);
  u16 pv[4];
#pragma unroll
  for (int i = 0; i < 4; ++i)
    pv[i] = ldc_u16(st + (((size_t)nt * 64 + mt * 16 + lg * 4 + i) << 4) + lm);
  vmfence();
  const f32x4 z = {0.f, 0.f, 0.f, 0.f};
  f32x4 c0 = z, c1 = z, h0 = z, h1 = z;
#pragma unroll
  for (int kb = 0; kb < 27; ++kb) {
    s16x8 bc = *(const s16x8*)(lds + l * 8 + (size_t)kb * 512);
    s16x8 bh = *(const s16x8*)(lds + PAIR_U16 + l * 8 + (size_t)kb * 512);
    if (kb & 1) { c1 = MFMA_BF16(ab[kb], bc, c1); h1 = MFMA_BF16(ab[kb], bh, h1); }
    else        { c0 = MFMA_BF16(ab[kb], bc, c0); h0 = MFMA_BF16(ab[kb], bh, h0); }
  }
  cc += c0 + c1; hh += h0 + h1;
#pragma unroll
  for (int i = 0; i < 4; ++i) prev[i] = bf2f(pv[i]);
}

// One shared A burst, two LDS B slots; prev at two column tiles (ntA, ntB).
__device__ __forceinline__ void unit2S(const u16* lds0, const u16* lds1, const u16* st,
                                       int ntA, int ntB, int mt, int l,
                                       f32x4& cA, f32x4& hA, f32x4& cB, f32x4& hB,
                                       float* prevA, float* prevB) {
  const int lm = l & 15, lg = l >> 4;
  s16x8 ab[27];
  burstA(st, mt, l, ab);
  u16 pa[4], pb[4];
#pragma unroll
  for (int i = 0; i < 4; ++i) {
    size_t row = mt * 16 + lg * 4 + i;
    pa[i] = ldc_u16(st + (((size_t)ntA * 64 + row) << 4) + lm);
    pb[i] = ldc_u16(st + (((size_t)ntB * 64 + row) << 4) + lm);
  }
  vmfence();
#pragma unroll
  for (int kb = 0; kb < 27; ++kb) {
    cA = MFMA_BF16(ab[kb], *(const s16x8*)(lds0 + l * 8 + (size_t)kb * 512), cA);
    hA = MFMA_BF16(ab[kb], *(const s16x8*)(lds0 + PAIR_U16 + l * 8 + (size_t)kb * 512), hA);
    cB = MFMA_BF16(ab[kb], *(const s16x8*)(lds1 + l * 8 + (size_t)kb * 512), cB);
    hB = MFMA_BF16(ab[kb], *(const s16x8*)(lds1 + PAIR_U16 + l * 8 + (size_t)kb * 512), hB);
  }
#pragma unroll
  for (int i = 0; i < 4; ++i) { prevA[i] = bf2f(pa[i]); prevB[i] = bf2f(pb[i]); }
}

// x-part of L0: plain loads (L2-hot), B = W0_lo c/h from global PK_rec.
__device__ __forceinline__ void unit_x(const P& p, int nt, int t, int mt, int l,
                                       f32x4& cc, f32x4& hh) {
  const int lm = l & 15, lg = l >> 4;
  const u16* Ax = p.xbf + ((size_t)t * 64 + mt * 16 + lm) * 864 + (size_t)lg * 8;
  const u16* B0 = p.PK_rec + (size_t)(0 * 54 + nt) * PAIR_U16 + l * 8;
  const u16* B1 = p.PK_rec + (size_t)(1 * 54 + nt) * PAIR_U16 + l * 8;
  s16x8 ab[27];
#pragma unroll
  for (int kb = 0; kb < 27; ++kb) ab[kb] = *(const s16x8*)(Ax + (size_t)kb * 32);
  const f32x4 z = {0.f, 0.f, 0.f, 0.f};
  f32x4 c0 = z, c1 = z, h0 = z, h1 = z;
#pragma unroll
  for (int kb = 0; kb < 27; ++kb) {
    s16x8 bc = *(const s16x8*)(B0 + (size_t)kb * 512);
    s16x8 bh = *(const s16x8*)(B1 + (size_t)kb * 512);
    if (kb & 1) { c1 = MFMA_BF16(ab[kb], bc, c1); h1 = MFMA_BF16(ab[kb], bh, h1); }
    else        { c0 = MFMA_BF16(ab[kb], bc, c0); h0 = MFMA_BF16(ab[kb], bh, h0); }
  }
  cc += c0 + c1; hh += h0 + h1;
}

// gates + bf16 state store (tiled layout)
__device__ __forceinline__ void epiS(const P& p, int par, int slot, int nt, int mt,
                                     int l, const float* prev, int act,
                                     f32x4 c, f32x4 h) {
  int lm = l & 15, lg = l >> 4, n = nt * 16 + lm;
  if (n >= 850) return;
  u16* dst = p.Sbf + (size_t)(par * 8 + slot) * ST_SLOT;
#pragma unroll
  for (int i = 0; i < 4; ++i) {
    size_t row = mt * 16 + lg * 4 + i;
    float s = prev[i] + sigm(c[i]) * (actf(act, h[i]) - prev[i]);
    stc_u16(dst + (((size_t)nt * 64 + row) << 4) + lm, f2bf(s));
  }
}

__global__ __launch_bounds__(256, 1) void k_scan(P p) {
  extern __shared__ u16 ldsw[];
  const int tid = threadIdx.x;
  const int l = tid & 63, lm = l & 15, lg = l >> 4, mt = tid >> 6;
  const int blk = blockIdx.x;
  const int bf = p.ctrl[0];
#define STP(par, slot) (p.Sbf + (size_t)((par) * 8 + (slot)) * ST_SLOT)

  int role, matA, ntA, matB, ntB;
  if (blk < 54)       { role = 0; matA = 1; ntA = blk;       matB = 3; ntB = ntA; }
  else if (blk < 108) { role = 1; matA = 2; ntA = blk - 54;  matB = 4; ntB = ntA; }
  else if (blk < 162) { role = 2; matA = 6; ntA = blk - 108; matB = 5; ntB = ntA; }
  else if (blk < 216) { role = 3; matA = 7; ntA = blk - 162; matB = 9; ntB = ntA; }
  else                { role = 4; matA = 8; ntA = 2 * (blk - 216); matB = 8; ntB = ntA + 1; }

  // stage this block's two weight pairs into LDS (only block-level sync, pre-loop)
  for (int s = 0; s < 2; ++s) {
    int m = s ? matB : matA, nt = s ? ntB : ntA;
    for (int h = 0; h < 2; ++h) {
      const uint4* src = (const uint4*)(p.PK_rec + ((size_t)(m * 2 + h) * 54 + nt) * PAIR_U16);
      uint4* dst = (uint4*)(ldsw + s * SLOT_U16 + h * PAIR_U16);
      for (int i = tid; i < PAIR_U16 / 8; i += 256) dst[i] = src[i];
    }
  }
  __syncthreads();

  const f32x4 z = {0.f, 0.f, 0.f, 0.f};

  if (role == 0) {
    const int fi = blk;
    for (int t = 0; t < 128; ++t) {
      int par = t & 1;
      f32x4 cc = z, hh = z;
      unit_x(p, ntA, t, mt, l, cc, hh);      // x@W0_lo, overlaps the F4 wait
      waitW(FB(p, 7, mt), 54, t);             // h(t) ready (this m-tile)
      float pv[4];
      unitS(ldsw, STP(par, 7), ntA, mt, l, cc, hh, pv);  // + h@W0_hi
      epiS(p, par, 0, ntA, mt, l, pv, 2, cc, hh);        // s0 (tanh)
      setfW(FB(p, 0, mt), fi, t + 1);
      waitW(FB(p, 1, mt), 54, t + 1);
      f32x4 c2 = z, h2 = z; float p2[4];
      unitS(ldsw + SLOT_U16, STP(par, 1), ntA, mt, l, c2, h2, p2); // s1@Ws[1]
      epiS(p, par, 2, ntA, mt, l, p2, 1, c2, h2);        // s2 (relu)
      setfW(FB(p, 2, mt), fi, t + 1);
    }
    // decoder + log_softmax: blocks 0..15, one wave per batch row
    if (blk < 16) {
      int b = blk * 4 + mt;
      waitW(FB(p, 7, b >> 4), 54, 128);
      float myval = 0.0f;
      for (int c = 0; c < 42; ++c) {
        float part = 0.0f;
        for (int d = l; d < 850; d += 64)
          part += ldc_f32(p.accr + b * 850 + d) * ldf(p.dec_W, c * 850 + d, bf);
        for (int off = 32; off > 0; off >>= 1) part += __shfl_xor(part, off);
        if (l == c) myval = part * (1.0f / 128.0f) + ldf(p.dec_b, c, bf);
      }
      float mx = (l < 42) ? myval : -INFINITY;
      for (int off = 32; off > 0; off >>= 1) mx = fmaxf(mx, __shfl_xor(mx, off));
      float ex = (l < 42) ? expf(myval - mx) : 0.0f;
      float sm = ex;
      for (int off = 32; off > 0; off >>= 1) sm += __shfl_xor(sm, off);
      if (l < 42) stout(p.out, (size_t)b * 42 + l, myval - mx - logf(sm), bf);
    }
  } else if (role == 1) {
    const int fi = blk - 54;
    for (int t = 0; t < 128; ++t) {
      int par = t & 1;
      waitW(FB(p, 0, mt), 54, t + 1);
      f32x4 cc = z, hh = z; float pv[4];
      unitS(ldsw, STP(par, 0), ntA, mt, l, cc, hh, pv);  // s0@Ws[0]
      epiS(p, par, 1, ntA, mt, l, pv, 0, cc, hh);        // s1 (sigmoid)
      setfW(FB(p, 1, mt), fi, t + 1);
      f32x4 c2 = z, h2 = z; float p2[4];                 // own s1: flags imply done
      unitS(ldsw + SLOT_U16, STP(par, 1), ntA, mt, l, c2, h2, p2); // s1@Ws[2]
      epiS(p, par, 3, ntA, mt, l, p2, 1, c2, h2);        // s3 (relu)
      setfW(FB(p, 3, mt), fi, t + 1);
    }
  } else if (role == 2) {
    const int fi = blk - 108;
    for (int t = 0; t < 128; ++t) {
      int par = t & 1;
      waitW(FB(p, 1, mt), 54, t + 1);
      f32x4 cc = z, hh = z; float pv[4];
      unitS(ldsw + SLOT_U16, STP(par, 1), ntA, mt, l, cc, hh, pv); // s1@Ws[3]
      epiS(p, par, 4, ntA, mt, l, pv, 3, cc, hh);        // s4 (identity)
      setfW(FB(p, 4, mt), fi, t + 1);
      waitW(FB(p, 2, mt), 54, t + 1);
      f32x4 c2 = z, h2 = z; float p2[4];
      unitS(ldsw, STP(par, 2), ntA, mt, l, c2, h2, p2);  // s2@Ws[4]
      epiS(p, par, 5, ntA, mt, l, p2, 2, c2, h2);        // s5 (tanh)
      setfW(FB(p, 5, mt), fi, t + 1);
    }
  } else if (role == 4) {
    const int fi = blk - 216;
    for (int t = 0; t < 128; ++t) {
      int par = t & 1;
      waitW(FB(p, 3, mt), 54, t + 1);
      f32x4 cA = z, hA = z, cB = z, hB = z; float pa[4], pb[4];
      unit2S(ldsw, ldsw + SLOT_U16, STP(par, 3), ntA, ntB, mt, l,
             cA, hA, cB, hB, pa, pb);                    // s3@Ws[6], 2 nt
      epiS(p, par, 6, ntA, mt, l, pa, 2, cA, hA);        // s7 (tanh)
      epiS(p, par, 6, ntB, mt, l, pb, 2, cB, hB);
      setfW(FB(p, 6, mt), fi, t + 1);
    }
  } else { // role 3
    const int fi = blk - 162;
    float areg[4] = {0.f, 0.f, 0.f, 0.f};
    const int n = ntA * 16 + lm;
    for (int t = 0; t < 128; ++t) {
      int par = t & 1, par2 = (t + 1) & 1;
      waitW3(FB(p, 2, mt), FB(p, 3, mt), FB(p, 4, mt), 54, t + 1);
      float psum[4];                                     // prefetch s1+s2+s3+s4
      {
        u16 q1[4], q2[4], q3[4], q4[4];
#pragma unroll
        for (int i = 0; i < 4; ++i) {
          size_t off = (((size_t)ntA * 64 + mt * 16 + lg * 4 + i) << 4) + lm;
          q1[i] = ldc_u16(STP(par, 1) + off); q2[i] = ldc_u16(STP(par, 2) + off);
          q3[i] = ldc_u16(STP(par, 3) + off); q4[i] = ldc_u16(STP(par, 4) + off);
        }
#pragma unroll
        for (int i = 0; i < 4; ++i)
          psum[i] = bf2f(q1[i]) + bf2f(q2[i]) + bf2f(q3[i]) + bf2f(q4[i]);
      }
      waitW2(FB(p, 5, mt), 54, FB(p, 6, mt), 27, t + 1);
      u16 q7[4];
#pragma unroll
      for (int i = 0; i < 4; ++i)
        q7[i] = ldc_u16(STP(par, 6) + (((size_t)ntA * 64 + mt * 16 + lg * 4 + i) << 4) + lm);
      f32x4 cA = z, hA = z, cB = z, hB = z; float s5v[4], s5d[4];
      unit2S(ldsw, ldsw + SLOT_U16, STP(par, 5), ntA, ntA, mt, l,
             cA, hA, cB, hB, s5v, s5d);                  // s5@Ws[5], s5@Ws[7]
      if (n < 850) {
        u16* hdst = STP(par2, 7);
#pragma unroll
        for (int i = 0; i < 4; ++i) {
          int b = mt * 16 + lg * 4 + i;
          float s6 = s5v[i] + sigm(cA[i]) * (sigm(hA[i]) - s5v[i]);
          float s8 = s5v[i] + sigm(cB[i]) * (fmaxf(hB[i], 0.f) - s5v[i]);
          float sum = psum[i] + s5v[i] + bf2f(q7[i]) + s6 + s8;
          float outv = sum * 0.125f;
          float mk = ldf(p.masks, b * 128 + t, bf);
          areg[i] += outv * mk;
          stc_u16(hdst + (((size_t)ntA * 64 + b) << 4) + lm, f2bf(outv));
          if (t == 127) {
            stout(p.out, 2688 + (size_t)b * 850 + n, outv * mk, bf);
            stc_f32(p.accr + b * 850 + n, areg[i]);
          }
        }
      }
      setfW(FB(p, 7, mt), fi, t + 1);
    }
  }
#undef STP
}

// ---------------- launch ----------------

extern "C" void kernel_launch(void* const* d_in, const int* in_sizes, int n_in,
                              void* d_out, int out_size, void* d_ws, size_t ws_size,
                              hipStream_t stream) {
  (void)in_sizes; (void)n_in; (void)out_size;
  P p;
  p.tokens = (const int*)d_in[0];
  p.masks  = d_in[1];
  p.pos    = (const int*)d_in[2];
  p.ner    = (const int*)d_in[3];
  p.hidden = d_in[4];
  p.enc_W  = d_in[5];
  p.ner_W  = d_in[6];
  p.pos_W  = d_in[7];
  p.agg_W  = d_in[8];
  p.agg_b  = d_in[9];
  p.W0     = d_in[10];
  p.Ws     = d_in[11];
  p.dec_W  = d_in[12];
  p.dec_b  = d_in[13];
  p.out    = d_out;

  unsigned char* ws = (unsigned char*)d_ws;
  p.ctrl = (int*)ws;
  unsigned char* R0 = ws + 32768;
  p.PK_agg = (unsigned short*)R0;
  p.comb   = (unsigned short*)(R0 + 1603584);
  p.PK_rec = (unsigned short*)R0;
  unsigned char* q = R0 + 29859840;
  p.xbf  = (unsigned short*)q; q += 14155776;
  p.Sbf  = (unsigned short*)q; q += 1769472;
  p.accr = (float*)q;          q += 217600;

  size_t need = (size_t)(q - ws);
  if (ws_size < need) {
    hipLaunchKernelGGL(k_diag, dim3(1), dim3(64), 0, stream, p);
    return;
  }

  static int lds_attr_set = 0;
  if (!lds_attr_set) { // host-side attribute, idempotent, graph-capture safe
    (void)hipFuncSetAttribute((const void*)k_scan,
                              hipFuncAttributeMaxDynamicSharedMemorySize, LDS_BYTES);
    lds_attr_set = 1;
  }

  hipLaunchKernelGGL(k_detect,   dim3(1),    dim3(64),  0, stream, p);
  hipLaunchKernelGGL(k_init0,    dim3(256),  dim3(256), 0, stream, p);
  hipLaunchKernelGGL(k_init1,    dim3(64),   dim3(256), 0, stream, p);
  hipLaunchKernelGGL(k_pack_agg, dim3(512),  dim3(256), 0, stream, p);
  hipLaunchKernelGGL(k_comb,     dim3(4096), dim3(256), 0, stream, p);
  hipLaunchKernelGGL(k_phaseA,   dim3(256),  dim3(256), 0, stream, p);
  hipLaunchKernelGGL(k_pack_rec, dim3(4096), dim3(256), 0, stream, p);
  hipLaunchKernelGGL(k_scan,     dim3(NBLK), dim3(256), LDS_BYTES, stream, p);
}

// Round 9
// 3394.930 us; speedup vs baseline: 13.5556x; 1.3769x over previous
//
#include <hip/hip_runtime.h>
#include <math.h>

typedef float f32x4 __attribute__((ext_vector_type(4)));
typedef short s16x8 __attribute__((ext_vector_type(8)));
typedef unsigned short u16;

#define MFMA_BF16(a,b,c) __builtin_amdgcn_mfma_f32_16x16x32_bf16((a),(b),(c),0,0,0)
#define NBLK 243
#define PAIR_U16 13824   // one half-matrix tile: 27 kb * 512
#define SLOT_U16 27648   // c+h halves
#define LDS_BYTES 110592 // 2 slots * 27648 u16 * 2B
#define ST_SLOT 55296    // u16 per state slot (54 nt * 64 rows * 16 cols)

// Dataflow scan: 243 persistent blocks (1/CU), weights LDS-resident.
// State (bf16) [parity][slot][nt][64][16]: slots 0=s0 1=s1 2=s2 3=s3 4=s4 5=s5 6=s7 7=h
// Sync: PER-WAVE epoch flags, ONE FLAG PER 64B (stride-16 ints) to spread LLC bank
// load; polls back off with s_sleep after 2 hot iterations (anti-congestion).
// Loads = inline-asm global_load_dwordx4 sc1 bursts; stores = relaxed agent atomics.

struct P {
  const int* tokens; const void* masks; const int* pos; const int* ner;
  const void* hidden;
  const void* enc_W; const void* ner_W; const void* pos_W;
  const void* agg_W; const void* agg_b;
  const void* W0; const void* Ws;
  const void* dec_W; const void* dec_b;
  void* out;
  unsigned short* PK_agg; unsigned short* PK_rec; unsigned short* comb;
  unsigned short* xbf; unsigned short* Sbf;
  float* accr;
  int* ctrl; // [0]=bf16 flag; flags at 1024: F[g][mt][fi], one per 16 ints (64B)
};

#define FB(pp, g, mtv) ((pp).ctrl + 1024 + (((g) * 4 + (mtv)) * 54) * 16)

__device__ __forceinline__ unsigned short f2bf(float f) {
  union { float f; unsigned u; } v; v.f = f;
  return (unsigned short)((v.u + 0x7FFFu + ((v.u >> 16) & 1u)) >> 16);
}
__device__ __forceinline__ float bf2f(u16 x) {
  union { unsigned u; float f; } v; v.u = (unsigned)x << 16; return v.f;
}
__device__ __forceinline__ float ldf(const void* q, size_t i, int bf) {
  if (bf) return bf2f(((const u16*)q)[i]);
  return ((const float*)q)[i];
}
__device__ __forceinline__ void stout(void* o, size_t i, float v, int bf) {
  if (bf) ((u16*)o)[i] = f2bf(v);
  else    ((float*)o)[i] = v;
}
__device__ __forceinline__ float sigm(float x) { return 1.0f / (1.0f + expf(-x)); }
__device__ __forceinline__ float actf(int a, float x) {
  if (a == 0) return sigm(x);
  if (a == 1) return fmaxf(x, 0.0f);
  if (a == 2) return tanhf(x);
  return x;
}

// ---- LLC-coherent accessors ----
__device__ __forceinline__ s16x8 ldg16_sc1(const u16* p) {
  s16x8 r;
  asm volatile("global_load_dwordx4 %0, %1, off sc1" : "=v"(r) : "v"(p) : "memory");
  return r;
}
__device__ __forceinline__ void vmfence() {
  asm volatile("s_waitcnt vmcnt(0)" ::: "memory");
  __builtin_amdgcn_sched_barrier(0); // rule #18
}
__device__ __forceinline__ u16 ldc_u16(const u16* p) {
  return __hip_atomic_load(p, __ATOMIC_RELAXED, __HIP_MEMORY_SCOPE_AGENT);
}
__device__ __forceinline__ float ldc_f32(const float* p) {
  unsigned x = __hip_atomic_load((const unsigned*)p, __ATOMIC_RELAXED,
                                 __HIP_MEMORY_SCOPE_AGENT);
  union { unsigned u; float f; } v; v.u = x; return v.f;
}
__device__ __forceinline__ void stc_f32(float* p, float f) {
  union { float f; unsigned u; } v; v.f = f;
  __hip_atomic_store((unsigned*)p, v.u, __ATOMIC_RELAXED, __HIP_MEMORY_SCOPE_AGENT);
}
__device__ __forceinline__ void stc_u16(u16* p, u16 x) {
  __hip_atomic_store(p, x, __ATOMIC_RELAXED, __HIP_MEMORY_SCOPE_AGENT);
}
__device__ __forceinline__ void stc_i32(int* p, int x) {
  __hip_atomic_store(p, x, __ATOMIC_RELAXED, __HIP_MEMORY_SCOPE_AGENT);
}
__device__ __forceinline__ int ldc_i32(const int* p) {
  return __hip_atomic_load(p, __ATOMIC_RELAXED, __HIP_MEMORY_SCOPE_AGENT);
}

// ---- per-wave sync (spread flags + backoff polls) ----
__device__ __forceinline__ void setfW(int* fb, int fi, int e) {
  asm volatile("s_waitcnt vmcnt(0)" ::: "memory"); // drain this wave's state stores
  if ((threadIdx.x & 63) == 0) stc_i32(fb + fi * 16, e);
}
__device__ __forceinline__ void waitW(const int* fb, int n, int e) {
  int l = threadIdx.x & 63, it = 0;
  for (;;) {
    int ok = (l < n) ? (ldc_i32(fb + l * 16) >= e) : 1;
    if (__all(ok)) break;
    if (++it > 4000000) break; // bounded diagnostic escape
    if (it > 2) __builtin_amdgcn_s_sleep(2);
  }
  asm volatile("" ::: "memory");
}
__device__ __forceinline__ void waitW2(const int* fa, int na, const int* fb, int nb, int e) {
  int l = threadIdx.x & 63, it = 0;
  for (;;) {
    int ok = ((l < na) ? (ldc_i32(fa + l * 16) >= e) : 1) &
             ((l < nb) ? (ldc_i32(fb + l * 16) >= e) : 1);
    if (__all(ok)) break;
    if (++it > 4000000) break;
    if (it > 2) __builtin_amdgcn_s_sleep(2);
  }
  asm volatile("" ::: "memory");
}
__device__ __forceinline__ void waitW3(const int* fa, const int* fb, const int* fc,
                                       int n, int e) {
  int l = threadIdx.x & 63, it = 0;
  for (;;) {
    int ok = 1;
    if (l < n) ok = (ldc_i32(fa + l * 16) >= e) & (ldc_i32(fb + l * 16) >= e) &
                    (ldc_i32(fc + l * 16) >= e);
    if (__all(ok)) break;
    if (++it > 4000000) break;
    if (it > 2) __builtin_amdgcn_s_sleep(2);
  }
  asm volatile("" ::: "memory");
}

// ---------------- prep kernels ----------------

__global__ void k_detect(P p) {
  for (int j = threadIdx.x; j < 32768; j += 64) p.ctrl[j] = 0;
  __syncthreads();
  if (threadIdx.x == 0) {
    const u16* u = (const u16*)p.W0;
    int good = 0;
    for (int i = 0; i < 256; ++i) {
      int e = (u[i] >> 7) & 0xFF;
      if (e >= 90 && e <= 126) ++good;
    }
    p.ctrl[0] = (good >= 192) ? 1 : 0;
  }
}

__global__ __launch_bounds__(256) void k_init0(P p) { // zero Sbf + xbf pads
  const int total = 442368 + 114688;
  for (int e = blockIdx.x * blockDim.x + threadIdx.x; e < total;
       e += gridDim.x * blockDim.x) {
    if (e < 442368) {
      ((unsigned*)p.Sbf)[e] = 0u;
    } else {
      int e4 = e - 442368; int t = e4 / 896, r = e4 % 896;
      int b = r / 14, n = 850 + r % 14;
      p.xbf[((size_t)t * 64 + b) * 864 + n] = 0;
    }
  }
}

__global__ __launch_bounds__(256) void k_init1(P p) { // h(0) -> slot7 par0, tiled layout
  const int bf = p.ctrl[0];
  for (int e = blockIdx.x * blockDim.x + threadIdx.x; e < 54400;
       e += gridDim.x * blockDim.x) {
    int b = e / 850, n = e % 850;
    p.Sbf[(size_t)7 * ST_SLOT + (((size_t)(n >> 4) * 64 + b) << 4) + (n & 15)] =
        f2bf(ldf(p.hidden, e, bf));
  }
}

__global__ __launch_bounds__(256) void k_pack_agg(P p) {
  const int bf = p.ctrl[0];
  const long total = 801792L;
  for (long e = (long)blockIdx.x * blockDim.x + threadIdx.x; e < total;
       e += (long)gridDim.x * blockDim.x) {
    int j = (int)(e & 7), l = (int)((e >> 3) & 63);
    long q9 = e >> 9;
    int kb = (int)(q9 % 29), nt = (int)(q9 / 29);
    int n = nt * 16 + (l & 15);
    int k = kb * 32 + ((l >> 4) << 3) + j;
    float v = 0.0f;
    if (n < 850 && k < 910) v = ldf(p.agg_W, (size_t)n * 910 + k, bf);
    p.PK_agg[e] = f2bf(v);
  }
}

__global__ __launch_bounds__(256) void k_comb(P p) {
  const int bf = p.ctrl[0];
  const long total = 7602176L;
  for (long e = (long)blockIdx.x * blockDim.x + threadIdx.x; e < total;
       e += (long)gridDim.x * blockDim.x) {
    int k = (int)(e % 928);
    int r = (int)(e / 928);
    int t = r >> 6, b = r & 63;
    float v = 0.0f;
    if (k < 850)      { int tok = p.tokens[b * 128 + t]; v = ldf(p.enc_W, (size_t)tok * 850 + k, bf); }
    else if (k < 880) { int nv = p.ner[b * 128 + t];     v = ldf(p.ner_W, nv * 30 + (k - 850), bf); }
    else if (k < 910) { int pv = p.pos[b * 128 + t];     v = ldf(p.pos_W, pv * 30 + (k - 880), bf); }
    p.comb[e] = f2bf(v);
  }
}

__global__ __launch_bounds__(256) void k_pack_rec(P p) {
  const int bf = p.ctrl[0];
  const long total = 14929920L;
  for (long e = (long)blockIdx.x * blockDim.x + threadIdx.x; e < total;
       e += (long)gridDim.x * blockDim.x) {
    int j = (int)(e & 7), l = (int)((e >> 3) & 63);
    long q9 = e >> 9;
    int kb = (int)(q9 % 27);
    long q = q9 / 27;
    int nt = (int)(q % 54);
    int mh = (int)(q / 54);
    int half = mh & 1, mat = mh >> 1;
    int nl = nt * 16 + (l & 15);
    int col = half ? nl + 850 : nl;
    int k = kb * 32 + ((l >> 4) << 3) + j;
    float v = 0.0f;
    if (nl < 850 && k < 850) {
      if (mat == 0)      v = ldf(p.W0, (size_t)k * 1700 + col, bf);
      else if (mat == 1) v = ldf(p.W0, (size_t)(k + 850) * 1700 + col, bf);
      else               v = ldf(p.Ws, (size_t)(mat - 2) * 850 * 1700 + (size_t)k * 1700 + col, bf);
    }
    p.PK_rec[e] = f2bf(v);
  }
}

__global__ void k_diag(P p) {
  if (blockIdx.x == 0 && threadIdx.x == 0)
    for (int i = 0; i < 64; ++i) ((float*)p.out)[i] = 2000.0f;
}

__global__ __launch_bounds__(256) void k_phaseA(P p) {
  const int tid = threadIdx.x;
  const int l = tid & 63, lm = l & 15, lg = l >> 4;
  const int wid = (blockIdx.x << 2) | (tid >> 6);
  const int bf = p.ctrl[0];
  for (int u = wid; u < 512 * 54; u += 1024) {
    int mt = u / 54, nt = u - mt * 54;
    int r0 = mt << 4;
    f32x4 acc = {0.f, 0.f, 0.f, 0.f};
    const u16* Arow = p.comb + (size_t)(r0 + lm) * 928 + (size_t)lg * 8;
    const u16* Bp = p.PK_agg + (size_t)nt * 29 * 512 + (size_t)l * 8;
    for (int kb = 0; kb < 29; ++kb) {
      s16x8 a = *(const s16x8*)(Arow + (size_t)kb * 32);
      s16x8 b = *(const s16x8*)(Bp + (size_t)kb * 512);
      acc = MFMA_BF16(a, b, acc);
    }
    int n = nt * 16 + lm;
    if (n < 850) {
      float bias = ldf(p.agg_b, n, bf);
#pragma unroll
      for (int i = 0; i < 4; ++i) {
        int r = r0 + lg * 4 + i;
        p.xbf[(size_t)r * 864 + n] = f2bf(acc[i] + bias);
      }
    }
  }
}

// ---------------- scan units ----------------

// A burst from tiled state slot: fragment (row, k..k+7) at ((2kb+(lg>>1))*64+row)*16+(lg&1)*8
__device__ __forceinline__ void burstA(const u16* st, int mt, int l, s16x8* ab) {
  const int lm = l & 15, lg = l >> 4;
  const int row = mt * 16 + lm;
  const u16* A = st + (((size_t)(lg >> 1) * 64 + row) << 4) + ((lg & 1) << 3);
#pragma unroll
  for (int kb = 0; kb < 27; ++kb) ab[kb] = ldg16_sc1(A + (size_t)kb * 2048);
}

__device__ __forceinline__ void unitS(const u16* lds, const u16* st, int nt, int mt,
                                      int l, f32x4& cc, f32x4& hh, float* prev) {
  const int lm = l & 15, lg = l >> 4;
  s16x8 ab[27];
  burstA(st, mt, l, ab);
  u16 pv[4];
#pragma unroll
  for (int i = 0; i < 4; ++i)
    pv[i] = ldc_u16(st + (((size_t)nt * 64 + mt * 16 + lg * 4 + i) << 4) + lm);
  vmfence();
  const f32x4 z = {0.f, 0.f, 0.f, 0.f};
  f32x4 c0 = z, c1 = z, h0 = z, h1 = z;
#pragma unroll
  for (int kb = 0; kb < 27; ++kb) {
    s16x8 bc = *(const s16x8*)(lds + l * 8 + (size_t)kb * 512);
    s16x8 bh = *(const s16x8*)(lds + PAIR_U16 + l * 8 + (size_t)kb * 512);
    if (kb & 1) { c1 = MFMA_BF16(ab[kb], bc, c1); h1 = MFMA_BF16(ab[kb], bh, h1); }
    else        { c0 = MFMA_BF16(ab[kb], bc, c0); h0 = MFMA_BF16(ab[kb], bh, h0); }
  }
  cc += c0 + c1; hh += h0 + h1;
#pragma unroll
  for (int i = 0; i < 4; ++i) prev[i] = bf2f(pv[i]);
}

__device__ __forceinline__ void unit2S(const u16* lds0, const u16* lds1, const u16* st,
                                       int ntA, int ntB, int mt, int l,
                                       f32x4& cA, f32x4& hA, f32x4& cB, f32x4& hB,
                                       float* prevA, float* prevB) {
  const int lm = l & 15, lg = l >> 4;
  s16x8 ab[27];
  burstA(st, mt, l, ab);
  u16 pa[4], pb[4];
#pragma unroll
  for (int i = 0; i < 4; ++i) {
    size_t row = mt * 16 + lg * 4 + i;
    pa[i] = ldc_u16(st + (((size_t)ntA * 64 + row) << 4) + lm);
    pb[i] = ldc_u16(st + (((size_t)ntB * 64 + row) << 4) + lm);
  }
  vmfence();
#pragma unroll
  for (int kb = 0; kb < 27; ++kb) {
    cA = MFMA_BF16(ab[kb], *(const s16x8*)(lds0 + l * 8 + (size_t)kb * 512), cA);
    hA = MFMA_BF16(ab[kb], *(const s16x8*)(lds0 + PAIR_U16 + l * 8 + (size_t)kb * 512), hA);
    cB = MFMA_BF16(ab[kb], *(const s16x8*)(lds1 + l * 8 + (size_t)kb * 512), cB);
    hB = MFMA_BF16(ab[kb], *(const s16x8*)(lds1 + PAIR_U16 + l * 8 + (size_t)kb * 512), hB);
  }
#pragma unroll
  for (int i = 0; i < 4; ++i) { prevA[i] = bf2f(pa[i]); prevB[i] = bf2f(pb[i]); }
}

__device__ __forceinline__ void unit_x(const P& p, int nt, int t, int mt, int l,
                                       f32x4& cc, f32x4& hh) {
  const int lm = l & 15, lg = l >> 4;
  const u16* Ax = p.xbf + ((size_t)t * 64 + mt * 16 + lm) * 864 + (size_t)lg * 8;
  const u16* B0 = p.PK_rec + (size_t)(0 * 54 + nt) * PAIR_U16 + l * 8;
  const u16* B1 = p.PK_rec + (size_t)(1 * 54 + nt) * PAIR_U16 + l * 8;
  s16x8 ab[27];
#pragma unroll
  for (int kb = 0; kb < 27; ++kb) ab[kb] = *(const s16x8*)(Ax + (size_t)kb * 32);
  const f32x4 z = {0.f, 0.f, 0.f, 0.f};
  f32x4 c0 = z, c1 = z, h0 = z, h1 = z;
#pragma unroll
  for (int kb = 0; kb < 27; ++kb) {
    s16x8 bc = *(const s16x8*)(B0 + (size_t)kb * 512);
    s16x8 bh = *(const s16x8*)(B1 + (size_t)kb * 512);
    if (kb & 1) { c1 = MFMA_BF16(ab[kb], bc, c1); h1 = MFMA_BF16(ab[kb], bh, h1); }
    else        { c0 = MFMA_BF16(ab[kb], bc, c0); h0 = MFMA_BF16(ab[kb], bh, h0); }
  }
  cc += c0 + c1; hh += h0 + h1;
}

__device__ __forceinline__ void epiS(const P& p, int par, int slot, int nt, int mt,
                                     int l, const float* prev, int act,
                                     f32x4 c, f32x4 h) {
  int lm = l & 15, lg = l >> 4, n = nt * 16 + lm;
  if (n >= 850) return;
  u16* dst = p.Sbf + (size_t)(par * 8 + slot) * ST_SLOT;
#pragma unroll
  for (int i = 0; i < 4; ++i) {
    size_t row = mt * 16 + lg * 4 + i;
    float s = prev[i] + sigm(c[i]) * (actf(act, h[i]) - prev[i]);
    stc_u16(dst + (((size_t)nt * 64 + row) << 4) + lm, f2bf(s));
  }
}

__global__ __launch_bounds__(256, 1) void k_scan(P p) {
  extern __shared__ u16 ldsw[];
  const int tid = threadIdx.x;
  const int l = tid & 63, lm = l & 15, lg = l >> 4, mt = tid >> 6;
  const int blk = blockIdx.x;
  const int bf = p.ctrl[0];
#define STP(par, slot) (p.Sbf + (size_t)((par) * 8 + (slot)) * ST_SLOT)

  int role, matA, ntA, matB, ntB;
  if (blk < 54)       { role = 0; matA = 1; ntA = blk;       matB = 3; ntB = ntA; }
  else if (blk < 108) { role = 1; matA = 2; ntA = blk - 54;  matB = 4; ntB = ntA; }
  else if (blk < 162) { role = 2; matA = 6; ntA = blk - 108; matB = 5; ntB = ntA; }
  else if (blk < 216) { role = 3; matA = 7; ntA = blk - 162; matB = 9; ntB = ntA; }
  else                { role = 4; matA = 8; ntA = 2 * (blk - 216); matB = 8; ntB = ntA + 1; }

  for (int s = 0; s < 2; ++s) {
    int m = s ? matB : matA, nt = s ? ntB : ntA;
    for (int h = 0; h < 2; ++h) {
      const uint4* src = (const uint4*)(p.PK_rec + ((size_t)(m * 2 + h) * 54 + nt) * PAIR_U16);
      uint4* dst = (uint4*)(ldsw + s * SLOT_U16 + h * PAIR_U16);
      for (int i = tid; i < PAIR_U16 / 8; i += 256) dst[i] = src[i];
    }
  }
  __syncthreads();

  const f32x4 z = {0.f, 0.f, 0.f, 0.f};

  if (role == 0) {
    const int fi = blk;
    for (int t = 0; t < 128; ++t) {
      int par = t & 1;
      f32x4 cc = z, hh = z;
      unit_x(p, ntA, t, mt, l, cc, hh);      // x@W0_lo, overlaps the F4 wait
      waitW(FB(p, 7, mt), 54, t);             // h(t) ready (this m-tile)
      float pv[4];
      unitS(ldsw, STP(par, 7), ntA, mt, l, cc, hh, pv);  // + h@W0_hi
      epiS(p, par, 0, ntA, mt, l, pv, 2, cc, hh);        // s0 (tanh)
      setfW(FB(p, 0, mt), fi, t + 1);
      waitW(FB(p, 1, mt), 54, t + 1);
      f32x4 c2 = z, h2 = z; float p2[4];
      unitS(ldsw + SLOT_U16, STP(par, 1), ntA, mt, l, c2, h2, p2); // s1@Ws[1]
      epiS(p, par, 2, ntA, mt, l, p2, 1, c2, h2);        // s2 (relu)
      setfW(FB(p, 2, mt), fi, t + 1);
    }
    // decoder + log_softmax: blocks 0..15, one wave per batch row
    if (blk < 16) {
      int b = blk * 4 + mt;
      waitW(FB(p, 7, b >> 4), 54, 128);
      float myval = 0.0f;
      for (int c = 0; c < 42; ++c) {
        float part = 0.0f;
        for (int d = l; d < 850; d += 64)
          part += ldc_f32(p.accr + b * 850 + d) * ldf(p.dec_W, c * 850 + d, bf);
        for (int off = 32; off > 0; off >>= 1) part += __shfl_xor(part, off);
        if (l == c) myval = part * (1.0f / 128.0f) + ldf(p.dec_b, c, bf);
      }
      float mx = (l < 42) ? myval : -INFINITY;
      for (int off = 32; off > 0; off >>= 1) mx = fmaxf(mx, __shfl_xor(mx, off));
      float ex = (l < 42) ? expf(myval - mx) : 0.0f;
      float sm = ex;
      for (int off = 32; off > 0; off >>= 1) sm += __shfl_xor(sm, off);
      if (l < 42) stout(p.out, (size_t)b * 42 + l, myval - mx - logf(sm), bf);
    }
  } else if (role == 1) {
    const int fi = blk - 54;
    for (int t = 0; t < 128; ++t) {
      int par = t & 1;
      waitW(FB(p, 0, mt), 54, t + 1);
      f32x4 cc = z, hh = z; float pv[4];
      unitS(ldsw, STP(par, 0), ntA, mt, l, cc, hh, pv);  // s0@Ws[0]
      epiS(p, par, 1, ntA, mt, l, pv, 0, cc, hh);        // s1 (sigmoid)
      setfW(FB(p, 1, mt), fi, t + 1);
      waitW(FB(p, 1, mt), 54, t + 1);                    // all s1 tiles (race fix)
      f32x4 c2 = z, h2 = z; float p2[4];
      unitS(ldsw + SLOT_U16, STP(par, 1), ntA, mt, l, c2, h2, p2); // s1@Ws[2]
      epiS(p, par, 3, ntA, mt, l, p2, 1, c2, h2);        // s3 (relu)
      setfW(FB(p, 3, mt), fi, t + 1);
    }
  } else if (role == 2) {
    const int fi = blk - 108;
    for (int t = 0; t < 128; ++t) {
      int par = t & 1;
      waitW(FB(p, 1, mt), 54, t + 1);
      f32x4 cc = z, hh = z; float pv[4];
      unitS(ldsw + SLOT_U16, STP(par, 1), ntA, mt, l, cc, hh, pv); // s1@Ws[3]
      epiS(p, par, 4, ntA, mt, l, pv, 3, cc, hh);        // s4 (identity)
      setfW(FB(p, 4, mt), fi, t + 1);
      waitW(FB(p, 2, mt), 54, t + 1);
      f32x4 c2 = z, h2 = z; float p2[4];
      unitS(ldsw, STP(par, 2), ntA, mt, l, c2, h2, p2);  // s2@Ws[4]
      epiS(p, par, 5, ntA, mt, l, p2, 2, c2, h2);        // s5 (tanh)
      setfW(FB(p, 5, mt), fi, t + 1);
    }
  } else if (role == 4) {
    const int fi = blk - 216;
    for (int t = 0; t < 128; ++t) {
      int par = t & 1;
      waitW(FB(p, 3, mt), 54, t + 1);
      f32x4 cA = z, hA = z, cB = z, hB = z; float pa[4], pb[4];
      unit2S(ldsw, ldsw + SLOT_U16, STP(par, 3), ntA, ntB, mt, l,
             cA, hA, cB, hB, pa, pb);                    // s3@Ws[6], 2 nt
      epiS(p, par, 6, ntA, mt, l, pa, 2, cA, hA);        // s7 (tanh)
      epiS(p, par, 6, ntB, mt, l, pb, 2, cB, hB);
      setfW(FB(p, 6, mt), fi, t + 1);
    }
  } else { // role 3
    const int fi = blk - 162;
    float areg[4] = {0.f, 0.f, 0.f, 0.f};
    const int n = ntA * 16 + lm;
    for (int t = 0; t < 128; ++t) {
      int par = t & 1, par2 = (t + 1) & 1;
      waitW3(FB(p, 2, mt), FB(p, 3, mt), FB(p, 4, mt), 54, t + 1);
      float psum[4];                                     // prefetch s1+s2+s3+s4
      {
        u16 q1[4], q2[4], q3[4], q4[4];
#pragma unroll
        for (int i = 0; i < 4; ++i) {
          size_t off = (((size_t)ntA * 64 + mt * 16 + lg * 4 + i) << 4) + lm;
          q1[i] = ldc_u16(STP(par, 1) + off); q2[i] = ldc_u16(STP(par, 2) + off);
          q3[i] = ldc_u16(STP(par, 3) + off); q4[i] = ldc_u16(STP(par, 4) + off);
        }
#pragma unroll
        for (int i = 0; i < 4; ++i)
          psum[i] = bf2f(q1[i]) + bf2f(q2[i]) + bf2f(q3[i]) + bf2f(q4[i]);
      }
      waitW2(FB(p, 5, mt), 54, FB(p, 6, mt), 27, t + 1);
      u16 q7[4];
#pragma unroll
      for (int i = 0; i < 4; ++i)
        q7[i] = ldc_u16(STP(par, 6) + (((size_t)ntA * 64 + mt * 16 + lg * 4 + i) << 4) + lm);
      f32x4 cA = z, hA = z, cB = z, hB = z; float s5v[4], s5d[4];
      unit2S(ldsw, ldsw + SLOT_U16, STP(par, 5), ntA, ntA, mt, l,
             cA, hA, cB, hB, s5v, s5d);                  // s5@Ws[5], s5@Ws[7]
      if (n < 850) {
        u16* hdst = STP(par2, 7);
#pragma unroll
        for (int i = 0; i < 4; ++i) {
          int b = mt * 16 + lg * 4 + i;
          float s6 = s5v[i] + sigm(cA[i]) * (sigm(hA[i]) - s5v[i]);
          float s8 = s5v[i] + sigm(cB[i]) * (fmaxf(hB[i], 0.f) - s5v[i]);
          float sum = psum[i] + s5v[i] + bf2f(q7[i]) + s6 + s8;
          float outv = sum * 0.125f;
          float mk = ldf(p.masks, b * 128 + t, bf);
          areg[i] += outv * mk;
          stc_u16(hdst + (((size_t)ntA * 64 + b) << 4) + lm, f2bf(outv));
          if (t == 127) {
            stout(p.out, 2688 + (size_t)b * 850 + n, outv * mk, bf);
            stc_f32(p.accr + b * 850 + n, areg[i]);
          }
        }
      }
      setfW(FB(p, 7, mt), fi, t + 1);
    }
  }
#undef STP
}

// ---------------- launch ----------------

extern "C" void kernel_launch(void* const* d_in, const int* in_sizes, int n_in,
                              void* d_out, int out_size, void* d_ws, size_t ws_size,
                              hipStream_t stream) {
  (void)in_sizes; (void)n_in; (void)out_size;
  P p;
  p.tokens = (const int*)d_in[0];
  p.masks  = d_in[1];
  p.pos    = (const int*)d_in[2];
  p.ner    = (const int*)d_in[3];
  p.hidden = d_in[4];
  p.enc_W  = d_in[5];
  p.ner_W  = d_in[6];
  p.pos_W  = d_in[7];
  p.agg_W  = d_in[8];
  p.agg_b  = d_in[9];
  p.W0     = d_in[10];
  p.Ws     = d_in[11];
  p.dec_W  = d_in[12];
  p.dec_b  = d_in[13];
  p.out    = d_out;

  unsigned char* ws = (unsigned char*)d_ws;
  p.ctrl = (int*)ws;
  unsigned char* R0 = ws + 262144; // ctrl region: 1024 + 8*4*54*16 ints < 256KB
  p.PK_agg = (unsigned short*)R0;
  p.comb   = (unsigned short*)(R0 + 1603584);
  p.PK_rec = (unsigned short*)R0;
  unsigned char* q = R0 + 29859840;
  p.xbf  = (unsigned short*)q; q += 14155776;
  p.Sbf  = (unsigned short*)q; q += 1769472;
  p.accr = (float*)q;          q += 217600;

  size_t need = (size_t)(q - ws);
  if (ws_size < need) {
    hipLaunchKernelGGL(k_diag, dim3(1), dim3(64), 0, stream, p);
    return;
  }

  static int lds_attr_set = 0;
  if (!lds_attr_set) { // host-side attribute, idempotent, graph-capture safe
    (void)hipFuncSetAttribute((const void*)k_scan,
                              hipFuncAttributeMaxDynamicSharedMemorySize, LDS_BYTES);
    lds_attr_set = 1;
  }

  hipLaunchKernelGGL(k_detect,   dim3(1),    dim3(64),  0, stream, p);
  hipLaunchKernelGGL(k_init0,    dim3(256),  dim3(256), 0, stream, p);
  hipLaunchKernelGGL(k_init1,    dim3(64),   dim3(256), 0, stream, p);
  hipLaunchKernelGGL(k_pack_agg, dim3(512),  dim3(256), 0, stream, p);
  hipLaunchKernelGGL(k_comb,     dim3(4096), dim3(256), 0, stream, p);
  hipLaunchKernelGGL(k_phaseA,   dim3(256),  dim3(256), 0, stream, p);
  hipLaunchKernelGGL(k_pack_rec, dim3(4096), dim3(256), 0, stream, p);
  hipLaunchKernelGGL(k_scan,     dim3(NBLK), dim3(256), LDS_BYTES, stream, p);
}